// Round 1
// baseline (794.848 us; speedup 1.0000x reference)
//
#include <hip/hip_runtime.h>
#include <math.h>

#define NTOK 1024
#define DIMM 512
#define NH 8
#define HD 64
#define BCB 16
#define BSB 16
#define KSEL 8
#define WWIN 256
#define CBLK 64
#define SCALE 0.125f
#define EPSV 1e-6f
#define NEGV -1e30f

// ---------- residual mix + rmsnorm ----------
__global__ void __launch_bounds__(256)
k_resid_rms(const float* __restrict__ x, const float* __restrict__ x0,
            const float* __restrict__ lam, float* __restrict__ xr,
            float* __restrict__ xn) {
  int row = blockIdx.x, tid = threadIdx.x;
  float l0 = lam[0], l1 = lam[1];
  size_t b = (size_t)row * DIMM;
  float a0 = l0 * x[b + tid]       + l1 * x0[b + tid];
  float a1 = l0 * x[b + tid + 256] + l1 * x0[b + tid + 256];
  xr[b + tid] = a0; xr[b + tid + 256] = a1;
  float ss = a0 * a0 + a1 * a1;
  __shared__ float sm[8];
  for (int o = 32; o > 0; o >>= 1) ss += __shfl_down(ss, o);
  int lane = tid & 63, wid = tid >> 6;
  if (lane == 0) sm[wid] = ss;
  __syncthreads();
  if (tid == 0) {
    float s = sm[0] + sm[1] + sm[2] + sm[3];
    sm[0] = rsqrtf(s / (float)DIMM + EPSV);
  }
  __syncthreads();
  float r = sm[0];
  xn[b + tid] = a0 * r; xn[b + tid + 256] = a1 * r;
}

// ---------- plain rmsnorm ----------
__global__ void __launch_bounds__(256)
k_rms(const float* __restrict__ xin, float* __restrict__ y) {
  int row = blockIdx.x, tid = threadIdx.x;
  size_t b = (size_t)row * DIMM;
  float a0 = xin[b + tid], a1 = xin[b + tid + 256];
  float ss = a0 * a0 + a1 * a1;
  __shared__ float sm[8];
  for (int o = 32; o > 0; o >>= 1) ss += __shfl_down(ss, o);
  int lane = tid & 63, wid = tid >> 6;
  if (lane == 0) sm[wid] = ss;
  __syncthreads();
  if (tid == 0) {
    float s = sm[0] + sm[1] + sm[2] + sm[3];
    sm[0] = rsqrtf(s / (float)DIMM + EPSV);
  }
  __syncthreads();
  float r = sm[0];
  y[b + tid] = a0 * r; y[b + tid + 256] = a1 * r;
}

// ---------- generic f32 GEMM: C = epi(A@B) (+ Res). M=1024 rows; Kd,Nd mult of 16/64 ----------
__global__ void __launch_bounds__(256)
k_gemm(const float* __restrict__ A, const float* __restrict__ B,
       const float* __restrict__ Res, float* __restrict__ Co,
       int Kd, int Nd, int epi) {
  __shared__ float As[64][17];
  __shared__ float Bs[16][64];
  int tid = threadIdx.x;
  int tx = tid & 15, ty = tid >> 4;
  int rb = blockIdx.y << 6, cb = blockIdx.x << 6;
  float acc[4][4];
#pragma unroll
  for (int i = 0; i < 4; i++)
#pragma unroll
    for (int j = 0; j < 4; j++) acc[i][j] = 0.f;
  int l = tid << 2;
  int amr = l >> 4, akk = l & 15;
  int bkr = l >> 6, bnc = l & 63;
  for (int k0 = 0; k0 < Kd; k0 += 16) {
    float4 a4 = *(const float4*)(A + (size_t)(rb + amr) * Kd + k0 + akk);
    As[amr][akk] = a4.x; As[amr][akk + 1] = a4.y;
    As[amr][akk + 2] = a4.z; As[amr][akk + 3] = a4.w;
    float4 b4 = *(const float4*)(B + (size_t)(k0 + bkr) * Nd + cb + bnc);
    Bs[bkr][bnc] = b4.x; Bs[bkr][bnc + 1] = b4.y;
    Bs[bkr][bnc + 2] = b4.z; Bs[bkr][bnc + 3] = b4.w;
    __syncthreads();
#pragma unroll
    for (int kk = 0; kk < 16; kk++) {
      float a[4], bvl[4];
#pragma unroll
      for (int i = 0; i < 4; i++) a[i] = As[ty * 4 + i][kk];
#pragma unroll
      for (int j = 0; j < 4; j++) bvl[j] = Bs[kk][tx * 4 + j];
#pragma unroll
      for (int i = 0; i < 4; i++)
#pragma unroll
        for (int j = 0; j < 4; j++) acc[i][j] = fmaf(a[i], bvl[j], acc[i][j]);
    }
    __syncthreads();
  }
#pragma unroll
  for (int i = 0; i < 4; i++) {
    int r = rb + ty * 4 + i;
#pragma unroll
    for (int j = 0; j < 4; j++) {
      int c = cb + tx * 4 + j;
      float vv = acc[i][j];
      if (epi == 1) { float t = fmaxf(vv, 0.f); vv = t * t; }
      if (Res) vv += Res[(size_t)r * Nd + c];
      Co[(size_t)r * Nd + c] = vv;
    }
  }
}

// ---------- gates: sigmoid(xn @ Wg), Wg (512,24) ----------
__global__ void __launch_bounds__(256)
k_gates(const float* __restrict__ xn, const float* __restrict__ Wg,
        float* __restrict__ gates) {
  int idx = blockIdx.x * 256 + threadIdx.x;
  if (idx >= NTOK * NH * 3) return;
  int col = idx % (NH * 3), n = idx / (NH * 3);
  float acc = 0.f;
  for (int e = 0; e < DIMM; e++)
    acc = fmaf(xn[(size_t)n * DIMM + e], Wg[(size_t)e * (NH * 3) + col], acc);
  gates[idx] = 1.f / (1.f + expf(-acc));
}

// ---------- RoPE in-place on q and k (layout n x (h*64+d)) ----------
__global__ void __launch_bounds__(256)
k_rope(float* __restrict__ q, float* __restrict__ k) {
  int idx = blockIdx.x * 256 + threadIdx.x;   // 0 .. 2*1024*8*32-1
  int ten = idx >> 18;                        // P = 262144 = 2^18
  int r = idx & 262143;
  int j = r & 31;
  int h = (r >> 5) & 7;
  int n = r >> 8;
  float* p = ten ? k : q;
  size_t base = (size_t)n * DIMM + h * HD + j;
  float inv = powf(10000.f, -(float)j / 32.f);
  float ang = (float)n * inv;
  float sn, cs;
  sincosf(ang, &sn, &cs);
  float x1 = p[base], x2 = p[base + 32];
  p[base] = x1 * cs - x2 * sn;
  p[base + 32] = x2 * cs + x1 * sn;
}

// ---------- compressed k/v: ck[h,c,:] = (kb flat) @ Wck + bck ----------
__global__ void __launch_bounds__(64)
k_ckcv(const float* __restrict__ k, const float* __restrict__ v,
       const float* __restrict__ k_pos, const float* __restrict__ v_pos,
       const float* __restrict__ Wck, const float* __restrict__ bck,
       const float* __restrict__ Wcv, const float* __restrict__ bcv,
       float* __restrict__ ck, float* __restrict__ cv) {
  int bx = blockIdx.x;
  int h = bx >> 6, c = bx & 63;
  int d = threadIdx.x;
  float ak = bck[d], av = bcv[d];
  for (int t = 0; t < BCB; ++t) {
    const float* krow = k + (size_t)(c * BCB + t) * DIMM + h * HD;
    const float* vrow = v + (size_t)(c * BCB + t) * DIMM + h * HD;
    const float* kp = k_pos + (size_t)(h * BCB + t) * HD;
    const float* vp = v_pos + (size_t)(h * BCB + t) * HD;
    for (int e = 0; e < HD; ++e) {
      float kv = krow[e] + kp[e];
      float vv = vrow[e] + vp[e];
      ak = fmaf(kv, Wck[(size_t)(t * HD + e) * HD + d], ak);
      av = fmaf(vv, Wcv[(size_t)(t * HD + e) * HD + d], av);
    }
  }
  ck[(size_t)(h * CBLK + c) * HD + d] = ak;
  cv[(size_t)(h * CBLK + c) * HD + d] = av;
}

// ---------- compressed attention + top-8 selection ----------
__global__ void __launch_bounds__(128)
k_cmp(const float* __restrict__ q, const float* __restrict__ ck,
      const float* __restrict__ cv, const float* __restrict__ k_mem,
      const float* __restrict__ v_mem, float* __restrict__ cout,
      int* __restrict__ sel) {
  int i = blockIdx.x, h = blockIdx.y, tid = threadIdx.x;
  __shared__ float sp[CBLK + 1];
  __shared__ float sred[2];
  const float* qr = q + (size_t)i * DIMM + h * HD;
  if (tid <= CBLK) {
    const float* kr = (tid == 0) ? (k_mem + h * HD)
                                 : (ck + (size_t)(h * CBLK + tid - 1) * HD);
    float dot = 0.f;
    for (int e = 0; e < HD; e++) dot = fmaf(qr[e], kr[e], dot);
    bool vis = (tid == 0) || (tid * BCB - 1 < i);
    sp[tid] = vis ? dot * SCALE : NEGV;
  }
  __syncthreads();
  if (tid == 0) {
    float m = sp[0];
    for (int j = 1; j <= CBLK; j++) m = fmaxf(m, sp[j]);
    sred[0] = m;
  }
  __syncthreads();
  if (tid <= CBLK) sp[tid] = expf(sp[tid] - sred[0]);
  __syncthreads();
  if (tid == 0) {
    float s = 0.f;
    for (int j = 0; j <= CBLK; j++) s += sp[j];
    sred[1] = s;
  }
  __syncthreads();
  float inv = 1.f / sred[1];
  if (tid < HD) {
    float acc = sp[0] * v_mem[h * HD + tid];
    for (int j = 1; j <= CBLK; j++)
      acc = fmaf(sp[j], cv[(size_t)(h * CBLK + j - 1) * HD + tid], acc);
    cout[(size_t)i * DIMM + h * HD + tid] = acc * inv;
  }
  if (tid == 0) {
    // top-8 over imp[c] = past ? p[c+1] : NEG ; tie -> smallest index (strict >)
    unsigned long long used = 0ULL;
    int base = (h * NTOK + i) * KSEL;
    for (int kk = 0; kk < KSEL; ++kk) {
      float bv = -INFINITY; int bc = 0;
      for (int c = 0; c < CBLK; c++) {
        if ((used >> c) & 1ULL) continue;
        float imp = (c * BCB + BCB - 1 < i) ? sp[c + 1] : NEGV;
        if (imp > bv) { bv = imp; bc = c; }
      }
      used |= 1ULL << bc;
      sel[base + kk] = (bv >= 0.f) ? bc : -1;
    }
  }
}

// ---------- fine attention over 8 selected blocks + own block ----------
__global__ void __launch_bounds__(192)
k_fine(const float* __restrict__ q, const float* __restrict__ k,
       const float* __restrict__ v, const int* __restrict__ sel,
       float* __restrict__ fout) {
  int i = blockIdx.x, h = blockIdx.y, tid = threadIdx.x;
  const int NL = (KSEL + 1) * BSB;   // 144
  __shared__ float sp[(KSEL + 1) * BSB];
  __shared__ int srow[(KSEL + 1) * BSB];
  __shared__ float sred[2];
  const float* qr = q + (size_t)i * DIMM + h * HD;
  int own = i >> 4;
  if (tid < NL) {
    int kk = tid >> 4, s = tid & 15;
    int bidx; bool vis;
    if (kk < KSEL) {
      bidx = sel[(h * NTOK + i) * KSEL + kk];
      vis = (bidx >= 0);
      if (!vis) bidx = 0;
    } else {
      bidx = own;
      vis = (s <= (i & 15));
    }
    int row = bidx * BSB + s;
    const float* kr = k + (size_t)row * DIMM + h * HD;
    float dot = 0.f;
    for (int e = 0; e < HD; e++) dot = fmaf(qr[e], kr[e], dot);
    sp[tid] = vis ? dot * SCALE : NEGV;
    srow[tid] = row;
  }
  __syncthreads();
  if (tid == 0) {
    float m = sp[0];
    for (int j = 1; j < NL; j++) m = fmaxf(m, sp[j]);
    sred[0] = m;
  }
  __syncthreads();
  if (tid < NL) sp[tid] = expf(sp[tid] - sred[0]);
  __syncthreads();
  if (tid == 0) {
    float s = 0.f;
    for (int j = 0; j < NL; j++) s += sp[j];
    sred[1] = s;
  }
  __syncthreads();
  float inv = 1.f / sred[1];
  if (tid < HD) {
    float acc = 0.f;
    for (int j = 0; j < NL; j++)
      acc = fmaf(sp[j], v[(size_t)srow[j] * DIMM + h * HD + tid], acc);
    fout[(size_t)i * DIMM + h * HD + tid] = acc * inv;
  }
}

// ---------- sliding window attention (window 256) ----------
__global__ void __launch_bounds__(256)
k_swin(const float* __restrict__ q, const float* __restrict__ k,
       const float* __restrict__ v, float* __restrict__ sout) {
  int i = blockIdx.x, h = blockIdx.y, tid = threadIdx.x;
  __shared__ float sp[WWIN];
  __shared__ float sred[2];
  int jstart = (i >= WWIN) ? (i - WWIN + 1) : 0;
  int cnt = i - jstart + 1;
  const float* qr = q + (size_t)i * DIMM + h * HD;
  float lg = NEGV;
  if (tid < cnt) {
    const float* kr = k + (size_t)(jstart + tid) * DIMM + h * HD;
    float dot = 0.f;
    for (int e = 0; e < HD; e++) dot = fmaf(qr[e], kr[e], dot);
    lg = dot * SCALE;
  }
  sp[tid] = lg;
  __syncthreads();
  if (tid == 0) {
    float m = sp[0];
    for (int j = 1; j < WWIN; j++) m = fmaxf(m, sp[j]);
    sred[0] = m;
  }
  __syncthreads();
  sp[tid] = expf(sp[tid] - sred[0]);
  __syncthreads();
  if (tid == 0) {
    float s = 0.f;
    for (int j = 0; j < WWIN; j++) s += sp[j];
    sred[1] = s;
  }
  __syncthreads();
  float inv = 1.f / sred[1];
  if (tid < HD) {
    float acc = 0.f;
    for (int j = 0; j < cnt; j++)
      acc = fmaf(sp[j], v[(size_t)(jstart + j) * DIMM + h * HD + tid], acc);
    sout[(size_t)i * DIMM + h * HD + tid] = acc * inv;
  }
}

// ---------- gated combine ----------
__global__ void __launch_bounds__(256)
k_combine(const float* __restrict__ cout, const float* __restrict__ fout,
          const float* __restrict__ sout, const float* __restrict__ gates,
          float* __restrict__ o) {
  int idx = blockIdx.x * 256 + threadIdx.x;   // 0..524287
  int h = (idx >> 6) & 7;
  int n = idx >> 9;
  const float* g = gates + (size_t)n * (NH * 3) + h * 3;
  o[idx] = g[0] * cout[idx] + g[1] * fout[idx] + g[2] * sout[idx];
}

extern "C" void kernel_launch(void* const* d_in, const int* in_sizes, int n_in,
                              void* d_out, int out_size, void* d_ws, size_t ws_size,
                              hipStream_t stream) {
  const float* x     = (const float*)d_in[0];
  const float* ve    = (const float*)d_in[1]; (void)ve;
  const float* x0    = (const float*)d_in[2];
  const float* lam   = (const float*)d_in[3];
  const float* Wq    = (const float*)d_in[4];
  const float* Wk    = (const float*)d_in[5];
  const float* Wv    = (const float*)d_in[6];
  const float* Wo    = (const float*)d_in[7];
  const float* Wg    = (const float*)d_in[8];
  const float* k_pos = (const float*)d_in[9];
  const float* v_pos = (const float*)d_in[10];
  const float* Wck   = (const float*)d_in[11];
  const float* bck   = (const float*)d_in[12];
  const float* Wcv   = (const float*)d_in[13];
  const float* bcv   = (const float*)d_in[14];
  const float* k_mem = (const float*)d_in[15];
  const float* v_mem = (const float*)d_in[16];
  const float* W1    = (const float*)d_in[17];
  const float* W2    = (const float*)d_in[18];
  float* out = (float*)d_out;
  float* ws  = (float*)d_ws;

  const size_t NW = (size_t)NTOK * DIMM;   // 524288
  float* xr    = ws;
  float* xn    = ws + 1 * NW;
  float* q     = ws + 2 * NW;
  float* k     = ws + 3 * NW;
  float* v     = ws + 4 * NW;
  float* coutb = ws + 5 * NW;
  float* foutb = ws + 6 * NW;
  float* soutb = ws + 7 * NW;
  float* x2    = ws + 8 * NW;
  float* gates = ws + 9 * NW;              // 24576 used, 32768 reserved
  float* ckb   = gates + 32768;            // 8*64*64
  float* cvb   = ckb + 32768;
  int*   selb  = (int*)(cvb + 32768);      // 8*1024*8 ints
  float* o  = xn;   // reuse after gates/QKV consumed xn
  float* y  = xr;   // reuse after Wo residual consumed xr
  float* h1 = q;    // reuse: spans q,k,v,coutb (4*NW) after attention done

  k_resid_rms<<<NTOK, 256, 0, stream>>>(x, x0, lam, xr, xn);

  dim3 g512(512 / 64, NTOK / 64);
  k_gemm<<<g512, 256, 0, stream>>>(xn, Wq, nullptr, q, 512, 512, 0);
  k_gemm<<<g512, 256, 0, stream>>>(xn, Wk, nullptr, k, 512, 512, 0);
  k_gemm<<<g512, 256, 0, stream>>>(xn, Wv, nullptr, v, 512, 512, 0);
  k_gates<<<(NTOK * NH * 3 + 255) / 256, 256, 0, stream>>>(xn, Wg, gates);
  k_rope<<<(2 * NTOK * NH * 32) / 256, 256, 0, stream>>>(q, k);

  k_ckcv<<<NH * CBLK, 64, 0, stream>>>(k, v, k_pos, v_pos, Wck, bck, Wcv, bcv,
                                       ckb, cvb);
  dim3 gNH(NTOK, NH);
  k_cmp<<<gNH, 128, 0, stream>>>(q, ckb, cvb, k_mem, v_mem, coutb, selb);
  k_fine<<<gNH, 192, 0, stream>>>(q, k, v, selb, foutb);
  k_swin<<<gNH, 256, 0, stream>>>(q, k, v, soutb);

  k_combine<<<NW / 256, 256, 0, stream>>>(coutb, foutb, soutb, gates, o);
  k_gemm<<<g512, 256, 0, stream>>>(o, Wo, xr, x2, 512, 512, 0);

  k_rms<<<NTOK, 256, 0, stream>>>(x2, y);
  dim3 g2048(2048 / 64, NTOK / 64);
  k_gemm<<<g2048, 256, 0, stream>>>(y, W1, nullptr, h1, 512, 2048, 1);
  k_gemm<<<g512, 256, 0, stream>>>(h1, W2, x2, out, 2048, 512, 0);
}

// Round 3
// 606.499 us; speedup vs baseline: 1.3106x; 1.3106x over previous
//
#include <hip/hip_runtime.h>
#include <math.h>

#define NTOK 1024
#define DIMM 512
#define NH 8
#define HD 64
#define BCB 16
#define BSB 16
#define KSEL 8
#define WWIN 256
#define CBLK 64
#define SCALE 0.125f
#define EPSV 1e-6f
#define NEGV -1e30f

typedef short bf16x8 __attribute__((ext_vector_type(8)));
typedef float f32x4 __attribute__((ext_vector_type(4)));

__device__ inline ushort f2b(float f) {
  union { float f; unsigned int u; } c; c.f = f;
  unsigned int u = c.u;
  return (ushort)((u + 0x7FFFu + ((u >> 16) & 1u)) >> 16);
}
__device__ inline float b2f(ushort h) {
  union { unsigned int u; float f; } c; c.u = ((unsigned int)h) << 16;
  return c.f;
}

// ---------- residual mix + rmsnorm ----------
__global__ void __launch_bounds__(256)
k_resid_rms(const float* __restrict__ x, const float* __restrict__ x0,
            const float* __restrict__ lam, float* __restrict__ xr,
            float* __restrict__ xn) {
  int row = blockIdx.x, tid = threadIdx.x;
  float l0 = lam[0], l1 = lam[1];
  size_t b = (size_t)row * DIMM;
  float a0 = l0 * x[b + tid]       + l1 * x0[b + tid];
  float a1 = l0 * x[b + tid + 256] + l1 * x0[b + tid + 256];
  xr[b + tid] = a0; xr[b + tid + 256] = a1;
  float ss = a0 * a0 + a1 * a1;
  __shared__ float sm[8];
  for (int o = 32; o > 0; o >>= 1) ss += __shfl_down(ss, o);
  int lane = tid & 63, wid = tid >> 6;
  if (lane == 0) sm[wid] = ss;
  __syncthreads();
  if (tid == 0) {
    float s = sm[0] + sm[1] + sm[2] + sm[3];
    sm[0] = rsqrtf(s / (float)DIMM + EPSV);
  }
  __syncthreads();
  float r = sm[0];
  xn[b + tid] = a0 * r; xn[b + tid + 256] = a1 * r;
}

// ---------- plain rmsnorm ----------
__global__ void __launch_bounds__(256)
k_rms(const float* __restrict__ xin, float* __restrict__ y) {
  int row = blockIdx.x, tid = threadIdx.x;
  size_t b = (size_t)row * DIMM;
  float a0 = xin[b + tid], a1 = xin[b + tid + 256];
  float ss = a0 * a0 + a1 * a1;
  __shared__ float sm[8];
  for (int o = 32; o > 0; o >>= 1) ss += __shfl_down(ss, o);
  int lane = tid & 63, wid = tid >> 6;
  if (lane == 0) sm[wid] = ss;
  __syncthreads();
  if (tid == 0) {
    float s = sm[0] + sm[1] + sm[2] + sm[3];
    sm[0] = rsqrtf(s / (float)DIMM + EPSV);
  }
  __syncthreads();
  float r = sm[0];
  y[b + tid] = a0 * r; y[b + tid + 256] = a1 * r;
}

// ---------- weight transpose + bf16 convert: src K×N f32 -> dst N×K bf16 (hi, optional lo) ----------
__global__ void __launch_bounds__(256)
k_wtr(const float* __restrict__ src, ushort* __restrict__ dsth,
      ushort* __restrict__ dstl, int K, int N) {
  __shared__ float t[32][33];
  int n0 = blockIdx.x * 32, k0 = blockIdx.y * 32;
  int tx = threadIdx.x, ty = threadIdx.y;  // 32 x 8
#pragma unroll
  for (int i = 0; i < 32; i += 8)
    t[ty + i][tx] = src[(size_t)(k0 + ty + i) * N + n0 + tx];
  __syncthreads();
#pragma unroll
  for (int i = 0; i < 32; i += 8) {
    float vv = t[tx][ty + i];
    ushort h = f2b(vv);
    size_t di = (size_t)(n0 + ty + i) * K + k0 + tx;
    dsth[di] = h;
    if (dstl) dstl[di] = f2b(vv - b2f(h));
  }
}

// ---------- plain bf16 MFMA GEMM: C = epi(A @ BT^T) (+ Res)
// epi 0: f32 store (+Res) ; epi 1: relu^2
__global__ void __launch_bounds__(256)
k_gemm_bf16(const float* __restrict__ A, const ushort* __restrict__ BT,
            const float* __restrict__ Res, float* __restrict__ Co,
            int Kd, int Nd, int epi) {
  __shared__ ushort As[64 * 40];
  __shared__ ushort Bs[64 * 40];
  int tid = threadIdx.x;
  int lane = tid & 63, wave = tid >> 6;
  int rb = blockIdx.y * 64, cb = blockIdx.x * 64;
  int wm = (wave >> 1) * 32, wn = (wave & 1) * 32;
  int q = lane >> 4, l15 = lane & 15;
  int srow = tid >> 2, scol = (tid & 3) * 8;

  f32x4 acc[2][2];
#pragma unroll
  for (int i = 0; i < 2; i++)
#pragma unroll
    for (int j = 0; j < 2; j++) acc[i][j] = (f32x4){0.f, 0.f, 0.f, 0.f};

  const float*  ap = A  + (size_t)(rb + srow) * Kd + scol;
  const ushort* bp = BT + (size_t)(cb + srow) * Kd + scol;
  ushort* aw = &As[srow * 40 + scol];
  ushort* bw = &Bs[srow * 40 + scol];

  for (int k0 = 0; k0 < Kd; k0 += 32) {
    float4 a0 = *(const float4*)(ap + k0);
    float4 a1 = *(const float4*)(ap + k0 + 4);
    ushort h[8] = {f2b(a0.x), f2b(a0.y), f2b(a0.z), f2b(a0.w),
                   f2b(a1.x), f2b(a1.y), f2b(a1.z), f2b(a1.w)};
    *(int4*)aw = *(int4*)h;
    *(int4*)bw = *(const int4*)(bp + k0);
    __syncthreads();
    bf16x8 af[2], bfr[2];
#pragma unroll
    for (int t = 0; t < 2; t++) {
      af[t]  = *(const bf16x8*)&As[(wm + t * 16 + l15) * 40 + q * 8];
      bfr[t] = *(const bf16x8*)&Bs[(wn + t * 16 + l15) * 40 + q * 8];
    }
#pragma unroll
    for (int i = 0; i < 2; i++)
#pragma unroll
      for (int j = 0; j < 2; j++)
        acc[i][j] = __builtin_amdgcn_mfma_f32_16x16x32_bf16(af[i], bfr[j],
                                                            acc[i][j], 0, 0, 0);
    __syncthreads();
  }

#pragma unroll
  for (int i = 0; i < 2; i++) {
#pragma unroll
    for (int j = 0; j < 2; j++) {
      int col = cb + wn + j * 16 + l15;
#pragma unroll
      for (int r = 0; r < 4; r++) {
        int row = rb + wm + i * 16 + q * 4 + r;
        float vv = acc[i][j][r];
        if (epi == 1) { float t = fmaxf(vv, 0.f); vv = t * t; }
        if (Res) vv += Res[(size_t)row * Nd + col];
        Co[(size_t)row * Nd + col] = vv;
      }
    }
  }
}

// ---------- split-bf16 MFMA GEMM (hi+lo, 3 MFMAs): QKV, split-plane store ----------
__global__ void __launch_bounds__(256)
k_gemm_qkv(const float* __restrict__ A, const ushort* __restrict__ BTh,
           const ushort* __restrict__ BTl, float* __restrict__ Co, int Kd) {
  __shared__ ushort Ash[64 * 40];
  __shared__ ushort Asl[64 * 40];
  __shared__ ushort Bsh[64 * 40];
  __shared__ ushort Bsl[64 * 40];
  int tid = threadIdx.x;
  int lane = tid & 63, wave = tid >> 6;
  int rb = blockIdx.y * 64, cb = blockIdx.x * 64;
  int wm = (wave >> 1) * 32, wn = (wave & 1) * 32;
  int q = lane >> 4, l15 = lane & 15;
  int srow = tid >> 2, scol = (tid & 3) * 8;

  f32x4 acc[2][2];
#pragma unroll
  for (int i = 0; i < 2; i++)
#pragma unroll
    for (int j = 0; j < 2; j++) acc[i][j] = (f32x4){0.f, 0.f, 0.f, 0.f};

  const float*  ap  = A   + (size_t)(rb + srow) * Kd + scol;
  const ushort* bph = BTh + (size_t)(cb + srow) * Kd + scol;
  const ushort* bpl = BTl + (size_t)(cb + srow) * Kd + scol;
  ushort* awh = &Ash[srow * 40 + scol];
  ushort* awl = &Asl[srow * 40 + scol];
  ushort* bwh = &Bsh[srow * 40 + scol];
  ushort* bwl = &Bsl[srow * 40 + scol];

  for (int k0 = 0; k0 < Kd; k0 += 32) {
    float4 a0 = *(const float4*)(ap + k0);
    float4 a1 = *(const float4*)(ap + k0 + 4);
    float va[8] = {a0.x, a0.y, a0.z, a0.w, a1.x, a1.y, a1.z, a1.w};
    ushort hh[8], hl[8];
#pragma unroll
    for (int e = 0; e < 8; e++) {
      hh[e] = f2b(va[e]);
      hl[e] = f2b(va[e] - b2f(hh[e]));
    }
    *(int4*)awh = *(int4*)hh;
    *(int4*)awl = *(int4*)hl;
    *(int4*)bwh = *(const int4*)(bph + k0);
    *(int4*)bwl = *(const int4*)(bpl + k0);
    __syncthreads();
    bf16x8 afh[2], afl[2], bfh[2], bfl[2];
#pragma unroll
    for (int t = 0; t < 2; t++) {
      int ar = (wm + t * 16 + l15) * 40 + q * 8;
      int br = (wn + t * 16 + l15) * 40 + q * 8;
      afh[t] = *(const bf16x8*)&Ash[ar];
      afl[t] = *(const bf16x8*)&Asl[ar];
      bfh[t] = *(const bf16x8*)&Bsh[br];
      bfl[t] = *(const bf16x8*)&Bsl[br];
    }
#pragma unroll
    for (int i = 0; i < 2; i++)
#pragma unroll
      for (int j = 0; j < 2; j++) {
        acc[i][j] = __builtin_amdgcn_mfma_f32_16x16x32_bf16(afh[i], bfh[j],
                                                            acc[i][j], 0, 0, 0);
        acc[i][j] = __builtin_amdgcn_mfma_f32_16x16x32_bf16(afh[i], bfl[j],
                                                            acc[i][j], 0, 0, 0);
        acc[i][j] = __builtin_amdgcn_mfma_f32_16x16x32_bf16(afl[i], bfh[j],
                                                            acc[i][j], 0, 0, 0);
      }
    __syncthreads();
  }

  const size_t NW = (size_t)NTOK * DIMM;
#pragma unroll
  for (int i = 0; i < 2; i++) {
#pragma unroll
    for (int j = 0; j < 2; j++) {
      int col = cb + wn + j * 16 + l15;
#pragma unroll
      for (int r = 0; r < 4; r++) {
        int row = rb + wm + i * 16 + q * 4 + r;
        Co[(size_t)(col >> 9) * NW + (size_t)row * 512 + (col & 511)] =
            acc[i][j][r];
      }
    }
  }
}

// ---------- gates: sigmoid(xn @ Wg), Wg (512,24) ----------
__global__ void __launch_bounds__(256)
k_gates(const float* __restrict__ xn, const float* __restrict__ Wg,
        float* __restrict__ gates) {
  int idx = blockIdx.x * 256 + threadIdx.x;
  if (idx >= NTOK * NH * 3) return;
  int col = idx % (NH * 3), n = idx / (NH * 3);
  float acc = 0.f;
  for (int e = 0; e < DIMM; e++)
    acc = fmaf(xn[(size_t)n * DIMM + e], Wg[(size_t)e * (NH * 3) + col], acc);
  gates[idx] = 1.f / (1.f + expf(-acc));
}

// ---------- RoPE in-place on q and k (layout n x (h*64+d)) ----------
__global__ void __launch_bounds__(256)
k_rope(float* __restrict__ q, float* __restrict__ k) {
  int idx = blockIdx.x * 256 + threadIdx.x;   // 0 .. 2*1024*8*32-1
  int ten = idx >> 18;
  int r = idx & 262143;
  int j = r & 31;
  int h = (r >> 5) & 7;
  int n = r >> 8;
  float* p = ten ? k : q;
  size_t base = (size_t)n * DIMM + h * HD + j;
  float inv = powf(10000.f, -(float)j / 32.f);
  float ang = (float)n * inv;
  float sn, cs;
  sincosf(ang, &sn, &cs);
  float x1 = p[base], x2 = p[base + 32];
  p[base] = x1 * cs - x2 * sn;
  p[base + 32] = x2 * cs + x1 * sn;
}

// ---------- compressed k/v: ck[h,c,:] = (kb flat) @ Wck + bck ----------
__global__ void __launch_bounds__(64)
k_ckcv(const float* __restrict__ k, const float* __restrict__ v,
       const float* __restrict__ k_pos, const float* __restrict__ v_pos,
       const float* __restrict__ Wck, const float* __restrict__ bck,
       const float* __restrict__ Wcv, const float* __restrict__ bcv,
       float* __restrict__ ck, float* __restrict__ cv) {
  int bx = blockIdx.x;
  int h = bx >> 6, c = bx & 63;
  int d = threadIdx.x;
  float ak = bck[d], av = bcv[d];
  for (int t = 0; t < BCB; ++t) {
    const float* krow = k + (size_t)(c * BCB + t) * DIMM + h * HD;
    const float* vrow = v + (size_t)(c * BCB + t) * DIMM + h * HD;
    const float* kp = k_pos + (size_t)(h * BCB + t) * HD;
    const float* vp = v_pos + (size_t)(h * BCB + t) * HD;
    for (int e = 0; e < HD; ++e) {
      float kv = krow[e] + kp[e];
      float vv = vrow[e] + vp[e];
      ak = fmaf(kv, Wck[(size_t)(t * HD + e) * HD + d], ak);
      av = fmaf(vv, Wcv[(size_t)(t * HD + e) * HD + d], av);
    }
  }
  ck[(size_t)(h * CBLK + c) * HD + d] = ak;
  cv[(size_t)(h * CBLK + c) * HD + d] = av;
}

// ---------- compressed attention + top-8 selection ----------
__global__ void __launch_bounds__(128)
k_cmp(const float* __restrict__ q, const float* __restrict__ ck,
      const float* __restrict__ cv, const float* __restrict__ k_mem,
      const float* __restrict__ v_mem, float* __restrict__ cout,
      int* __restrict__ sel) {
  int i = blockIdx.x, h = blockIdx.y, tid = threadIdx.x;
  __shared__ float sp[CBLK + 1];
  __shared__ float sred[2];
  const float* qr = q + (size_t)i * DIMM + h * HD;
  if (tid <= CBLK) {
    const float* kr = (tid == 0) ? (k_mem + h * HD)
                                 : (ck + (size_t)(h * CBLK + tid - 1) * HD);
    float dot = 0.f;
    for (int e = 0; e < HD; e++) dot = fmaf(qr[e], kr[e], dot);
    bool vis = (tid == 0) || (tid * BCB - 1 < i);
    sp[tid] = vis ? dot * SCALE : NEGV;
  }
  __syncthreads();
  if (tid == 0) {
    float m = sp[0];
    for (int j = 1; j <= CBLK; j++) m = fmaxf(m, sp[j]);
    sred[0] = m;
  }
  __syncthreads();
  if (tid <= CBLK) sp[tid] = expf(sp[tid] - sred[0]);
  __syncthreads();
  if (tid == 0) {
    float s = 0.f;
    for (int j = 0; j <= CBLK; j++) s += sp[j];
    sred[1] = s;
  }
  __syncthreads();
  float inv = 1.f / sred[1];
  if (tid < HD) {
    float acc = sp[0] * v_mem[h * HD + tid];
    for (int j = 1; j <= CBLK; j++)
      acc = fmaf(sp[j], cv[(size_t)(h * CBLK + j - 1) * HD + tid], acc);
    cout[(size_t)i * DIMM + h * HD + tid] = acc * inv;
  }
  if (tid == 0) {
    unsigned long long used = 0ULL;
    int base = (h * NTOK + i) * KSEL;
    for (int kk = 0; kk < KSEL; ++kk) {
      float bv = -INFINITY; int bc = 0;
      for (int c = 0; c < CBLK; c++) {
        if ((used >> c) & 1ULL) continue;
        float imp = (c * BCB + BCB - 1 < i) ? sp[c + 1] : NEGV;
        if (imp > bv) { bv = imp; bc = c; }
      }
      used |= 1ULL << bc;
      sel[base + kk] = (bv >= 0.f) ? bc : -1;
    }
  }
}

// ---------- fine attention over 8 selected blocks + own block ----------
__global__ void __launch_bounds__(192)
k_fine(const float* __restrict__ q, const float* __restrict__ k,
       const float* __restrict__ v, const int* __restrict__ sel,
       float* __restrict__ fout) {
  int i = blockIdx.x, h = blockIdx.y, tid = threadIdx.x;
  const int NL = (KSEL + 1) * BSB;   // 144
  __shared__ float sp[(KSEL + 1) * BSB];
  __shared__ int srow[(KSEL + 1) * BSB];
  __shared__ float sred[2];
  const float* qr = q + (size_t)i * DIMM + h * HD;
  int own = i >> 4;
  if (tid < NL) {
    int kk = tid >> 4, s = tid & 15;
    int bidx; bool vis;
    if (kk < KSEL) {
      bidx = sel[(h * NTOK + i) * KSEL + kk];
      vis = (bidx >= 0);
      if (!vis) bidx = 0;
    } else {
      bidx = own;
      vis = (s <= (i & 15));
    }
    int row = bidx * BSB + s;
    const float* kr = k + (size_t)row * DIMM + h * HD;
    float dot = 0.f;
    for (int e = 0; e < HD; e++) dot = fmaf(qr[e], kr[e], dot);
    sp[tid] = vis ? dot * SCALE : NEGV;
    srow[tid] = row;
  }
  __syncthreads();
  if (tid == 0) {
    float m = sp[0];
    for (int j = 1; j < NL; j++) m = fmaxf(m, sp[j]);
    sred[0] = m;
  }
  __syncthreads();
  if (tid < NL) sp[tid] = expf(sp[tid] - sred[0]);
  __syncthreads();
  if (tid == 0) {
    float s = 0.f;
    for (int j = 0; j < NL; j++) s += sp[j];
    sred[1] = s;
  }
  __syncthreads();
  float inv = 1.f / sred[1];
  if (tid < HD) {
    float acc = 0.f;
    for (int j = 0; j < NL; j++)
      acc = fmaf(sp[j], v[(size_t)srow[j] * DIMM + h * HD + tid], acc);
    fout[(size_t)i * DIMM + h * HD + tid] = acc * inv;
  }
}

// ---------- sliding window attention (window 256) ----------
__global__ void __launch_bounds__(256)
k_swin(const float* __restrict__ q, const float* __restrict__ k,
       const float* __restrict__ v, float* __restrict__ sout) {
  int i = blockIdx.x, h = blockIdx.y, tid = threadIdx.x;
  __shared__ float sp[WWIN];
  __shared__ float sred[2];
  int jstart = (i >= WWIN) ? (i - WWIN + 1) : 0;
  int cnt = i - jstart + 1;
  const float* qr = q + (size_t)i * DIMM + h * HD;
  float lg = NEGV;
  if (tid < cnt) {
    const float* kr = k + (size_t)(jstart + tid) * DIMM + h * HD;
    float dot = 0.f;
    for (int e = 0; e < HD; e++) dot = fmaf(qr[e], kr[e], dot);
    lg = dot * SCALE;
  }
  sp[tid] = lg;
  __syncthreads();
  if (tid == 0) {
    float m = sp[0];
    for (int j = 1; j < WWIN; j++) m = fmaxf(m, sp[j]);
    sred[0] = m;
  }
  __syncthreads();
  sp[tid] = expf(sp[tid] - sred[0]);
  __syncthreads();
  if (tid == 0) {
    float s = 0.f;
    for (int j = 0; j < WWIN; j++) s += sp[j];
    sred[1] = s;
  }
  __syncthreads();
  float inv = 1.f / sred[1];
  if (tid < HD) {
    float acc = 0.f;
    for (int j = 0; j < cnt; j++)
      acc = fmaf(sp[j], v[(size_t)(jstart + j) * DIMM + h * HD + tid], acc);
    sout[(size_t)i * DIMM + h * HD + tid] = acc * inv;
  }
}

// ---------- gated combine ----------
__global__ void __launch_bounds__(256)
k_combine(const float* __restrict__ cout, const float* __restrict__ fout,
          const float* __restrict__ sout, const float* __restrict__ gates,
          float* __restrict__ o) {
  int idx = blockIdx.x * 256 + threadIdx.x;
  int h = (idx >> 6) & 7;
  int n = idx >> 9;
  const float* g = gates + (size_t)n * (NH * 3) + h * 3;
  o[idx] = g[0] * cout[idx] + g[1] * fout[idx] + g[2] * sout[idx];
}

extern "C" void kernel_launch(void* const* d_in, const int* in_sizes, int n_in,
                              void* d_out, int out_size, void* d_ws, size_t ws_size,
                              hipStream_t stream) {
  const float* x     = (const float*)d_in[0];
  const float* ve    = (const float*)d_in[1]; (void)ve;
  const float* x0    = (const float*)d_in[2];
  const float* lam   = (const float*)d_in[3];
  const float* Wq    = (const float*)d_in[4];
  const float* Wk    = (const float*)d_in[5];
  const float* Wv    = (const float*)d_in[6];
  const float* Wo    = (const float*)d_in[7];
  const float* Wg    = (const float*)d_in[8];
  const float* k_pos = (const float*)d_in[9];
  const float* v_pos = (const float*)d_in[10];
  const float* Wck   = (const float*)d_in[11];
  const float* bck   = (const float*)d_in[12];
  const float* Wcv   = (const float*)d_in[13];
  const float* bcv   = (const float*)d_in[14];
  const float* k_mem = (const float*)d_in[15];
  const float* v_mem = (const float*)d_in[16];
  const float* W1    = (const float*)d_in[17];
  const float* W2    = (const float*)d_in[18];
  float* out = (float*)d_out;
  float* ws  = (float*)d_ws;

  const size_t NW = (size_t)NTOK * DIMM;   // 524288
  float* xr    = ws;
  float* xn    = ws + 1 * NW;
  float* q     = ws + 2 * NW;
  float* k     = ws + 3 * NW;
  float* v     = ws + 4 * NW;
  float* coutb = ws + 5 * NW;
  float* foutb = ws + 6 * NW;
  float* soutb = ws + 7 * NW;
  float* x2    = ws + 8 * NW;
  float* gates = ws + 9 * NW;               // 24576 used
  float* ckb   = gates + 32768;
  float* cvb   = ckb + 32768;
  int*   selb  = (int*)(cvb + 32768);       // 65536 ints
  ushort* qkvTh = (ushort*)(cvb + 32768 + 65536);  // 1536*512
  ushort* qkvTl = qkvTh + 1536 * 512;              // 1536*512
  ushort* WoT   = qkvTl + 1536 * 512;              // 512*512
  ushort* W1T   = WoT   + 512 * 512;               // 2048*512
  ushort* W2T   = W1T   + 2048 * 512;              // 512*2048
  float* o  = v;    // reuse after swin consumed v
  float* y  = xr;   // reuse after Wo residual consumed xr
  float* h1 = q;    // f32 1024x2048, spans q..coutb after attention done

  // weight transposes (f32 -> bf16 hi[/lo], N x K)
  dim3 tb(32, 8);
  k_wtr<<<dim3(16, 16), tb, 0, stream>>>(Wq, qkvTh,              qkvTl,              512, 512);
  k_wtr<<<dim3(16, 16), tb, 0, stream>>>(Wk, qkvTh + 512 * 512,  qkvTl + 512 * 512,  512, 512);
  k_wtr<<<dim3(16, 16), tb, 0, stream>>>(Wv, qkvTh + 1024 * 512, qkvTl + 1024 * 512, 512, 512);
  k_wtr<<<dim3(16, 16), tb, 0, stream>>>(Wo, WoT, nullptr,  512, 512);
  k_wtr<<<dim3(64, 16), tb, 0, stream>>>(W1, W1T, nullptr,  512, 2048);
  k_wtr<<<dim3(16, 64), tb, 0, stream>>>(W2, W2T, nullptr, 2048, 512);

  k_resid_rms<<<NTOK, 256, 0, stream>>>(x, x0, lam, xr, xn);

  // fused QKV (split precision): A=xn, BT=qkvT hi/lo -> q,k,v planes
  k_gemm_qkv<<<dim3(1536 / 64, NTOK / 64), 256, 0, stream>>>(
      xn, qkvTh, qkvTl, q, 512);
  k_gates<<<(NTOK * NH * 3 + 255) / 256, 256, 0, stream>>>(xn, Wg, gates);
  k_rope<<<(2 * NTOK * NH * 32) / 256, 256, 0, stream>>>(q, k);

  k_ckcv<<<NH * CBLK, 64, 0, stream>>>(k, v, k_pos, v_pos, Wck, bck, Wcv, bcv,
                                       ckb, cvb);
  dim3 gNH(NTOK, NH);
  k_cmp<<<gNH, 128, 0, stream>>>(q, ckb, cvb, k_mem, v_mem, coutb, selb);
  k_fine<<<gNH, 192, 0, stream>>>(q, k, v, selb, foutb);
  k_swin<<<gNH, 256, 0, stream>>>(q, k, v, soutb);

  k_combine<<<NW / 256, 256, 0, stream>>>(coutb, foutb, soutb, gates, o);
  k_gemm_bf16<<<dim3(512 / 64, NTOK / 64), 256, 0, stream>>>(
      o, WoT, xr, x2, 512, 512, 0);

  k_rms<<<NTOK, 256, 0, stream>>>(x2, y);
  k_gemm_bf16<<<dim3(2048 / 64, NTOK / 64), 256, 0, stream>>>(
      y, W1T, nullptr, h1, 512, 2048, 1);
  k_gemm_bf16<<<dim3(512 / 64, NTOK / 64), 256, 0, stream>>>(
      h1, W2T, x2, out, 2048, 512, 0);
}

// Round 4
// 461.876 us; speedup vs baseline: 1.7209x; 1.3131x over previous
//
#include <hip/hip_runtime.h>
#include <math.h>

#define NTOK 1024
#define DIMM 512
#define NH 8
#define HD 64
#define BCB 16
#define BSB 16
#define KSEL 8
#define WWIN 256
#define CBLK 64
#define SCALE 0.125f
#define EPSV 1e-6f
#define NEGV -1e30f

typedef short bf16x8 __attribute__((ext_vector_type(8)));
typedef float f32x4 __attribute__((ext_vector_type(4)));

__device__ inline ushort f2b(float f) {
  union { float f; unsigned int u; } c; c.f = f;
  unsigned int u = c.u;
  return (ushort)((u + 0x7FFFu + ((u >> 16) & 1u)) >> 16);
}
__device__ inline float b2f(ushort h) {
  union { unsigned int u; float f; } c; c.u = ((unsigned int)h) << 16;
  return c.f;
}

__device__ inline float wred_max(float v) {
#pragma unroll
  for (int off = 1; off < 64; off <<= 1) v = fmaxf(v, __shfl_xor(v, off));
  return v;
}
__device__ inline float wred_sum(float v) {
#pragma unroll
  for (int off = 1; off < 64; off <<= 1) v += __shfl_xor(v, off);
  return v;
}

// ---------- residual mix + rmsnorm ----------
__global__ void __launch_bounds__(256)
k_resid_rms(const float* __restrict__ x, const float* __restrict__ x0,
            const float* __restrict__ lam, float* __restrict__ xr,
            float* __restrict__ xn) {
  int row = blockIdx.x, tid = threadIdx.x;
  float l0 = lam[0], l1 = lam[1];
  size_t b = (size_t)row * DIMM;
  float a0 = l0 * x[b + tid]       + l1 * x0[b + tid];
  float a1 = l0 * x[b + tid + 256] + l1 * x0[b + tid + 256];
  xr[b + tid] = a0; xr[b + tid + 256] = a1;
  float ss = a0 * a0 + a1 * a1;
  __shared__ float sm[8];
  for (int o = 32; o > 0; o >>= 1) ss += __shfl_down(ss, o);
  int lane = tid & 63, wid = tid >> 6;
  if (lane == 0) sm[wid] = ss;
  __syncthreads();
  if (tid == 0) {
    float s = sm[0] + sm[1] + sm[2] + sm[3];
    sm[0] = rsqrtf(s / (float)DIMM + EPSV);
  }
  __syncthreads();
  float r = sm[0];
  xn[b + tid] = a0 * r; xn[b + tid + 256] = a1 * r;
}

// ---------- plain rmsnorm ----------
__global__ void __launch_bounds__(256)
k_rms(const float* __restrict__ xin, float* __restrict__ y) {
  int row = blockIdx.x, tid = threadIdx.x;
  size_t b = (size_t)row * DIMM;
  float a0 = xin[b + tid], a1 = xin[b + tid + 256];
  float ss = a0 * a0 + a1 * a1;
  __shared__ float sm[8];
  for (int o = 32; o > 0; o >>= 1) ss += __shfl_down(ss, o);
  int lane = tid & 63, wid = tid >> 6;
  if (lane == 0) sm[wid] = ss;
  __syncthreads();
  if (tid == 0) {
    float s = sm[0] + sm[1] + sm[2] + sm[3];
    sm[0] = rsqrtf(s / (float)DIMM + EPSV);
  }
  __syncthreads();
  float r = sm[0];
  y[b + tid] = a0 * r; y[b + tid + 256] = a1 * r;
}

// ---------- weight transpose + bf16 convert ----------
__global__ void __launch_bounds__(256)
k_wtr(const float* __restrict__ src, ushort* __restrict__ dsth,
      ushort* __restrict__ dstl, int K, int N) {
  __shared__ float t[32][33];
  int n0 = blockIdx.x * 32, k0 = blockIdx.y * 32;
  int tx = threadIdx.x, ty = threadIdx.y;  // 32 x 8
#pragma unroll
  for (int i = 0; i < 32; i += 8)
    t[ty + i][tx] = src[(size_t)(k0 + ty + i) * N + n0 + tx];
  __syncthreads();
#pragma unroll
  for (int i = 0; i < 32; i += 8) {
    float vv = t[tx][ty + i];
    ushort h = f2b(vv);
    size_t di = (size_t)(n0 + ty + i) * K + k0 + tx;
    dsth[di] = h;
    if (dstl) dstl[di] = f2b(vv - b2f(h));
  }
}

// ---------- plain bf16 MFMA GEMM ----------
__global__ void __launch_bounds__(256)
k_gemm_bf16(const float* __restrict__ A, const ushort* __restrict__ BT,
            const float* __restrict__ Res, float* __restrict__ Co,
            int Kd, int Nd, int epi) {
  __shared__ ushort As[64 * 40];
  __shared__ ushort Bs[64 * 40];
  int tid = threadIdx.x;
  int lane = tid & 63, wave = tid >> 6;
  int rb = blockIdx.y * 64, cb = blockIdx.x * 64;
  int wm = (wave >> 1) * 32, wn = (wave & 1) * 32;
  int q = lane >> 4, l15 = lane & 15;
  int srow = tid >> 2, scol = (tid & 3) * 8;

  f32x4 acc[2][2];
#pragma unroll
  for (int i = 0; i < 2; i++)
#pragma unroll
    for (int j = 0; j < 2; j++) acc[i][j] = (f32x4){0.f, 0.f, 0.f, 0.f};

  const float*  ap = A  + (size_t)(rb + srow) * Kd + scol;
  const ushort* bp = BT + (size_t)(cb + srow) * Kd + scol;
  ushort* aw = &As[srow * 40 + scol];
  ushort* bw = &Bs[srow * 40 + scol];

  for (int k0 = 0; k0 < Kd; k0 += 32) {
    float4 a0 = *(const float4*)(ap + k0);
    float4 a1 = *(const float4*)(ap + k0 + 4);
    ushort h[8] = {f2b(a0.x), f2b(a0.y), f2b(a0.z), f2b(a0.w),
                   f2b(a1.x), f2b(a1.y), f2b(a1.z), f2b(a1.w)};
    *(int4*)aw = *(int4*)h;
    *(int4*)bw = *(const int4*)(bp + k0);
    __syncthreads();
    bf16x8 af[2], bfr[2];
#pragma unroll
    for (int t = 0; t < 2; t++) {
      af[t]  = *(const bf16x8*)&As[(wm + t * 16 + l15) * 40 + q * 8];
      bfr[t] = *(const bf16x8*)&Bs[(wn + t * 16 + l15) * 40 + q * 8];
    }
#pragma unroll
    for (int i = 0; i < 2; i++)
#pragma unroll
      for (int j = 0; j < 2; j++)
        acc[i][j] = __builtin_amdgcn_mfma_f32_16x16x32_bf16(af[i], bfr[j],
                                                            acc[i][j], 0, 0, 0);
    __syncthreads();
  }

#pragma unroll
  for (int i = 0; i < 2; i++) {
#pragma unroll
    for (int j = 0; j < 2; j++) {
      int col = cb + wn + j * 16 + l15;
#pragma unroll
      for (int r = 0; r < 4; r++) {
        int row = rb + wm + i * 16 + q * 4 + r;
        float vv = acc[i][j][r];
        if (epi == 1) { float t = fmaxf(vv, 0.f); vv = t * t; }
        if (Res) vv += Res[(size_t)row * Nd + col];
        Co[(size_t)row * Nd + col] = vv;
      }
    }
  }
}

// ---------- split-bf16 MFMA GEMM (hi+lo): QKV, split-plane store ----------
__global__ void __launch_bounds__(256)
k_gemm_qkv(const float* __restrict__ A, const ushort* __restrict__ BTh,
           const ushort* __restrict__ BTl, float* __restrict__ Co, int Kd) {
  __shared__ ushort Ash[64 * 40];
  __shared__ ushort Asl[64 * 40];
  __shared__ ushort Bsh[64 * 40];
  __shared__ ushort Bsl[64 * 40];
  int tid = threadIdx.x;
  int lane = tid & 63, wave = tid >> 6;
  int rb = blockIdx.y * 64, cb = blockIdx.x * 64;
  int wm = (wave >> 1) * 32, wn = (wave & 1) * 32;
  int q = lane >> 4, l15 = lane & 15;
  int srow = tid >> 2, scol = (tid & 3) * 8;

  f32x4 acc[2][2];
#pragma unroll
  for (int i = 0; i < 2; i++)
#pragma unroll
    for (int j = 0; j < 2; j++) acc[i][j] = (f32x4){0.f, 0.f, 0.f, 0.f};

  const float*  ap  = A   + (size_t)(rb + srow) * Kd + scol;
  const ushort* bph = BTh + (size_t)(cb + srow) * Kd + scol;
  const ushort* bpl = BTl + (size_t)(cb + srow) * Kd + scol;
  ushort* awh = &Ash[srow * 40 + scol];
  ushort* awl = &Asl[srow * 40 + scol];
  ushort* bwh = &Bsh[srow * 40 + scol];
  ushort* bwl = &Bsl[srow * 40 + scol];

  for (int k0 = 0; k0 < Kd; k0 += 32) {
    float4 a0 = *(const float4*)(ap + k0);
    float4 a1 = *(const float4*)(ap + k0 + 4);
    float va[8] = {a0.x, a0.y, a0.z, a0.w, a1.x, a1.y, a1.z, a1.w};
    ushort hh[8], hl[8];
#pragma unroll
    for (int e = 0; e < 8; e++) {
      hh[e] = f2b(va[e]);
      hl[e] = f2b(va[e] - b2f(hh[e]));
    }
    *(int4*)awh = *(int4*)hh;
    *(int4*)awl = *(int4*)hl;
    *(int4*)bwh = *(const int4*)(bph + k0);
    *(int4*)bwl = *(const int4*)(bpl + k0);
    __syncthreads();
    bf16x8 afh[2], afl[2], bfh[2], bfl[2];
#pragma unroll
    for (int t = 0; t < 2; t++) {
      int ar = (wm + t * 16 + l15) * 40 + q * 8;
      int br = (wn + t * 16 + l15) * 40 + q * 8;
      afh[t] = *(const bf16x8*)&Ash[ar];
      afl[t] = *(const bf16x8*)&Asl[ar];
      bfh[t] = *(const bf16x8*)&Bsh[br];
      bfl[t] = *(const bf16x8*)&Bsl[br];
    }
#pragma unroll
    for (int i = 0; i < 2; i++)
#pragma unroll
      for (int j = 0; j < 2; j++) {
        acc[i][j] = __builtin_amdgcn_mfma_f32_16x16x32_bf16(afh[i], bfh[j],
                                                            acc[i][j], 0, 0, 0);
        acc[i][j] = __builtin_amdgcn_mfma_f32_16x16x32_bf16(afh[i], bfl[j],
                                                            acc[i][j], 0, 0, 0);
        acc[i][j] = __builtin_amdgcn_mfma_f32_16x16x32_bf16(afl[i], bfh[j],
                                                            acc[i][j], 0, 0, 0);
      }
    __syncthreads();
  }

  const size_t NW = (size_t)NTOK * DIMM;
#pragma unroll
  for (int i = 0; i < 2; i++) {
#pragma unroll
    for (int j = 0; j < 2; j++) {
      int col = cb + wn + j * 16 + l15;
#pragma unroll
      for (int r = 0; r < 4; r++) {
        int row = rb + wm + i * 16 + q * 4 + r;
        Co[(size_t)(col >> 9) * NW + (size_t)row * 512 + (col & 511)] =
            acc[i][j][r];
      }
    }
  }
}

// ---------- gates ----------
__global__ void __launch_bounds__(256)
k_gates(const float* __restrict__ xn, const float* __restrict__ Wg,
        float* __restrict__ gates) {
  int idx = blockIdx.x * 256 + threadIdx.x;
  if (idx >= NTOK * NH * 3) return;
  int col = idx % (NH * 3), n = idx / (NH * 3);
  float acc = 0.f;
  for (int e = 0; e < DIMM; e++)
    acc = fmaf(xn[(size_t)n * DIMM + e], Wg[(size_t)e * (NH * 3) + col], acc);
  gates[idx] = 1.f / (1.f + expf(-acc));
}

// ---------- RoPE in-place ----------
__global__ void __launch_bounds__(256)
k_rope(float* __restrict__ q, float* __restrict__ k) {
  int idx = blockIdx.x * 256 + threadIdx.x;
  int ten = idx >> 18;
  int r = idx & 262143;
  int j = r & 31;
  int h = (r >> 5) & 7;
  int n = r >> 8;
  float* p = ten ? k : q;
  size_t base = (size_t)n * DIMM + h * HD + j;
  float inv = powf(10000.f, -(float)j / 32.f);
  float ang = (float)n * inv;
  float sn, cs;
  sincosf(ang, &sn, &cs);
  float x1 = p[base], x2 = p[base + 32];
  p[base] = x1 * cs - x2 * sn;
  p[base + 32] = x2 * cs + x1 * sn;
}

// ---------- compressed k/v ----------
__global__ void __launch_bounds__(64)
k_ckcv(const float* __restrict__ k, const float* __restrict__ v,
       const float* __restrict__ k_pos, const float* __restrict__ v_pos,
       const float* __restrict__ Wck, const float* __restrict__ bck,
       const float* __restrict__ Wcv, const float* __restrict__ bcv,
       float* __restrict__ ck, float* __restrict__ cv) {
  int bx = blockIdx.x;
  int h = bx >> 6, c = bx & 63;
  int d = threadIdx.x;
  float ak = bck[d], av = bcv[d];
  for (int t = 0; t < BCB; ++t) {
    const float* krow = k + (size_t)(c * BCB + t) * DIMM + h * HD;
    const float* vrow = v + (size_t)(c * BCB + t) * DIMM + h * HD;
    const float* kp = k_pos + (size_t)(h * BCB + t) * HD;
    const float* vp = v_pos + (size_t)(h * BCB + t) * HD;
    for (int e = 0; e < HD; ++e) {
      float kv = krow[e] + kp[e];
      float vv = vrow[e] + vp[e];
      ak = fmaf(kv, Wck[(size_t)(t * HD + e) * HD + d], ak);
      av = fmaf(vv, Wcv[(size_t)(t * HD + e) * HD + d], av);
    }
  }
  ck[(size_t)(h * CBLK + c) * HD + d] = ak;
  cv[(size_t)(h * CBLK + c) * HD + d] = av;
}

// ---------- compressed attention + top-8: block = (h, 16 q rows), 4 waves ----------
__global__ void __launch_bounds__(256)
k_cmp(const float* __restrict__ qg, const float* __restrict__ ckb,
      const float* __restrict__ cvb, const float* __restrict__ k_mem,
      const float* __restrict__ v_mem, float* __restrict__ cout,
      int* __restrict__ sel) {
  int h = blockIdx.y, i0 = blockIdx.x * 16;
  int tid = threadIdx.x, lane = tid & 63, w = tid >> 6;
  __shared__ float ckt[64][65];   // transposed: ckt[e][c]
  __shared__ float cvs[64][65];   // row-major: cvs[c][d]
  __shared__ float qs[16][64];
  __shared__ float kms[64], vms[64];
  __shared__ float sp[4][64];

  // stage ck (transposed) + cv (row-major)
#pragma unroll
  for (int r = 0; r < 4; r++) {
    int f = r * 256 + tid;           // float4 idx in [0,1024)
    int c = f >> 4, d0 = (f & 15) * 4;
    float4 t = *(const float4*)(ckb + ((size_t)h * 64 + c) * 64 + d0);
    ckt[d0][c] = t.x; ckt[d0 + 1][c] = t.y; ckt[d0 + 2][c] = t.z; ckt[d0 + 3][c] = t.w;
    float4 u = *(const float4*)(cvb + ((size_t)h * 64 + c) * 64 + d0);
    cvs[c][d0] = u.x; cvs[c][d0 + 1] = u.y; cvs[c][d0 + 2] = u.z; cvs[c][d0 + 3] = u.w;
  }
  { // q rows
    int r = tid >> 4, d0 = (tid & 15) * 4;
    float4 t = *(const float4*)(qg + (size_t)(i0 + r) * DIMM + h * HD + d0);
    qs[r][d0] = t.x; qs[r][d0 + 1] = t.y; qs[r][d0 + 2] = t.z; qs[r][d0 + 3] = t.w;
  }
  if (tid < 64) kms[tid] = k_mem[h * HD + tid];
  else if (tid < 128) vms[tid - 64] = v_mem[h * HD + tid - 64];
  __syncthreads();

  for (int s = 0; s < 4; s++) {
    int ql = w * 4 + s, qi = i0 + ql;
    float dot = 0.f, dm = 0.f;
#pragma unroll 8
    for (int e = 0; e < 64; e++) {
      float qe = qs[ql][e];
      dot = fmaf(qe, ckt[e][lane], dot);
      dm  = fmaf(qe, kms[e], dm);
    }
    bool vis = (lane * BCB + BCB - 1) < qi;
    float sj = vis ? dot * SCALE : NEGV;
    float smem = dm * SCALE;
    float m = wred_max(fmaxf(sj, smem));
    float p = expf(sj - m);                 // invisible -> exp(-huge) = 0
    float pmem = expf(smem - m);
    float l = wred_sum(p) + pmem;
    float inv = 1.f / l;

    // top-8 wave argmax (tie -> smallest index)
    float impv = vis ? p : NEGV;
#pragma unroll
    for (int kk = 0; kk < KSEL; kk++) {
      float bv = impv; int bi = lane;
#pragma unroll
      for (int off = 32; off > 0; off >>= 1) {
        float ov = __shfl_xor(bv, off);
        int   oi = __shfl_xor(bi, off);
        if (ov > bv || (ov == bv && oi < bi)) { bv = ov; bi = oi; }
      }
      if (lane == 0) sel[((size_t)h * NTOK + qi) * KSEL + kk] = (bv >= 0.f) ? bi : -1;
      if (lane == bi) impv = NEGV;
    }

    sp[w][lane] = p;
    __syncthreads();
    float od = pmem * vms[lane];
#pragma unroll 8
    for (int j = 0; j < 64; j++) od = fmaf(sp[w][j], cvs[j][lane], od);
    cout[(size_t)qi * DIMM + h * HD + lane] = od * inv;
    __syncthreads();
  }
}

// ---------- sliding window: block = (h, 16 q rows), online softmax over 64-key tiles ----------
__global__ void __launch_bounds__(256)
k_swin(const float* __restrict__ qg, const float* __restrict__ kg,
       const float* __restrict__ vg, float* __restrict__ sout) {
  int h = blockIdx.y, i0 = blockIdx.x * 16;
  int tid = threadIdx.x, lane = tid & 63, w = tid >> 6;
  __shared__ float kt[64][65];   // transposed
  __shared__ float vs[64][65];   // row-major
  __shared__ float qs[16][64];
  __shared__ float sp[4][64];

  { // q rows
    int r = tid >> 4, d0 = (tid & 15) * 4;
    float4 t = *(const float4*)(qg + (size_t)(i0 + r) * DIMM + h * HD + d0);
    qs[r][d0] = t.x; qs[r][d0 + 1] = t.y; qs[r][d0 + 2] = t.z; qs[r][d0 + 3] = t.w;
  }

  int lo = i0 - (WWIN - 1); if (lo < 0) lo = 0;
  int jb_lo = lo >> 6, jb_hi = (i0 + 15) >> 6;

  float mrow[4], lrow[4], orow[4];
#pragma unroll
  for (int s = 0; s < 4; s++) { mrow[s] = NEGV; lrow[s] = 0.f; orow[s] = 0.f; }

  for (int jb = jb_lo; jb <= jb_hi; jb++) {
    __syncthreads();
#pragma unroll
    for (int r = 0; r < 4; r++) {
      int f = r * 256 + tid;
      int c = f >> 4, d0 = (f & 15) * 4;
      float4 t = *(const float4*)(kg + (size_t)(jb * 64 + c) * DIMM + h * HD + d0);
      kt[d0][c] = t.x; kt[d0 + 1][c] = t.y; kt[d0 + 2][c] = t.z; kt[d0 + 3][c] = t.w;
      float4 u = *(const float4*)(vg + (size_t)(jb * 64 + c) * DIMM + h * HD + d0);
      vs[c][d0] = u.x; vs[c][d0 + 1] = u.y; vs[c][d0 + 2] = u.z; vs[c][d0 + 3] = u.w;
    }
    __syncthreads();

    for (int s = 0; s < 4; s++) {
      int ql = w * 4 + s, qi = i0 + ql;
      float dot = 0.f;
#pragma unroll 8
      for (int e = 0; e < 64; e++) dot = fmaf(qs[ql][e], kt[e][lane], dot);
      int gj = jb * 64 + lane;
      bool vis = (gj <= qi) && (qi - gj < WWIN);
      float sj = vis ? dot * SCALE : NEGV;
      float tm = wred_max(sj);
      float newm = fmaxf(mrow[s], tm);
      float p = vis ? expf(sj - newm) : 0.f;
      float ts = wred_sum(p);
      float alpha = expf(mrow[s] - newm);
      sp[w][lane] = p;
      __syncthreads();
      float acc = 0.f;
#pragma unroll 8
      for (int j = 0; j < 64; j++) acc = fmaf(sp[w][j], vs[j][lane], acc);
      orow[s] = orow[s] * alpha + acc;
      lrow[s] = lrow[s] * alpha + ts;
      mrow[s] = newm;
      __syncthreads();
    }
  }
#pragma unroll
  for (int s = 0; s < 4; s++) {
    int qi = i0 + w * 4 + s;
    sout[(size_t)qi * DIMM + h * HD + lane] = orow[s] / lrow[s];
  }
}

// ---------- fine attention: one wave per (h,i) ----------
__global__ void __launch_bounds__(64)
k_fine(const float* __restrict__ qg, const float* __restrict__ kg,
       const float* __restrict__ vg, const int* __restrict__ sel,
       float* __restrict__ fout) {
  int i = blockIdx.x, h = blockIdx.y, lane = threadIdx.x;
  __shared__ float qsh[64];
  __shared__ float spf[144];
  __shared__ int srow[144];

  qsh[lane] = qg[(size_t)i * DIMM + h * HD + lane];
  __syncthreads();

  int own = i >> 4;
  float s[3];
  int rows[3];
#pragma unroll
  for (int g = 0; g < 3; g++) {
    int key = g * 64 + lane;
    int bidx; bool vis;
    if (g < 2) {
      int kk = key >> 4;
      bidx = sel[((size_t)h * NTOK + i) * KSEL + kk];
      vis = (bidx >= 0);
      if (!vis) bidx = 0;
    } else {
      bidx = own;
      vis = (lane < 16) && ((key & 15) <= (i & 15));
    }
    int row = bidx * BSB + (key & 15);
    rows[g] = row;
    const float* kr = kg + (size_t)row * DIMM + h * HD;
    float dot = 0.f;
#pragma unroll
    for (int e4 = 0; e4 < 16; e4++) {
      float4 kv = *(const float4*)(kr + e4 * 4);
      float4 qv = *(const float4*)&qsh[e4 * 4];
      dot = fmaf(qv.x, kv.x, dot); dot = fmaf(qv.y, kv.y, dot);
      dot = fmaf(qv.z, kv.z, dot); dot = fmaf(qv.w, kv.w, dot);
    }
    s[g] = vis ? dot * SCALE : NEGV;
  }
  float m = fmaxf(s[0], s[1]);
  if (lane < 16) m = fmaxf(m, s[2]);
  m = wred_max(m);
  float p0 = expf(s[0] - m), p1 = expf(s[1] - m);
  float p2 = (lane < 16) ? expf(s[2] - m) : 0.f;
  float l = wred_sum(p0 + p1 + p2);

  spf[lane] = p0; spf[64 + lane] = p1;
  srow[lane] = rows[0]; srow[64 + lane] = rows[1];
  if (lane < 16) { spf[128 + lane] = p2; srow[128 + lane] = rows[2]; }
  __syncthreads();

  float acc = 0.f;
  for (int j = 0; j < 144; j++)
    acc = fmaf(spf[j], vg[(size_t)srow[j] * DIMM + h * HD + lane], acc);
  fout[(size_t)i * DIMM + h * HD + lane] = acc / l;
}

// ---------- gated combine ----------
__global__ void __launch_bounds__(256)
k_combine(const float* __restrict__ cout, const float* __restrict__ fout,
          const float* __restrict__ sout, const float* __restrict__ gates,
          float* __restrict__ o) {
  int idx = blockIdx.x * 256 + threadIdx.x;
  int h = (idx >> 6) & 7;
  int n = idx >> 9;
  const float* g = gates + (size_t)n * (NH * 3) + h * 3;
  o[idx] = g[0] * cout[idx] + g[1] * fout[idx] + g[2] * sout[idx];
}

extern "C" void kernel_launch(void* const* d_in, const int* in_sizes, int n_in,
                              void* d_out, int out_size, void* d_ws, size_t ws_size,
                              hipStream_t stream) {
  const float* x     = (const float*)d_in[0];
  const float* ve    = (const float*)d_in[1]; (void)ve;
  const float* x0    = (const float*)d_in[2];
  const float* lam   = (const float*)d_in[3];
  const float* Wq    = (const float*)d_in[4];
  const float* Wk    = (const float*)d_in[5];
  const float* Wv    = (const float*)d_in[6];
  const float* Wo    = (const float*)d_in[7];
  const float* Wg    = (const float*)d_in[8];
  const float* k_pos = (const float*)d_in[9];
  const float* v_pos = (const float*)d_in[10];
  const float* Wck   = (const float*)d_in[11];
  const float* bck   = (const float*)d_in[12];
  const float* Wcv   = (const float*)d_in[13];
  const float* bcv   = (const float*)d_in[14];
  const float* k_mem = (const float*)d_in[15];
  const float* v_mem = (const float*)d_in[16];
  const float* W1    = (const float*)d_in[17];
  const float* W2    = (const float*)d_in[18];
  float* out = (float*)d_out;
  float* ws  = (float*)d_ws;

  const size_t NW = (size_t)NTOK * DIMM;   // 524288
  float* xr    = ws;
  float* xn    = ws + 1 * NW;
  float* q     = ws + 2 * NW;
  float* k     = ws + 3 * NW;
  float* v     = ws + 4 * NW;
  float* coutb = ws + 5 * NW;
  float* foutb = ws + 6 * NW;
  float* soutb = ws + 7 * NW;
  float* x2    = ws + 8 * NW;
  float* gates = ws + 9 * NW;
  float* ckb   = gates + 32768;
  float* cvb   = ckb + 32768;
  int*   selb  = (int*)(cvb + 32768);
  ushort* qkvTh = (ushort*)(cvb + 32768 + 65536);
  ushort* qkvTl = qkvTh + 1536 * 512;
  ushort* WoT   = qkvTl + 1536 * 512;
  ushort* W1T   = WoT   + 512 * 512;
  ushort* W2T   = W1T   + 2048 * 512;
  float* o  = v;    // reuse after swin consumed v
  float* y  = xr;   // reuse after Wo residual consumed xr
  float* h1 = q;    // f32 1024x2048, spans q..coutb after attention done

  dim3 tb(32, 8);
  k_wtr<<<dim3(16, 16), tb, 0, stream>>>(Wq, qkvTh,              qkvTl,              512, 512);
  k_wtr<<<dim3(16, 16), tb, 0, stream>>>(Wk, qkvTh + 512 * 512,  qkvTl + 512 * 512,  512, 512);
  k_wtr<<<dim3(16, 16), tb, 0, stream>>>(Wv, qkvTh + 1024 * 512, qkvTl + 1024 * 512, 512, 512);
  k_wtr<<<dim3(16, 16), tb, 0, stream>>>(Wo, WoT, nullptr,  512, 512);
  k_wtr<<<dim3(64, 16), tb, 0, stream>>>(W1, W1T, nullptr,  512, 2048);
  k_wtr<<<dim3(16, 64), tb, 0, stream>>>(W2, W2T, nullptr, 2048, 512);

  k_resid_rms<<<NTOK, 256, 0, stream>>>(x, x0, lam, xr, xn);

  k_gemm_qkv<<<dim3(1536 / 64, NTOK / 64), 256, 0, stream>>>(
      xn, qkvTh, qkvTl, q, 512);
  k_gates<<<(NTOK * NH * 3 + 255) / 256, 256, 0, stream>>>(xn, Wg, gates);
  k_rope<<<(2 * NTOK * NH * 32) / 256, 256, 0, stream>>>(q, k);

  k_ckcv<<<NH * CBLK, 64, 0, stream>>>(k, v, k_pos, v_pos, Wck, bck, Wcv, bcv,
                                       ckb, cvb);
  dim3 gT(NTOK / 16, NH);
  k_cmp<<<gT, 256, 0, stream>>>(q, ckb, cvb, k_mem, v_mem, coutb, selb);
  k_fine<<<dim3(NTOK, NH), 64, 0, stream>>>(q, k, v, selb, foutb);
  k_swin<<<gT, 256, 0, stream>>>(q, k, v, soutb);

  k_combine<<<NW / 256, 256, 0, stream>>>(coutb, foutb, soutb, gates, o);
  k_gemm_bf16<<<dim3(512 / 64, NTOK / 64), 256, 0, stream>>>(
      o, WoT, xr, x2, 512, 512, 0);

  k_rms<<<NTOK, 256, 0, stream>>>(x2, y);
  k_gemm_bf16<<<dim3(2048 / 64, NTOK / 64), 256, 0, stream>>>(
      y, W1T, nullptr, h1, 512, 2048, 1);
  k_gemm_bf16<<<dim3(512 / 64, NTOK / 64), 256, 0, stream>>>(
      h1, W2T, x2, out, 2048, 512, 0);
}

// Round 5
// 412.480 us; speedup vs baseline: 1.9270x; 1.1198x over previous
//
#include <hip/hip_runtime.h>
#include <math.h>

#define NTOK 1024
#define DIMM 512
#define NH 8
#define HD 64
#define BCB 16
#define BSB 16
#define KSEL 8
#define WWIN 256
#define CBLK 64
#define SCALE 0.125f
#define EPSV 1e-6f
#define NEGV -1e30f

typedef short bf16x8 __attribute__((ext_vector_type(8)));
typedef float f32x4 __attribute__((ext_vector_type(4)));

__device__ inline ushort f2b(float f) {
  union { float f; unsigned int u; } c; c.f = f;
  unsigned int u = c.u;
  return (ushort)((u + 0x7FFFu + ((u >> 16) & 1u)) >> 16);
}
__device__ inline float b2f(ushort h) {
  union { unsigned int u; float f; } c; c.u = ((unsigned int)h) << 16;
  return c.f;
}

__device__ inline float wred_max(float v) {
#pragma unroll
  for (int off = 1; off < 64; off <<= 1) v = fmaxf(v, __shfl_xor(v, off));
  return v;
}
__device__ inline float wred_sum(float v) {
#pragma unroll
  for (int off = 1; off < 64; off <<= 1) v += __shfl_xor(v, off);
  return v;
}

// ---------- residual mix + rmsnorm ----------
__global__ void __launch_bounds__(256)
k_resid_rms(const float* __restrict__ x, const float* __restrict__ x0,
            const float* __restrict__ lam, float* __restrict__ xr,
            float* __restrict__ xn) {
  int row = blockIdx.x, tid = threadIdx.x;
  float l0 = lam[0], l1 = lam[1];
  size_t b = (size_t)row * DIMM;
  float a0 = l0 * x[b + tid]       + l1 * x0[b + tid];
  float a1 = l0 * x[b + tid + 256] + l1 * x0[b + tid + 256];
  xr[b + tid] = a0; xr[b + tid + 256] = a1;
  float ss = a0 * a0 + a1 * a1;
  __shared__ float sm[8];
  for (int o = 32; o > 0; o >>= 1) ss += __shfl_down(ss, o);
  int lane = tid & 63, wid = tid >> 6;
  if (lane == 0) sm[wid] = ss;
  __syncthreads();
  if (tid == 0) {
    float s = sm[0] + sm[1] + sm[2] + sm[3];
    sm[0] = rsqrtf(s / (float)DIMM + EPSV);
  }
  __syncthreads();
  float r = sm[0];
  xn[b + tid] = a0 * r; xn[b + tid + 256] = a1 * r;
}

// ---------- plain rmsnorm ----------
__global__ void __launch_bounds__(256)
k_rms(const float* __restrict__ xin, float* __restrict__ y) {
  int row = blockIdx.x, tid = threadIdx.x;
  size_t b = (size_t)row * DIMM;
  float a0 = xin[b + tid], a1 = xin[b + tid + 256];
  float ss = a0 * a0 + a1 * a1;
  __shared__ float sm[8];
  for (int o = 32; o > 0; o >>= 1) ss += __shfl_down(ss, o);
  int lane = tid & 63, wid = tid >> 6;
  if (lane == 0) sm[wid] = ss;
  __syncthreads();
  if (tid == 0) {
    float s = sm[0] + sm[1] + sm[2] + sm[3];
    sm[0] = rsqrtf(s / (float)DIMM + EPSV);
  }
  __syncthreads();
  float r = sm[0];
  y[b + tid] = a0 * r; y[b + tid + 256] = a1 * r;
}

// ---------- weight transpose + bf16 convert ----------
__global__ void __launch_bounds__(256)
k_wtr(const float* __restrict__ src, ushort* __restrict__ dsth,
      ushort* __restrict__ dstl, int K, int N) {
  __shared__ float t[32][33];
  int n0 = blockIdx.x * 32, k0 = blockIdx.y * 32;
  int tx = threadIdx.x, ty = threadIdx.y;  // 32 x 8
#pragma unroll
  for (int i = 0; i < 32; i += 8)
    t[ty + i][tx] = src[(size_t)(k0 + ty + i) * N + n0 + tx];
  __syncthreads();
#pragma unroll
  for (int i = 0; i < 32; i += 8) {
    float vv = t[tx][ty + i];
    ushort h = f2b(vv);
    size_t di = (size_t)(n0 + ty + i) * K + k0 + tx;
    dsth[di] = h;
    if (dstl) dstl[di] = f2b(vv - b2f(h));
  }
}

// ---------- plain bf16 MFMA GEMM ----------
__global__ void __launch_bounds__(256)
k_gemm_bf16(const float* __restrict__ A, const ushort* __restrict__ BT,
            const float* __restrict__ Res, float* __restrict__ Co,
            int Kd, int Nd, int epi) {
  __shared__ ushort As[64 * 40];
  __shared__ ushort Bs[64 * 40];
  int tid = threadIdx.x;
  int lane = tid & 63, wave = tid >> 6;
  int rb = blockIdx.y * 64, cb = blockIdx.x * 64;
  int wm = (wave >> 1) * 32, wn = (wave & 1) * 32;
  int q = lane >> 4, l15 = lane & 15;
  int srow = tid >> 2, scol = (tid & 3) * 8;

  f32x4 acc[2][2];
#pragma unroll
  for (int i = 0; i < 2; i++)
#pragma unroll
    for (int j = 0; j < 2; j++) acc[i][j] = (f32x4){0.f, 0.f, 0.f, 0.f};

  const float*  ap = A  + (size_t)(rb + srow) * Kd + scol;
  const ushort* bp = BT + (size_t)(cb + srow) * Kd + scol;
  ushort* aw = &As[srow * 40 + scol];
  ushort* bw = &Bs[srow * 40 + scol];

  for (int k0 = 0; k0 < Kd; k0 += 32) {
    float4 a0 = *(const float4*)(ap + k0);
    float4 a1 = *(const float4*)(ap + k0 + 4);
    ushort h[8] = {f2b(a0.x), f2b(a0.y), f2b(a0.z), f2b(a0.w),
                   f2b(a1.x), f2b(a1.y), f2b(a1.z), f2b(a1.w)};
    *(int4*)aw = *(int4*)h;
    *(int4*)bw = *(const int4*)(bp + k0);
    __syncthreads();
    bf16x8 af[2], bfr[2];
#pragma unroll
    for (int t = 0; t < 2; t++) {
      af[t]  = *(const bf16x8*)&As[(wm + t * 16 + l15) * 40 + q * 8];
      bfr[t] = *(const bf16x8*)&Bs[(wn + t * 16 + l15) * 40 + q * 8];
    }
#pragma unroll
    for (int i = 0; i < 2; i++)
#pragma unroll
      for (int j = 0; j < 2; j++)
        acc[i][j] = __builtin_amdgcn_mfma_f32_16x16x32_bf16(af[i], bfr[j],
                                                            acc[i][j], 0, 0, 0);
    __syncthreads();
  }

#pragma unroll
  for (int i = 0; i < 2; i++) {
#pragma unroll
    for (int j = 0; j < 2; j++) {
      int col = cb + wn + j * 16 + l15;
#pragma unroll
      for (int r = 0; r < 4; r++) {
        int row = rb + wm + i * 16 + q * 4 + r;
        float vv = acc[i][j][r];
        if (epi == 1) { float t = fmaxf(vv, 0.f); vv = t * t; }
        if (Res) vv += Res[(size_t)row * Nd + col];
        Co[(size_t)row * Nd + col] = vv;
      }
    }
  }
}

// ---------- split-bf16 MFMA GEMM (hi+lo): QKV, split-plane store ----------
__global__ void __launch_bounds__(256)
k_gemm_qkv(const float* __restrict__ A, const ushort* __restrict__ BTh,
           const ushort* __restrict__ BTl, float* __restrict__ Co, int Kd) {
  __shared__ ushort Ash[64 * 40];
  __shared__ ushort Asl[64 * 40];
  __shared__ ushort Bsh[64 * 40];
  __shared__ ushort Bsl[64 * 40];
  int tid = threadIdx.x;
  int lane = tid & 63, wave = tid >> 6;
  int rb = blockIdx.y * 64, cb = blockIdx.x * 64;
  int wm = (wave >> 1) * 32, wn = (wave & 1) * 32;
  int q = lane >> 4, l15 = lane & 15;
  int srow = tid >> 2, scol = (tid & 3) * 8;

  f32x4 acc[2][2];
#pragma unroll
  for (int i = 0; i < 2; i++)
#pragma unroll
    for (int j = 0; j < 2; j++) acc[i][j] = (f32x4){0.f, 0.f, 0.f, 0.f};

  const float*  ap  = A   + (size_t)(rb + srow) * Kd + scol;
  const ushort* bph = BTh + (size_t)(cb + srow) * Kd + scol;
  const ushort* bpl = BTl + (size_t)(cb + srow) * Kd + scol;
  ushort* awh = &Ash[srow * 40 + scol];
  ushort* awl = &Asl[srow * 40 + scol];
  ushort* bwh = &Bsh[srow * 40 + scol];
  ushort* bwl = &Bsl[srow * 40 + scol];

  for (int k0 = 0; k0 < Kd; k0 += 32) {
    float4 a0 = *(const float4*)(ap + k0);
    float4 a1 = *(const float4*)(ap + k0 + 4);
    float va[8] = {a0.x, a0.y, a0.z, a0.w, a1.x, a1.y, a1.z, a1.w};
    ushort hh[8], hl[8];
#pragma unroll
    for (int e = 0; e < 8; e++) {
      hh[e] = f2b(va[e]);
      hl[e] = f2b(va[e] - b2f(hh[e]));
    }
    *(int4*)awh = *(int4*)hh;
    *(int4*)awl = *(int4*)hl;
    *(int4*)bwh = *(const int4*)(bph + k0);
    *(int4*)bwl = *(const int4*)(bpl + k0);
    __syncthreads();
    bf16x8 afh[2], afl[2], bfh[2], bfl[2];
#pragma unroll
    for (int t = 0; t < 2; t++) {
      int ar = (wm + t * 16 + l15) * 40 + q * 8;
      int br = (wn + t * 16 + l15) * 40 + q * 8;
      afh[t] = *(const bf16x8*)&Ash[ar];
      afl[t] = *(const bf16x8*)&Asl[ar];
      bfh[t] = *(const bf16x8*)&Bsh[br];
      bfl[t] = *(const bf16x8*)&Bsl[br];
    }
#pragma unroll
    for (int i = 0; i < 2; i++)
#pragma unroll
      for (int j = 0; j < 2; j++) {
        acc[i][j] = __builtin_amdgcn_mfma_f32_16x16x32_bf16(afh[i], bfh[j],
                                                            acc[i][j], 0, 0, 0);
        acc[i][j] = __builtin_amdgcn_mfma_f32_16x16x32_bf16(afh[i], bfl[j],
                                                            acc[i][j], 0, 0, 0);
        acc[i][j] = __builtin_amdgcn_mfma_f32_16x16x32_bf16(afl[i], bfh[j],
                                                            acc[i][j], 0, 0, 0);
      }
    __syncthreads();
  }

  const size_t NW = (size_t)NTOK * DIMM;
#pragma unroll
  for (int i = 0; i < 2; i++) {
#pragma unroll
    for (int j = 0; j < 2; j++) {
      int col = cb + wn + j * 16 + l15;
#pragma unroll
      for (int r = 0; r < 4; r++) {
        int row = rb + wm + i * 16 + q * 4 + r;
        Co[(size_t)(col >> 9) * NW + (size_t)row * 512 + (col & 511)] =
            acc[i][j][r];
      }
    }
  }
}

// ---------- gates ----------
__global__ void __launch_bounds__(256)
k_gates(const float* __restrict__ xn, const float* __restrict__ Wg,
        float* __restrict__ gates) {
  int idx = blockIdx.x * 256 + threadIdx.x;
  if (idx >= NTOK * NH * 3) return;
  int col = idx % (NH * 3), n = idx / (NH * 3);
  float acc = 0.f;
  for (int e = 0; e < DIMM; e++)
    acc = fmaf(xn[(size_t)n * DIMM + e], Wg[(size_t)e * (NH * 3) + col], acc);
  gates[idx] = 1.f / (1.f + expf(-acc));
}

// ---------- RoPE in-place ----------
__global__ void __launch_bounds__(256)
k_rope(float* __restrict__ q, float* __restrict__ k) {
  int idx = blockIdx.x * 256 + threadIdx.x;
  int ten = idx >> 18;
  int r = idx & 262143;
  int j = r & 31;
  int h = (r >> 5) & 7;
  int n = r >> 8;
  float* p = ten ? k : q;
  size_t base = (size_t)n * DIMM + h * HD + j;
  float inv = powf(10000.f, -(float)j / 32.f);
  float ang = (float)n * inv;
  float sn, cs;
  sincosf(ang, &sn, &cs);
  float x1 = p[base], x2 = p[base + 32];
  p[base] = x1 * cs - x2 * sn;
  p[base + 32] = x2 * cs + x1 * sn;
}

// ---------- compressed k/v via MFMA hi/lo: block=(h, kv), M=64(c) N=64(d) K=1024 ----------
__global__ void __launch_bounds__(256)
k_ckcv_m(const float* __restrict__ kg, const float* __restrict__ vg,
         const float* __restrict__ k_pos, const float* __restrict__ v_pos,
         const ushort* __restrict__ WckTh, const ushort* __restrict__ WckTl,
         const ushort* __restrict__ WcvTh, const ushort* __restrict__ WcvTl,
         const float* __restrict__ bck, const float* __restrict__ bcv,
         float* __restrict__ ckb, float* __restrict__ cvb) {
  int h = blockIdx.x, kv = blockIdx.y;
  const float* src = kv ? vg : kg;
  const float* pos = kv ? v_pos : k_pos;
  const ushort* WTh = kv ? WcvTh : WckTh;
  const ushort* WTl = kv ? WcvTl : WckTl;
  const float* bias = kv ? bcv : bck;
  float* outp = kv ? cvb : ckb;

  __shared__ ushort Ash[64 * 72], Asl[64 * 72];
  __shared__ ushort Bsh[64 * 72], Bsl[64 * 72];
  int tid = threadIdx.x;
  int lane = tid & 63, wave = tid >> 6;
  int wm = (wave >> 1) * 32, wn = (wave & 1) * 32;
  int q = lane >> 4, l15 = lane & 15;
  int srow = tid >> 2;            // 0..63
  int e0 = (tid & 3) * 16;        // 16 floats per thread

  f32x4 acc[2][2];
#pragma unroll
  for (int i = 0; i < 2; i++)
#pragma unroll
    for (int j = 0; j < 2; j++) acc[i][j] = (f32x4){0.f, 0.f, 0.f, 0.f};

  for (int t = 0; t < 16; t++) {
    // A: row c=srow, cols e0..e0+16 of K-chunk t (kk = t*64+e)
    const float* ar = src + (size_t)(srow * 16 + t) * DIMM + h * HD + e0;
    const float* pr = pos + (size_t)(h * 16 + t) * HD + e0;
    ushort hh[16], hl[16];
#pragma unroll
    for (int u = 0; u < 4; u++) {
      float4 av = *(const float4*)(ar + u * 4);
      float4 pv = *(const float4*)(pr + u * 4);
      float vals[4] = {av.x + pv.x, av.y + pv.y, av.z + pv.z, av.w + pv.w};
#pragma unroll
      for (int e = 0; e < 4; e++) {
        ushort hb = f2b(vals[e]);
        hh[u * 4 + e] = hb;
        hl[u * 4 + e] = f2b(vals[e] - b2f(hb));
      }
    }
    *(int4*)&Ash[srow * 72 + e0]     = *(int4*)&hh[0];
    *(int4*)&Ash[srow * 72 + e0 + 8] = *(int4*)&hh[8];
    *(int4*)&Asl[srow * 72 + e0]     = *(int4*)&hl[0];
    *(int4*)&Asl[srow * 72 + e0 + 8] = *(int4*)&hl[8];
    // B: row d=srow, cols kk=t*64+e0..+16 (precomputed bf16 hi/lo)
    const ushort* bh = WTh + (size_t)srow * 1024 + t * 64 + e0;
    const ushort* bl = WTl + (size_t)srow * 1024 + t * 64 + e0;
    *(int4*)&Bsh[srow * 72 + e0]     = *(const int4*)bh;
    *(int4*)&Bsh[srow * 72 + e0 + 8] = *(const int4*)(bh + 8);
    *(int4*)&Bsl[srow * 72 + e0]     = *(const int4*)bl;
    *(int4*)&Bsl[srow * 72 + e0 + 8] = *(const int4*)(bl + 8);
    __syncthreads();
#pragma unroll
    for (int sub = 0; sub < 2; sub++) {
      bf16x8 afh[2], afl[2], bfh[2], bfl[2];
#pragma unroll
      for (int ti = 0; ti < 2; ti++) {
        int ar2 = (wm + ti * 16 + l15) * 72 + sub * 32 + q * 8;
        int br2 = (wn + ti * 16 + l15) * 72 + sub * 32 + q * 8;
        afh[ti] = *(const bf16x8*)&Ash[ar2];
        afl[ti] = *(const bf16x8*)&Asl[ar2];
        bfh[ti] = *(const bf16x8*)&Bsh[br2];
        bfl[ti] = *(const bf16x8*)&Bsl[br2];
      }
#pragma unroll
      for (int i = 0; i < 2; i++)
#pragma unroll
        for (int j = 0; j < 2; j++) {
          acc[i][j] = __builtin_amdgcn_mfma_f32_16x16x32_bf16(afh[i], bfh[j],
                                                              acc[i][j], 0, 0, 0);
          acc[i][j] = __builtin_amdgcn_mfma_f32_16x16x32_bf16(afh[i], bfl[j],
                                                              acc[i][j], 0, 0, 0);
          acc[i][j] = __builtin_amdgcn_mfma_f32_16x16x32_bf16(afl[i], bfh[j],
                                                              acc[i][j], 0, 0, 0);
        }
    }
    __syncthreads();
  }

#pragma unroll
  for (int i = 0; i < 2; i++) {
#pragma unroll
    for (int j = 0; j < 2; j++) {
      int d = wn + j * 16 + l15;
      float bv = bias[d];
#pragma unroll
      for (int r = 0; r < 4; r++) {
        int c = wm + i * 16 + q * 4 + r;
        outp[((size_t)h * 64 + c) * 64 + d] = acc[i][j][r] + bv;
      }
    }
  }
}

// ---------- compressed attention + top-8: block = (h, 16 q rows), 4 waves ----------
__global__ void __launch_bounds__(256)
k_cmp(const float* __restrict__ qg, const float* __restrict__ ckb,
      const float* __restrict__ cvb, const float* __restrict__ k_mem,
      const float* __restrict__ v_mem, float* __restrict__ cout,
      int* __restrict__ sel) {
  int h = blockIdx.y, i0 = blockIdx.x * 16;
  int tid = threadIdx.x, lane = tid & 63, w = tid >> 6;
  __shared__ float ckt[64][65];
  __shared__ float cvs[64][65];
  __shared__ float qs[16][64];
  __shared__ float kms[64], vms[64];
  __shared__ float sp[4][64];

#pragma unroll
  for (int r = 0; r < 4; r++) {
    int f = r * 256 + tid;
    int c = f >> 4, d0 = (f & 15) * 4;
    float4 t = *(const float4*)(ckb + ((size_t)h * 64 + c) * 64 + d0);
    ckt[d0][c] = t.x; ckt[d0 + 1][c] = t.y; ckt[d0 + 2][c] = t.z; ckt[d0 + 3][c] = t.w;
    float4 u = *(const float4*)(cvb + ((size_t)h * 64 + c) * 64 + d0);
    cvs[c][d0] = u.x; cvs[c][d0 + 1] = u.y; cvs[c][d0 + 2] = u.z; cvs[c][d0 + 3] = u.w;
  }
  {
    int r = tid >> 4, d0 = (tid & 15) * 4;
    float4 t = *(const float4*)(qg + (size_t)(i0 + r) * DIMM + h * HD + d0);
    qs[r][d0] = t.x; qs[r][d0 + 1] = t.y; qs[r][d0 + 2] = t.z; qs[r][d0 + 3] = t.w;
  }
  if (tid < 64) kms[tid] = k_mem[h * HD + tid];
  else if (tid < 128) vms[tid - 64] = v_mem[h * HD + tid - 64];
  __syncthreads();

  for (int s = 0; s < 4; s++) {
    int ql = w * 4 + s, qi = i0 + ql;
    float dot = 0.f, dm = 0.f;
#pragma unroll 8
    for (int e = 0; e < 64; e++) {
      float qe = qs[ql][e];
      dot = fmaf(qe, ckt[e][lane], dot);
      dm  = fmaf(qe, kms[e], dm);
    }
    bool vis = (lane * BCB + BCB - 1) < qi;
    float sj = vis ? dot * SCALE : NEGV;
    float smem = dm * SCALE;
    float m = wred_max(fmaxf(sj, smem));
    float p = expf(sj - m);
    float pmem = expf(smem - m);
    float l = wred_sum(p) + pmem;
    float inv = 1.f / l;

    float impv = vis ? p : NEGV;
#pragma unroll
    for (int kk = 0; kk < KSEL; kk++) {
      float bv = impv; int bi = lane;
#pragma unroll
      for (int off = 32; off > 0; off >>= 1) {
        float ov = __shfl_xor(bv, off);
        int   oi = __shfl_xor(bi, off);
        if (ov > bv || (ov == bv && oi < bi)) { bv = ov; bi = oi; }
      }
      if (lane == 0) sel[((size_t)h * NTOK + qi) * KSEL + kk] = (bv >= 0.f) ? bi : -1;
      if (lane == bi) impv = NEGV;
    }

    sp[w][lane] = p;
    __syncthreads();
    float od = pmem * vms[lane];
#pragma unroll 8
    for (int j = 0; j < 64; j++) od = fmaf(sp[w][j], cvs[j][lane], od);
    cout[(size_t)qi * DIMM + h * HD + lane] = od * inv;
    __syncthreads();
  }
}

// ---------- sliding window: block = (h, 16 q rows), online softmax ----------
__global__ void __launch_bounds__(256)
k_swin(const float* __restrict__ qg, const float* __restrict__ kg,
       const float* __restrict__ vg, float* __restrict__ sout) {
  int h = blockIdx.y, i0 = blockIdx.x * 16;
  int tid = threadIdx.x, lane = tid & 63, w = tid >> 6;
  __shared__ float kt[64][65];
  __shared__ float vs[64][65];
  __shared__ float qs[16][64];
  __shared__ float sp[4][64];

  {
    int r = tid >> 4, d0 = (tid & 15) * 4;
    float4 t = *(const float4*)(qg + (size_t)(i0 + r) * DIMM + h * HD + d0);
    qs[r][d0] = t.x; qs[r][d0 + 1] = t.y; qs[r][d0 + 2] = t.z; qs[r][d0 + 3] = t.w;
  }

  int lo = i0 - (WWIN - 1); if (lo < 0) lo = 0;
  int jb_lo = lo >> 6, jb_hi = (i0 + 15) >> 6;

  float mrow[4], lrow[4], orow[4];
#pragma unroll
  for (int s = 0; s < 4; s++) { mrow[s] = NEGV; lrow[s] = 0.f; orow[s] = 0.f; }

  for (int jb = jb_lo; jb <= jb_hi; jb++) {
    __syncthreads();
#pragma unroll
    for (int r = 0; r < 4; r++) {
      int f = r * 256 + tid;
      int c = f >> 4, d0 = (f & 15) * 4;
      float4 t = *(const float4*)(kg + (size_t)(jb * 64 + c) * DIMM + h * HD + d0);
      kt[d0][c] = t.x; kt[d0 + 1][c] = t.y; kt[d0 + 2][c] = t.z; kt[d0 + 3][c] = t.w;
      float4 u = *(const float4*)(vg + (size_t)(jb * 64 + c) * DIMM + h * HD + d0);
      vs[c][d0] = u.x; vs[c][d0 + 1] = u.y; vs[c][d0 + 2] = u.z; vs[c][d0 + 3] = u.w;
    }
    __syncthreads();

    for (int s = 0; s < 4; s++) {
      int ql = w * 4 + s, qi = i0 + ql;
      float dot = 0.f;
#pragma unroll 8
      for (int e = 0; e < 64; e++) dot = fmaf(qs[ql][e], kt[e][lane], dot);
      int gj = jb * 64 + lane;
      bool vis = (gj <= qi) && (qi - gj < WWIN);
      float sj = vis ? dot * SCALE : NEGV;
      float tm = wred_max(sj);
      float newm = fmaxf(mrow[s], tm);
      float p = vis ? expf(sj - newm) : 0.f;
      float ts = wred_sum(p);
      float alpha = expf(mrow[s] - newm);
      sp[w][lane] = p;
      __syncthreads();
      float acc = 0.f;
#pragma unroll 8
      for (int j = 0; j < 64; j++) acc = fmaf(sp[w][j], vs[j][lane], acc);
      orow[s] = orow[s] * alpha + acc;
      lrow[s] = lrow[s] * alpha + ts;
      mrow[s] = newm;
      __syncthreads();
    }
  }
#pragma unroll
  for (int s = 0; s < 4; s++) {
    int qi = i0 + w * 4 + s;
    sout[(size_t)qi * DIMM + h * HD + lane] = orow[s] / lrow[s];
  }
}

// ---------- fine attention: 4-wave block per (h,i) ----------
__global__ void __launch_bounds__(256)
k_fine(const float* __restrict__ qg, const float* __restrict__ kg,
       const float* __restrict__ vg, const int* __restrict__ sel,
       float* __restrict__ fout) {
  int i = blockIdx.x, h = blockIdx.y;
  int tid = threadIdx.x, lane = tid & 63, w = tid >> 6;
  __shared__ float qsh[64];
  __shared__ float sp[144];
  __shared__ int srow[144];
  __shared__ float mred[4], sred[4];
  __shared__ float pacc[4][64];

  if (tid < 64) qsh[tid] = qg[(size_t)i * DIMM + h * HD + tid];
  __syncthreads();

  int own = i >> 4;
  float s_loc = NEGV;
  bool active = (tid < 144);
  int row = 0;
  if (active) {
    int key = tid;
    int bidx; bool vis;
    if (key < 128) {
      int kk = key >> 4;
      bidx = sel[((size_t)h * NTOK + i) * KSEL + kk];
      vis = (bidx >= 0);
      if (!vis) bidx = 0;
    } else {
      bidx = own;
      vis = (key - 128) <= (i & 15);
    }
    row = bidx * BSB + (key & 15);
    const float* kr = kg + (size_t)row * DIMM + h * HD;
    float dot = 0.f;
#pragma unroll
    for (int e4 = 0; e4 < 16; e4++) {
      float4 kv = *(const float4*)(kr + e4 * 4);
      float4 qv = *(const float4*)&qsh[e4 * 4];
      dot = fmaf(qv.x, kv.x, dot); dot = fmaf(qv.y, kv.y, dot);
      dot = fmaf(qv.z, kv.z, dot); dot = fmaf(qv.w, kv.w, dot);
    }
    s_loc = vis ? dot * SCALE : NEGV;
  }
  float mw = wred_max(s_loc);
  if (lane == 0) mred[w] = mw;
  __syncthreads();
  float m = fmaxf(fmaxf(mred[0], mred[1]), fmaxf(mred[2], mred[3]));
  float p = active ? expf(s_loc - m) : 0.f;
  float sw = wred_sum(p);
  if (lane == 0) sred[w] = sw;
  if (active) { sp[tid] = p; srow[tid] = row; }
  __syncthreads();
  float l = sred[0] + sred[1] + sred[2] + sred[3];

  // PV: wave w covers j = 36w .. 36w+35
  float acc = 0.f;
  int j0 = w * 36;
#pragma unroll 4
  for (int jj = 0; jj < 36; jj++) {
    int j = j0 + jj;
    acc = fmaf(sp[j], vg[(size_t)srow[j] * DIMM + h * HD + lane], acc);
  }
  pacc[w][lane] = acc;
  __syncthreads();
  if (w == 0) {
    float o = (pacc[0][lane] + pacc[1][lane] + pacc[2][lane] + pacc[3][lane]) / l;
    fout[(size_t)i * DIMM + h * HD + lane] = o;
  }
}

// ---------- gated combine ----------
__global__ void __launch_bounds__(256)
k_combine(const float* __restrict__ cout, const float* __restrict__ fout,
          const float* __restrict__ sout, const float* __restrict__ gates,
          float* __restrict__ o) {
  int idx = blockIdx.x * 256 + threadIdx.x;
  int h = (idx >> 6) & 7;
  int n = idx >> 9;
  const float* g = gates + (size_t)n * (NH * 3) + h * 3;
  o[idx] = g[0] * cout[idx] + g[1] * fout[idx] + g[2] * sout[idx];
}

extern "C" void kernel_launch(void* const* d_in, const int* in_sizes, int n_in,
                              void* d_out, int out_size, void* d_ws, size_t ws_size,
                              hipStream_t stream) {
  const float* x     = (const float*)d_in[0];
  const float* ve    = (const float*)d_in[1]; (void)ve;
  const float* x0    = (const float*)d_in[2];
  const float* lam   = (const float*)d_in[3];
  const float* Wq    = (const float*)d_in[4];
  const float* Wk    = (const float*)d_in[5];
  const float* Wv    = (const float*)d_in[6];
  const float* Wo    = (const float*)d_in[7];
  const float* Wg    = (const float*)d_in[8];
  const float* k_pos = (const float*)d_in[9];
  const float* v_pos = (const float*)d_in[10];
  const float* Wck   = (const float*)d_in[11];
  const float* bck   = (const float*)d_in[12];
  const float* Wcv   = (const float*)d_in[13];
  const float* bcv   = (const float*)d_in[14];
  const float* k_mem = (const float*)d_in[15];
  const float* v_mem = (const float*)d_in[16];
  const float* W1    = (const float*)d_in[17];
  const float* W2    = (const float*)d_in[18];
  float* out = (float*)d_out;
  float* ws  = (float*)d_ws;

  const size_t NW = (size_t)NTOK * DIMM;   // 524288
  float* xr    = ws;
  float* xn    = ws + 1 * NW;
  float* q     = ws + 2 * NW;
  float* k     = ws + 3 * NW;
  float* v     = ws + 4 * NW;
  float* coutb = ws + 5 * NW;
  float* foutb = ws + 6 * NW;
  float* soutb = ws + 7 * NW;
  float* x2    = ws + 8 * NW;
  float* gates = ws + 9 * NW;
  float* ckb   = gates + 32768;
  float* cvb   = ckb + 32768;
  int*   selb  = (int*)(cvb + 32768);
  ushort* qkvTh = (ushort*)(cvb + 32768 + 65536);
  ushort* qkvTl = qkvTh + 1536 * 512;
  ushort* WoT   = qkvTl + 1536 * 512;
  ushort* W1T   = WoT   + 512 * 512;
  ushort* W2T   = W1T   + 2048 * 512;
  ushort* WckTh = W2T   + 512 * 2048;   // 64*1024
  ushort* WckTl = WckTh + 64 * 1024;
  ushort* WcvTh = WckTl + 64 * 1024;
  ushort* WcvTl = WcvTh + 64 * 1024;
  float* o  = v;    // reuse after swin consumed v
  float* y  = xr;   // reuse after Wo residual consumed xr
  float* h1 = q;    // f32 1024x2048, spans q..coutb after attention done

  dim3 tb(32, 8);
  k_wtr<<<dim3(16, 16), tb, 0, stream>>>(Wq, qkvTh,              qkvTl,              512, 512);
  k_wtr<<<dim3(16, 16), tb, 0, stream>>>(Wk, qkvTh + 512 * 512,  qkvTl + 512 * 512,  512, 512);
  k_wtr<<<dim3(16, 16), tb, 0, stream>>>(Wv, qkvTh + 1024 * 512, qkvTl + 1024 * 512, 512, 512);
  k_wtr<<<dim3(16, 16), tb, 0, stream>>>(Wo, WoT, nullptr,  512, 512);
  k_wtr<<<dim3(64, 16), tb, 0, stream>>>(W1, W1T, nullptr,  512, 2048);
  k_wtr<<<dim3(16, 64), tb, 0, stream>>>(W2, W2T, nullptr, 2048, 512);
  k_wtr<<<dim3(2, 32),  tb, 0, stream>>>(Wck, WckTh, WckTl, 1024, 64);
  k_wtr<<<dim3(2, 32),  tb, 0, stream>>>(Wcv, WcvTh, WcvTl, 1024, 64);

  k_resid_rms<<<NTOK, 256, 0, stream>>>(x, x0, lam, xr, xn);

  k_gemm_qkv<<<dim3(1536 / 64, NTOK / 64), 256, 0, stream>>>(
      xn, qkvTh, qkvTl, q, 512);
  k_gates<<<(NTOK * NH * 3 + 255) / 256, 256, 0, stream>>>(xn, Wg, gates);
  k_rope<<<(2 * NTOK * NH * 32) / 256, 256, 0, stream>>>(q, k);

  k_ckcv_m<<<dim3(NH, 2), 256, 0, stream>>>(k, v, k_pos, v_pos,
                                            WckTh, WckTl, WcvTh, WcvTl,
                                            bck, bcv, ckb, cvb);
  dim3 gT(NTOK / 16, NH);
  k_cmp<<<gT, 256, 0, stream>>>(q, ckb, cvb, k_mem, v_mem, coutb, selb);
  k_fine<<<dim3(NTOK, NH), 256, 0, stream>>>(q, k, v, selb, foutb);
  k_swin<<<gT, 256, 0, stream>>>(q, k, v, soutb);

  k_combine<<<NW / 256, 256, 0, stream>>>(coutb, foutb, soutb, gates, o);
  k_gemm_bf16<<<dim3(512 / 64, NTOK / 64), 256, 0, stream>>>(
      o, WoT, xr, x2, 512, 512, 0);

  k_rms<<<NTOK, 256, 0, stream>>>(x2, y);
  k_gemm_bf16<<<dim3(2048 / 64, NTOK / 64), 256, 0, stream>>>(
      y, W1T, nullptr, h1, 512, 2048, 1);
  k_gemm_bf16<<<dim3(512 / 64, NTOK / 64), 256, 0, stream>>>(
      h1, W2T, x2, out, 2048, 512, 0);
}

// Round 6
// 368.363 us; speedup vs baseline: 2.1578x; 1.1198x over previous
//
#include <hip/hip_runtime.h>
#include <math.h>

#define NTOK 1024
#define DIMM 512
#define NH 8
#define HD 64
#define BCB 16
#define BSB 16
#define KSEL 8
#define WWIN 256
#define CBLK 64
#define SCALE 0.125f
#define EPSV 1e-6f
#define NEGV -1e30f

typedef short bf16x8 __attribute__((ext_vector_type(8)));
typedef float f32x4 __attribute__((ext_vector_type(4)));

__device__ inline ushort f2b(float f) {
  union { float f; unsigned int u; } c; c.f = f;
  unsigned int u = c.u;
  return (ushort)((u + 0x7FFFu + ((u >> 16) & 1u)) >> 16);
}
__device__ inline float b2f(ushort h) {
  union { unsigned int u; float f; } c; c.u = ((unsigned int)h) << 16;
  return c.f;
}

__device__ inline float wred_max(float v) {
#pragma unroll
  for (int off = 1; off < 64; off <<= 1) v = fmaxf(v, __shfl_xor(v, off));
  return v;
}
__device__ inline float wred_sum(float v) {
#pragma unroll
  for (int off = 1; off < 64; off <<= 1) v += __shfl_xor(v, off);
  return v;
}

// ---------- residual mix + rmsnorm ----------
__global__ void __launch_bounds__(256)
k_resid_rms(const float* __restrict__ x, const float* __restrict__ x0,
            const float* __restrict__ lam, float* __restrict__ xr,
            float* __restrict__ xn) {
  int row = blockIdx.x, tid = threadIdx.x;
  float l0 = lam[0], l1 = lam[1];
  size_t b = (size_t)row * DIMM;
  float a0 = l0 * x[b + tid]       + l1 * x0[b + tid];
  float a1 = l0 * x[b + tid + 256] + l1 * x0[b + tid + 256];
  xr[b + tid] = a0; xr[b + tid + 256] = a1;
  float ss = a0 * a0 + a1 * a1;
  __shared__ float sm[8];
  for (int o = 32; o > 0; o >>= 1) ss += __shfl_down(ss, o);
  int lane = tid & 63, wid = tid >> 6;
  if (lane == 0) sm[wid] = ss;
  __syncthreads();
  if (tid == 0) {
    float s = sm[0] + sm[1] + sm[2] + sm[3];
    sm[0] = rsqrtf(s / (float)DIMM + EPSV);
  }
  __syncthreads();
  float r = sm[0];
  xn[b + tid] = a0 * r; xn[b + tid + 256] = a1 * r;
}

// ---------- plain rmsnorm ----------
__global__ void __launch_bounds__(256)
k_rms(const float* __restrict__ xin, float* __restrict__ y) {
  int row = blockIdx.x, tid = threadIdx.x;
  size_t b = (size_t)row * DIMM;
  float a0 = xin[b + tid], a1 = xin[b + tid + 256];
  float ss = a0 * a0 + a1 * a1;
  __shared__ float sm[8];
  for (int o = 32; o > 0; o >>= 1) ss += __shfl_down(ss, o);
  int lane = tid & 63, wid = tid >> 6;
  if (lane == 0) sm[wid] = ss;
  __syncthreads();
  if (tid == 0) {
    float s = sm[0] + sm[1] + sm[2] + sm[3];
    sm[0] = rsqrtf(s / (float)DIMM + EPSV);
  }
  __syncthreads();
  float r = sm[0];
  y[b + tid] = a0 * r; y[b + tid + 256] = a1 * r;
}

// ---------- consolidated weight transposes (f32 K×N -> bf16 hi/lo N×K) ----------
struct WtrDesc { const float* src; ushort* dh; ushort* dl; int K; int Nsrc; int Npad; };
struct WtrPack { WtrDesc d[9]; int cum[9]; };

__global__ void __launch_bounds__(256)
k_wtr_all(WtrPack pk) {
  int gb = blockIdx.x;
  int e = 0;
  while (gb >= pk.cum[e]) e++;
  int start = e ? pk.cum[e - 1] : 0;
  WtrDesc dd = pk.d[e];
  int local = gb - start;
  int XT = dd.Npad >> 5;
  int bx = local % XT, by = local / XT;
  __shared__ float t[32][33];
  int n0 = bx * 32, k0 = by * 32;
  int tx = threadIdx.x, ty = threadIdx.y;  // 32 x 8
#pragma unroll
  for (int i = 0; i < 32; i += 8)
    t[ty + i][tx] = (n0 + tx < dd.Nsrc)
        ? dd.src[(size_t)(k0 + ty + i) * dd.Nsrc + n0 + tx] : 0.f;
  __syncthreads();
#pragma unroll
  for (int i = 0; i < 32; i += 8) {
    float vv = t[tx][ty + i];
    ushort h = f2b(vv);
    size_t di = (size_t)(n0 + ty + i) * dd.K + k0 + tx;
    dd.dh[di] = h;
    if (dd.dl) dd.dl[di] = f2b(vv - b2f(h));
  }
}

// ---------- plain bf16 MFMA GEMM (W1 relu^2, W2 +Res) ----------
__global__ void __launch_bounds__(256)
k_gemm_bf16(const float* __restrict__ A, const ushort* __restrict__ BT,
            const float* __restrict__ Res, float* __restrict__ Co,
            int Kd, int Nd, int epi) {
  __shared__ ushort As[64 * 40];
  __shared__ ushort Bs[64 * 40];
  int tid = threadIdx.x;
  int lane = tid & 63, wave = tid >> 6;
  int rb = blockIdx.y * 64, cb = blockIdx.x * 64;
  int wm = (wave >> 1) * 32, wn = (wave & 1) * 32;
  int q = lane >> 4, l15 = lane & 15;
  int srow = tid >> 2, scol = (tid & 3) * 8;

  f32x4 acc[2][2];
#pragma unroll
  for (int i = 0; i < 2; i++)
#pragma unroll
    for (int j = 0; j < 2; j++) acc[i][j] = (f32x4){0.f, 0.f, 0.f, 0.f};

  const float*  ap = A  + (size_t)(rb + srow) * Kd + scol;
  const ushort* bp = BT + (size_t)(cb + srow) * Kd + scol;
  ushort* aw = &As[srow * 40 + scol];
  ushort* bw = &Bs[srow * 40 + scol];

  for (int k0 = 0; k0 < Kd; k0 += 32) {
    float4 a0 = *(const float4*)(ap + k0);
    float4 a1 = *(const float4*)(ap + k0 + 4);
    ushort h[8] = {f2b(a0.x), f2b(a0.y), f2b(a0.z), f2b(a0.w),
                   f2b(a1.x), f2b(a1.y), f2b(a1.z), f2b(a1.w)};
    *(int4*)aw = *(int4*)h;
    *(int4*)bw = *(const int4*)(bp + k0);
    __syncthreads();
    bf16x8 af[2], bfr[2];
#pragma unroll
    for (int t = 0; t < 2; t++) {
      af[t]  = *(const bf16x8*)&As[(wm + t * 16 + l15) * 40 + q * 8];
      bfr[t] = *(const bf16x8*)&Bs[(wn + t * 16 + l15) * 40 + q * 8];
    }
#pragma unroll
    for (int i = 0; i < 2; i++)
#pragma unroll
      for (int j = 0; j < 2; j++)
        acc[i][j] = __builtin_amdgcn_mfma_f32_16x16x32_bf16(af[i], bfr[j],
                                                            acc[i][j], 0, 0, 0);
    __syncthreads();
  }

#pragma unroll
  for (int i = 0; i < 2; i++) {
#pragma unroll
    for (int j = 0; j < 2; j++) {
      int col = cb + wn + j * 16 + l15;
#pragma unroll
      for (int r = 0; r < 4; r++) {
        int row = rb + wm + i * 16 + q * 4 + r;
        float vv = acc[i][j][r];
        if (epi == 1) { float t = fmaxf(vv, 0.f); vv = t * t; }
        if (Res) vv += Res[(size_t)row * Nd + col];
        Co[(size_t)row * Nd + col] = vv;
      }
    }
  }
}

// ---------- Wo GEMM with fused gated combine in A-staging ----------
__global__ void __launch_bounds__(256)
k_gemm_wo(const float* __restrict__ cg, const float* __restrict__ fg,
          const float* __restrict__ sg, const float* __restrict__ gates,
          const ushort* __restrict__ BT, const float* __restrict__ Res,
          float* __restrict__ Co) {
  __shared__ ushort As[64 * 40];
  __shared__ ushort Bs[64 * 40];
  int tid = threadIdx.x;
  int lane = tid & 63, wave = tid >> 6;
  int rb = blockIdx.y * 64, cb = blockIdx.x * 64;
  int wm = (wave >> 1) * 32, wn = (wave & 1) * 32;
  int q = lane >> 4, l15 = lane & 15;
  int srow = tid >> 2, scol = (tid & 3) * 8;

  f32x4 acc[2][2];
#pragma unroll
  for (int i = 0; i < 2; i++)
#pragma unroll
    for (int j = 0; j < 2; j++) acc[i][j] = (f32x4){0.f, 0.f, 0.f, 0.f};

  int row = rb + srow;
  const ushort* bp = BT + (size_t)(cb + srow) * 512 + scol;
  ushort* aw = &As[srow * 40 + scol];
  ushort* bw = &Bs[srow * 40 + scol];

  for (int k0 = 0; k0 < 512; k0 += 32) {
    int colb = k0 + scol;
    int hh = colb >> 6;
    const float* gp = gates + (size_t)row * 24 + hh * 3;
    float g0 = gp[0], g1 = gp[1], g2 = gp[2];
    size_t off = (size_t)row * 512 + colb;
    float4 c0 = *(const float4*)(cg + off), c1 = *(const float4*)(cg + off + 4);
    float4 f0 = *(const float4*)(fg + off), f1 = *(const float4*)(fg + off + 4);
    float4 s0 = *(const float4*)(sg + off), s1 = *(const float4*)(sg + off + 4);
    float va[8] = {g0 * c0.x + g1 * f0.x + g2 * s0.x,
                   g0 * c0.y + g1 * f0.y + g2 * s0.y,
                   g0 * c0.z + g1 * f0.z + g2 * s0.z,
                   g0 * c0.w + g1 * f0.w + g2 * s0.w,
                   g0 * c1.x + g1 * f1.x + g2 * s1.x,
                   g0 * c1.y + g1 * f1.y + g2 * s1.y,
                   g0 * c1.z + g1 * f1.z + g2 * s1.z,
                   g0 * c1.w + g1 * f1.w + g2 * s1.w};
    ushort h[8];
#pragma unroll
    for (int e = 0; e < 8; e++) h[e] = f2b(va[e]);
    *(int4*)aw = *(int4*)h;
    *(int4*)bw = *(const int4*)(bp + k0);
    __syncthreads();
    bf16x8 af[2], bfr[2];
#pragma unroll
    for (int t = 0; t < 2; t++) {
      af[t]  = *(const bf16x8*)&As[(wm + t * 16 + l15) * 40 + q * 8];
      bfr[t] = *(const bf16x8*)&Bs[(wn + t * 16 + l15) * 40 + q * 8];
    }
#pragma unroll
    for (int i = 0; i < 2; i++)
#pragma unroll
      for (int j = 0; j < 2; j++)
        acc[i][j] = __builtin_amdgcn_mfma_f32_16x16x32_bf16(af[i], bfr[j],
                                                            acc[i][j], 0, 0, 0);
    __syncthreads();
  }

#pragma unroll
  for (int i = 0; i < 2; i++) {
#pragma unroll
    for (int j = 0; j < 2; j++) {
      int col = cb + wn + j * 16 + l15;
#pragma unroll
      for (int r = 0; r < 4; r++) {
        int rr = rb + wm + i * 16 + q * 4 + r;
        Co[(size_t)rr * 512 + col] = acc[i][j][r] + Res[(size_t)rr * 512 + col];
      }
    }
  }
}

// ---------- split-bf16 MFMA GEMM (hi+lo): QKV + gates, split-plane store ----------
__global__ void __launch_bounds__(256)
k_gemm_qkv(const float* __restrict__ A, const ushort* __restrict__ BTh,
           const ushort* __restrict__ BTl, float* __restrict__ Co,
           float* __restrict__ gates, int Kd) {
  __shared__ ushort Ash[64 * 40];
  __shared__ ushort Asl[64 * 40];
  __shared__ ushort Bsh[64 * 40];
  __shared__ ushort Bsl[64 * 40];
  int tid = threadIdx.x;
  int lane = tid & 63, wave = tid >> 6;
  int rb = blockIdx.y * 64, cb = blockIdx.x * 64;
  int wm = (wave >> 1) * 32, wn = (wave & 1) * 32;
  int q = lane >> 4, l15 = lane & 15;
  int srow = tid >> 2, scol = (tid & 3) * 8;

  f32x4 acc[2][2];
#pragma unroll
  for (int i = 0; i < 2; i++)
#pragma unroll
    for (int j = 0; j < 2; j++) acc[i][j] = (f32x4){0.f, 0.f, 0.f, 0.f};

  const float*  ap  = A   + (size_t)(rb + srow) * Kd + scol;
  const ushort* bph = BTh + (size_t)(cb + srow) * Kd + scol;
  const ushort* bpl = BTl + (size_t)(cb + srow) * Kd + scol;
  ushort* awh = &Ash[srow * 40 + scol];
  ushort* awl = &Asl[srow * 40 + scol];
  ushort* bwh = &Bsh[srow * 40 + scol];
  ushort* bwl = &Bsl[srow * 40 + scol];

  for (int k0 = 0; k0 < Kd; k0 += 32) {
    float4 a0 = *(const float4*)(ap + k0);
    float4 a1 = *(const float4*)(ap + k0 + 4);
    float va[8] = {a0.x, a0.y, a0.z, a0.w, a1.x, a1.y, a1.z, a1.w};
    ushort hh[8], hl[8];
#pragma unroll
    for (int e = 0; e < 8; e++) {
      hh[e] = f2b(va[e]);
      hl[e] = f2b(va[e] - b2f(hh[e]));
    }
    *(int4*)awh = *(int4*)hh;
    *(int4*)awl = *(int4*)hl;
    *(int4*)bwh = *(const int4*)(bph + k0);
    *(int4*)bwl = *(const int4*)(bpl + k0);
    __syncthreads();
    bf16x8 afh[2], afl[2], bfh[2], bfl[2];
#pragma unroll
    for (int t = 0; t < 2; t++) {
      int ar = (wm + t * 16 + l15) * 40 + q * 8;
      int br = (wn + t * 16 + l15) * 40 + q * 8;
      afh[t] = *(const bf16x8*)&Ash[ar];
      afl[t] = *(const bf16x8*)&Asl[ar];
      bfh[t] = *(const bf16x8*)&Bsh[br];
      bfl[t] = *(const bf16x8*)&Bsl[br];
    }
#pragma unroll
    for (int i = 0; i < 2; i++)
#pragma unroll
      for (int j = 0; j < 2; j++) {
        acc[i][j] = __builtin_amdgcn_mfma_f32_16x16x32_bf16(afh[i], bfh[j],
                                                            acc[i][j], 0, 0, 0);
        acc[i][j] = __builtin_amdgcn_mfma_f32_16x16x32_bf16(afh[i], bfl[j],
                                                            acc[i][j], 0, 0, 0);
        acc[i][j] = __builtin_amdgcn_mfma_f32_16x16x32_bf16(afl[i], bfh[j],
                                                            acc[i][j], 0, 0, 0);
      }
    __syncthreads();
  }

  const size_t NW = (size_t)NTOK * DIMM;
#pragma unroll
  for (int i = 0; i < 2; i++) {
#pragma unroll
    for (int j = 0; j < 2; j++) {
      int col = cb + wn + j * 16 + l15;
#pragma unroll
      for (int r = 0; r < 4; r++) {
        int row = rb + wm + i * 16 + q * 4 + r;
        float vv = acc[i][j][r];
        if (cb >= 1536) {
          int c24 = col - 1536;
          if (c24 < 24)
            gates[(size_t)row * 24 + c24] = 1.f / (1.f + expf(-vv));
        } else {
          Co[(size_t)(col >> 9) * NW + (size_t)row * 512 + (col & 511)] = vv;
        }
      }
    }
  }
}

// ---------- RoPE in-place ----------
__global__ void __launch_bounds__(256)
k_rope(float* __restrict__ q, float* __restrict__ k) {
  int idx = blockIdx.x * 256 + threadIdx.x;
  int ten = idx >> 18;
  int r = idx & 262143;
  int j = r & 31;
  int h = (r >> 5) & 7;
  int n = r >> 8;
  float* p = ten ? k : q;
  size_t base = (size_t)n * DIMM + h * HD + j;
  float inv = powf(10000.f, -(float)j / 32.f);
  float ang = (float)n * inv;
  float sn, cs;
  sincosf(ang, &sn, &cs);
  float x1 = p[base], x2 = p[base + 32];
  p[base] = x1 * cs - x2 * sn;
  p[base + 32] = x2 * cs + x1 * sn;
}

// ---------- compressed k/v via MFMA hi/lo ----------
__global__ void __launch_bounds__(256)
k_ckcv_m(const float* __restrict__ kg, const float* __restrict__ vg,
         const float* __restrict__ k_pos, const float* __restrict__ v_pos,
         const ushort* __restrict__ WckTh, const ushort* __restrict__ WckTl,
         const ushort* __restrict__ WcvTh, const ushort* __restrict__ WcvTl,
         const float* __restrict__ bck, const float* __restrict__ bcv,
         float* __restrict__ ckb, float* __restrict__ cvb) {
  int h = blockIdx.x, kv = blockIdx.y;
  const float* src = kv ? vg : kg;
  const float* pos = kv ? v_pos : k_pos;
  const ushort* WTh = kv ? WcvTh : WckTh;
  const ushort* WTl = kv ? WcvTl : WckTl;
  const float* bias = kv ? bcv : bck;
  float* outp = kv ? cvb : ckb;

  __shared__ ushort Ash[64 * 72], Asl[64 * 72];
  __shared__ ushort Bsh[64 * 72], Bsl[64 * 72];
  int tid = threadIdx.x;
  int lane = tid & 63, wave = tid >> 6;
  int wm = (wave >> 1) * 32, wn = (wave & 1) * 32;
  int q = lane >> 4, l15 = lane & 15;
  int srow = tid >> 2;
  int e0 = (tid & 3) * 16;

  f32x4 acc[2][2];
#pragma unroll
  for (int i = 0; i < 2; i++)
#pragma unroll
    for (int j = 0; j < 2; j++) acc[i][j] = (f32x4){0.f, 0.f, 0.f, 0.f};

  for (int t = 0; t < 16; t++) {
    const float* ar = src + (size_t)(srow * 16 + t) * DIMM + h * HD + e0;
    const float* pr = pos + (size_t)(h * 16 + t) * HD + e0;
    ushort hh[16], hl[16];
#pragma unroll
    for (int u = 0; u < 4; u++) {
      float4 av = *(const float4*)(ar + u * 4);
      float4 pv = *(const float4*)(pr + u * 4);
      float vals[4] = {av.x + pv.x, av.y + pv.y, av.z + pv.z, av.w + pv.w};
#pragma unroll
      for (int e = 0; e < 4; e++) {
        ushort hb = f2b(vals[e]);
        hh[u * 4 + e] = hb;
        hl[u * 4 + e] = f2b(vals[e] - b2f(hb));
      }
    }
    *(int4*)&Ash[srow * 72 + e0]     = *(int4*)&hh[0];
    *(int4*)&Ash[srow * 72 + e0 + 8] = *(int4*)&hh[8];
    *(int4*)&Asl[srow * 72 + e0]     = *(int4*)&hl[0];
    *(int4*)&Asl[srow * 72 + e0 + 8] = *(int4*)&hl[8];
    const ushort* bh = WTh + (size_t)srow * 1024 + t * 64 + e0;
    const ushort* bl = WTl + (size_t)srow * 1024 + t * 64 + e0;
    *(int4*)&Bsh[srow * 72 + e0]     = *(const int4*)bh;
    *(int4*)&Bsh[srow * 72 + e0 + 8] = *(const int4*)(bh + 8);
    *(int4*)&Bsl[srow * 72 + e0]     = *(const int4*)bl;
    *(int4*)&Bsl[srow * 72 + e0 + 8] = *(const int4*)(bl + 8);
    __syncthreads();
#pragma unroll
    for (int sub = 0; sub < 2; sub++) {
      bf16x8 afh[2], afl[2], bfh[2], bfl[2];
#pragma unroll
      for (int ti = 0; ti < 2; ti++) {
        int ar2 = (wm + ti * 16 + l15) * 72 + sub * 32 + q * 8;
        int br2 = (wn + ti * 16 + l15) * 72 + sub * 32 + q * 8;
        afh[ti] = *(const bf16x8*)&Ash[ar2];
        afl[ti] = *(const bf16x8*)&Asl[ar2];
        bfh[ti] = *(const bf16x8*)&Bsh[br2];
        bfl[ti] = *(const bf16x8*)&Bsl[br2];
      }
#pragma unroll
      for (int i = 0; i < 2; i++)
#pragma unroll
        for (int j = 0; j < 2; j++) {
          acc[i][j] = __builtin_amdgcn_mfma_f32_16x16x32_bf16(afh[i], bfh[j],
                                                              acc[i][j], 0, 0, 0);
          acc[i][j] = __builtin_amdgcn_mfma_f32_16x16x32_bf16(afh[i], bfl[j],
                                                              acc[i][j], 0, 0, 0);
          acc[i][j] = __builtin_amdgcn_mfma_f32_16x16x32_bf16(afl[i], bfh[j],
                                                              acc[i][j], 0, 0, 0);
        }
    }
    __syncthreads();
  }

#pragma unroll
  for (int i = 0; i < 2; i++) {
#pragma unroll
    for (int j = 0; j < 2; j++) {
      int d = wn + j * 16 + l15;
      float bv = bias[d];
#pragma unroll
      for (int r = 0; r < 4; r++) {
        int c = wm + i * 16 + q * 4 + r;
        outp[((size_t)h * 64 + c) * 64 + d] = acc[i][j][r] + bv;
      }
    }
  }
}

// ---------- compressed attention + top-8 ----------
__global__ void __launch_bounds__(256)
k_cmp(const float* __restrict__ qg, const float* __restrict__ ckb,
      const float* __restrict__ cvb, const float* __restrict__ k_mem,
      const float* __restrict__ v_mem, float* __restrict__ cout,
      int* __restrict__ sel) {
  int h = blockIdx.y, i0 = blockIdx.x * 16;
  int tid = threadIdx.x, lane = tid & 63, w = tid >> 6;
  __shared__ float ckt[64][65];
  __shared__ float cvs[64][65];
  __shared__ float qs[16][64];
  __shared__ float kms[64], vms[64];
  __shared__ float sp[4][64];

#pragma unroll
  for (int r = 0; r < 4; r++) {
    int f = r * 256 + tid;
    int c = f >> 4, d0 = (f & 15) * 4;
    float4 t = *(const float4*)(ckb + ((size_t)h * 64 + c) * 64 + d0);
    ckt[d0][c] = t.x; ckt[d0 + 1][c] = t.y; ckt[d0 + 2][c] = t.z; ckt[d0 + 3][c] = t.w;
    float4 u = *(const float4*)(cvb + ((size_t)h * 64 + c) * 64 + d0);
    cvs[c][d0] = u.x; cvs[c][d0 + 1] = u.y; cvs[c][d0 + 2] = u.z; cvs[c][d0 + 3] = u.w;
  }
  {
    int r = tid >> 4, d0 = (tid & 15) * 4;
    float4 t = *(const float4*)(qg + (size_t)(i0 + r) * DIMM + h * HD + d0);
    qs[r][d0] = t.x; qs[r][d0 + 1] = t.y; qs[r][d0 + 2] = t.z; qs[r][d0 + 3] = t.w;
  }
  if (tid < 64) kms[tid] = k_mem[h * HD + tid];
  else if (tid < 128) vms[tid - 64] = v_mem[h * HD + tid - 64];
  __syncthreads();

  for (int s = 0; s < 4; s++) {
    int ql = w * 4 + s, qi = i0 + ql;
    float dot = 0.f, dm = 0.f;
#pragma unroll 8
    for (int e = 0; e < 64; e++) {
      float qe = qs[ql][e];
      dot = fmaf(qe, ckt[e][lane], dot);
      dm  = fmaf(qe, kms[e], dm);
    }
    bool vis = (lane * BCB + BCB - 1) < qi;
    float sj = vis ? dot * SCALE : NEGV;
    float smem = dm * SCALE;
    float m = wred_max(fmaxf(sj, smem));
    float p = expf(sj - m);
    float pmem = expf(smem - m);
    float l = wred_sum(p) + pmem;
    float inv = 1.f / l;

    float impv = vis ? p : NEGV;
#pragma unroll
    for (int kk = 0; kk < KSEL; kk++) {
      float bv = impv; int bi = lane;
#pragma unroll
      for (int off = 32; off > 0; off >>= 1) {
        float ov = __shfl_xor(bv, off);
        int   oi = __shfl_xor(bi, off);
        if (ov > bv || (ov == bv && oi < bi)) { bv = ov; bi = oi; }
      }
      if (lane == 0) sel[((size_t)h * NTOK + qi) * KSEL + kk] = (bv >= 0.f) ? bi : -1;
      if (lane == bi) impv = NEGV;
    }

    sp[w][lane] = p;
    __syncthreads();
    float od = pmem * vms[lane];
#pragma unroll 8
    for (int j = 0; j < 64; j++) od = fmaf(sp[w][j], cvs[j][lane], od);
    cout[(size_t)qi * DIMM + h * HD + lane] = od * inv;
    __syncthreads();
  }
}

// ---------- sliding window ----------
__global__ void __launch_bounds__(256)
k_swin(const float* __restrict__ qg, const float* __restrict__ kg,
       const float* __restrict__ vg, float* __restrict__ sout) {
  int h = blockIdx.y, i0 = blockIdx.x * 16;
  int tid = threadIdx.x, lane = tid & 63, w = tid >> 6;
  __shared__ float kt[64][65];
  __shared__ float vs[64][65];
  __shared__ float qs[16][64];
  __shared__ float sp[4][64];

  {
    int r = tid >> 4, d0 = (tid & 15) * 4;
    float4 t = *(const float4*)(qg + (size_t)(i0 + r) * DIMM + h * HD + d0);
    qs[r][d0] = t.x; qs[r][d0 + 1] = t.y; qs[r][d0 + 2] = t.z; qs[r][d0 + 3] = t.w;
  }

  int lo = i0 - (WWIN - 1); if (lo < 0) lo = 0;
  int jb_lo = lo >> 6, jb_hi = (i0 + 15) >> 6;

  float mrow[4], lrow[4], orow[4];
#pragma unroll
  for (int s = 0; s < 4; s++) { mrow[s] = NEGV; lrow[s] = 0.f; orow[s] = 0.f; }

  for (int jb = jb_lo; jb <= jb_hi; jb++) {
    __syncthreads();
#pragma unroll
    for (int r = 0; r < 4; r++) {
      int f = r * 256 + tid;
      int c = f >> 4, d0 = (f & 15) * 4;
      float4 t = *(const float4*)(kg + (size_t)(jb * 64 + c) * DIMM + h * HD + d0);
      kt[d0][c] = t.x; kt[d0 + 1][c] = t.y; kt[d0 + 2][c] = t.z; kt[d0 + 3][c] = t.w;
      float4 u = *(const float4*)(vg + (size_t)(jb * 64 + c) * DIMM + h * HD + d0);
      vs[c][d0] = u.x; vs[c][d0 + 1] = u.y; vs[c][d0 + 2] = u.z; vs[c][d0 + 3] = u.w;
    }
    __syncthreads();

    for (int s = 0; s < 4; s++) {
      int ql = w * 4 + s, qi = i0 + ql;
      float dot = 0.f;
#pragma unroll 8
      for (int e = 0; e < 64; e++) dot = fmaf(qs[ql][e], kt[e][lane], dot);
      int gj = jb * 64 + lane;
      bool vis = (gj <= qi) && (qi - gj < WWIN);
      float sj = vis ? dot * SCALE : NEGV;
      float tm = wred_max(sj);
      float newm = fmaxf(mrow[s], tm);
      float p = vis ? expf(sj - newm) : 0.f;
      float ts = wred_sum(p);
      float alpha = expf(mrow[s] - newm);
      sp[w][lane] = p;
      __syncthreads();
      float acc = 0.f;
#pragma unroll 8
      for (int j = 0; j < 64; j++) acc = fmaf(sp[w][j], vs[j][lane], acc);
      orow[s] = orow[s] * alpha + acc;
      lrow[s] = lrow[s] * alpha + ts;
      mrow[s] = newm;
      __syncthreads();
    }
  }
#pragma unroll
  for (int s = 0; s < 4; s++) {
    int qi = i0 + w * 4 + s;
    sout[(size_t)qi * DIMM + h * HD + lane] = orow[s] / lrow[s];
  }
}

// ---------- fine attention: LDS-staged k rows, 4-wave block per (h,i) ----------
__global__ void __launch_bounds__(256)
k_fine(const float* __restrict__ qg, const float* __restrict__ kg,
       const float* __restrict__ vg, const int* __restrict__ sel,
       float* __restrict__ fout) {
  int i = blockIdx.x, h = blockIdx.y;
  int tid = threadIdx.x, lane = tid & 63, w = tid >> 6;
  __shared__ float ks[144 * 65];
  __shared__ float qsh[64];
  __shared__ float sp[144];
  __shared__ int srowS[144];
  __shared__ float mred[4], sredS[4];
  __shared__ float pacc[4][64];

  int own = i >> 4;
  size_t selbase = ((size_t)h * NTOK + i) * KSEL;

  if (tid < 64) qsh[tid] = qg[(size_t)i * DIMM + h * HD + tid];

  // stage 144 k-rows (contiguous 16-row blocks) into LDS
#pragma unroll
  for (int it = 0; it < 9; it++) {
    int idx = it * 256 + tid;          // 0..2303 float4s
    int row = idx >> 4, f4 = (idx & 15) * 4;
    int kk = row >> 4;
    int bidx = (kk < KSEL) ? sel[selbase + kk] : own;
    if (bidx < 0) bidx = 0;
    int gr = bidx * BSB + (row & 15);
    float4 t = *(const float4*)(kg + (size_t)gr * DIMM + h * HD + f4);
    int ba = row * 65 + f4;
    ks[ba] = t.x; ks[ba + 1] = t.y; ks[ba + 2] = t.z; ks[ba + 3] = t.w;
  }
  __syncthreads();

  float s_loc = NEGV;
  bool active = (tid < 144);
  int row = 0;
  if (active) {
    int kk = tid >> 4;
    int bidx; bool vis;
    if (kk < KSEL) {
      bidx = sel[selbase + kk];
      vis = (bidx >= 0);
      if (!vis) bidx = 0;
    } else {
      bidx = own;
      vis = (tid - 128) <= (i & 15);
    }
    row = bidx * BSB + (tid & 15);
    float dot = 0.f;
#pragma unroll 8
    for (int e = 0; e < 64; e++) dot = fmaf(qsh[e], ks[tid * 65 + e], dot);
    s_loc = vis ? dot * SCALE : NEGV;
  }
  float mw = wred_max(s_loc);
  if (lane == 0) mred[w] = mw;
  __syncthreads();
  float m = fmaxf(fmaxf(mred[0], mred[1]), fmaxf(mred[2], mred[3]));
  float p = active ? expf(s_loc - m) : 0.f;
  float sw = wred_sum(p);
  if (lane == 0) sredS[w] = sw;
  if (active) { sp[tid] = p; srowS[tid] = row; }
  __syncthreads();
  float l = sredS[0] + sredS[1] + sredS[2] + sredS[3];

  float acc = 0.f;
  int j0 = w * 36;
#pragma unroll 4
  for (int jj = 0; jj < 36; jj++) {
    int j = j0 + jj;
    acc = fmaf(sp[j], vg[(size_t)srowS[j] * DIMM + h * HD + lane], acc);
  }
  pacc[w][lane] = acc;
  __syncthreads();
  if (w == 0) {
    float o = (pacc[0][lane] + pacc[1][lane] + pacc[2][lane] + pacc[3][lane]) / l;
    fout[(size_t)i * DIMM + h * HD + lane] = o;
  }
}

extern "C" void kernel_launch(void* const* d_in, const int* in_sizes, int n_in,
                              void* d_out, int out_size, void* d_ws, size_t ws_size,
                              hipStream_t stream) {
  const float* x     = (const float*)d_in[0];
  const float* ve    = (const float*)d_in[1]; (void)ve;
  const float* x0    = (const float*)d_in[2];
  const float* lam   = (const float*)d_in[3];
  const float* Wq    = (const float*)d_in[4];
  const float* Wk    = (const float*)d_in[5];
  const float* Wv    = (const float*)d_in[6];
  const float* Wo    = (const float*)d_in[7];
  const float* Wg    = (const float*)d_in[8];
  const float* k_pos = (const float*)d_in[9];
  const float* v_pos = (const float*)d_in[10];
  const float* Wck   = (const float*)d_in[11];
  const float* bck   = (const float*)d_in[12];
  const float* Wcv   = (const float*)d_in[13];
  const float* bcv   = (const float*)d_in[14];
  const float* k_mem = (const float*)d_in[15];
  const float* v_mem = (const float*)d_in[16];
  const float* W1    = (const float*)d_in[17];
  const float* W2    = (const float*)d_in[18];
  float* out = (float*)d_out;
  float* ws  = (float*)d_ws;

  const size_t NW = (size_t)NTOK * DIMM;   // 524288
  float* xr    = ws;
  float* xn    = ws + 1 * NW;
  float* q     = ws + 2 * NW;
  float* k     = ws + 3 * NW;
  float* v     = ws + 4 * NW;
  float* coutb = ws + 5 * NW;
  float* foutb = ws + 6 * NW;
  float* soutb = ws + 7 * NW;
  float* x2    = ws + 8 * NW;
  float* gates = ws + 9 * NW;               // 1024*24
  float* ckb   = gates + 32768;
  float* cvb   = ckb + 32768;
  int*   selb  = (int*)(cvb + 32768);
  ushort* qkvTh = (ushort*)(cvb + 32768 + 65536);  // 1600*512
  ushort* qkvTl = qkvTh + 1600 * 512;
  ushort* WoT   = qkvTl + 1600 * 512;
  ushort* W1T   = WoT   + 512 * 512;
  ushort* W2T   = W1T   + 2048 * 512;
  ushort* WckTh = W2T   + 512 * 2048;
  ushort* WckTl = WckTh + 64 * 1024;
  ushort* WcvTh = WckTl + 64 * 1024;
  ushort* WcvTl = WcvTh + 64 * 1024;
  float* y  = xr;   // reuse after Wo residual consumed xr
  float* h1 = q;    // f32 1024x2048, spans q..coutb after attention done

  // consolidated weight transposes
  WtrPack pk;
  pk.d[0] = {Wq, qkvTh,              qkvTl,              512, 512,  512};
  pk.d[1] = {Wk, qkvTh + 512 * 512,  qkvTl + 512 * 512,  512, 512,  512};
  pk.d[2] = {Wv, qkvTh + 1024 * 512, qkvTl + 1024 * 512, 512, 512,  512};
  pk.d[3] = {Wo, WoT, nullptr,  512, 512,  512};
  pk.d[4] = {W1, W1T, nullptr,  512, 2048, 2048};
  pk.d[5] = {W2, W2T, nullptr, 2048, 512,  512};
  pk.d[6] = {Wck, WckTh, WckTl, 1024, 64, 64};
  pk.d[7] = {Wcv, WcvTh, WcvTl, 1024, 64, 64};
  pk.d[8] = {Wg, qkvTh + 1536 * 512, qkvTl + 1536 * 512, 512, 24, 64};
  int cum = 0;
  for (int e = 0; e < 9; e++) {
    cum += (pk.d[e].Npad / 32) * (pk.d[e].K / 32);
    pk.cum[e] = cum;
  }
  k_wtr_all<<<cum, dim3(32, 8), 0, stream>>>(pk);

  k_resid_rms<<<NTOK, 256, 0, stream>>>(x, x0, lam, xr, xn);

  // fused QKV + gates
  k_gemm_qkv<<<dim3(25, NTOK / 64), 256, 0, stream>>>(
      xn, qkvTh, qkvTl, q, gates, 512);
  k_rope<<<(2 * NTOK * NH * 32) / 256, 256, 0, stream>>>(q, k);

  k_ckcv_m<<<dim3(NH, 2), 256, 0, stream>>>(k, v, k_pos, v_pos,
                                            WckTh, WckTl, WcvTh, WcvTl,
                                            bck, bcv, ckb, cvb);
  dim3 gT(NTOK / 16, NH);
  k_cmp<<<gT, 256, 0, stream>>>(q, ckb, cvb, k_mem, v_mem, coutb, selb);
  k_fine<<<dim3(NTOK, NH), 256, 0, stream>>>(q, k, v, selb, foutb);
  k_swin<<<gT, 256, 0, stream>>>(q, k, v, soutb);

  // Wo with fused gated combine
  k_gemm_wo<<<dim3(512 / 64, NTOK / 64), 256, 0, stream>>>(
      coutb, foutb, soutb, gates, WoT, xr, x2);

  k_rms<<<NTOK, 256, 0, stream>>>(x2, y);
  k_gemm_bf16<<<dim3(2048 / 64, NTOK / 64), 256, 0, stream>>>(
      y, W1T, nullptr, h1, 512, 2048, 1);
  k_gemm_bf16<<<dim3(512 / 64, NTOK / 64), 256, 0, stream>>>(
      h1, W2T, x2, out, 2048, 512, 0);
}

// Round 7
// 363.383 us; speedup vs baseline: 2.1874x; 1.0137x over previous
//
#include <hip/hip_runtime.h>
#include <math.h>

#define NTOK 1024
#define DIMM 512
#define NH 8
#define HD 64
#define BCB 16
#define BSB 16
#define KSEL 8
#define WWIN 256
#define CBLK 64
#define SCALE 0.125f
#define EPSV 1e-6f
#define NEGV -1e30f

typedef short bf16x8 __attribute__((ext_vector_type(8)));
typedef float f32x4 __attribute__((ext_vector_type(4)));

__device__ inline ushort f2b(float f) {
  union { float f; unsigned int u; } c; c.f = f;
  unsigned int u = c.u;
  return (ushort)((u + 0x7FFFu + ((u >> 16) & 1u)) >> 16);
}
__device__ inline float b2f(ushort h) {
  union { unsigned int u; float f; } c; c.u = ((unsigned int)h) << 16;
  return c.f;
}

__device__ inline float wred_max(float v) {
#pragma unroll
  for (int off = 1; off < 64; off <<= 1) v = fmaxf(v, __shfl_xor(v, off));
  return v;
}
__device__ inline float wred_sum(float v) {
#pragma unroll
  for (int off = 1; off < 64; off <<= 1) v += __shfl_xor(v, off);
  return v;
}

// ---------- residual mix + rmsnorm ----------
__global__ void __launch_bounds__(256)
k_resid_rms(const float* __restrict__ x, const float* __restrict__ x0,
            const float* __restrict__ lam, float* __restrict__ xr,
            float* __restrict__ xn) {
  int row = blockIdx.x, tid = threadIdx.x;
  float l0 = lam[0], l1 = lam[1];
  size_t b = (size_t)row * DIMM;
  float a0 = l0 * x[b + tid]       + l1 * x0[b + tid];
  float a1 = l0 * x[b + tid + 256] + l1 * x0[b + tid + 256];
  xr[b + tid] = a0; xr[b + tid + 256] = a1;
  float ss = a0 * a0 + a1 * a1;
  __shared__ float sm[8];
  for (int o = 32; o > 0; o >>= 1) ss += __shfl_down(ss, o);
  int lane = tid & 63, wid = tid >> 6;
  if (lane == 0) sm[wid] = ss;
  __syncthreads();
  if (tid == 0) {
    float s = sm[0] + sm[1] + sm[2] + sm[3];
    sm[0] = rsqrtf(s / (float)DIMM + EPSV);
  }
  __syncthreads();
  float r = sm[0];
  xn[b + tid] = a0 * r; xn[b + tid + 256] = a1 * r;
}

// ---------- plain rmsnorm ----------
__global__ void __launch_bounds__(256)
k_rms(const float* __restrict__ xin, float* __restrict__ y) {
  int row = blockIdx.x, tid = threadIdx.x;
  size_t b = (size_t)row * DIMM;
  float a0 = xin[b + tid], a1 = xin[b + tid + 256];
  float ss = a0 * a0 + a1 * a1;
  __shared__ float sm[8];
  for (int o = 32; o > 0; o >>= 1) ss += __shfl_down(ss, o);
  int lane = tid & 63, wid = tid >> 6;
  if (lane == 0) sm[wid] = ss;
  __syncthreads();
  if (tid == 0) {
    float s = sm[0] + sm[1] + sm[2] + sm[3];
    sm[0] = rsqrtf(s / (float)DIMM + EPSV);
  }
  __syncthreads();
  float r = sm[0];
  y[b + tid] = a0 * r; y[b + tid + 256] = a1 * r;
}

// ---------- consolidated weight transposes (f32 K×N -> bf16 hi/lo N×K) ----------
struct WtrDesc { const float* src; ushort* dh; ushort* dl; int K; int Nsrc; int Npad; };
struct WtrPack { WtrDesc d[9]; int cum[9]; };

__global__ void __launch_bounds__(256)
k_wtr_all(WtrPack pk) {
  int gb = blockIdx.x;
  int e = 0;
  while (gb >= pk.cum[e]) e++;
  int start = e ? pk.cum[e - 1] : 0;
  WtrDesc dd = pk.d[e];
  int local = gb - start;
  int XT = dd.Npad >> 5;
  int bx = local % XT, by = local / XT;
  __shared__ float t[32][33];
  int n0 = bx * 32, k0 = by * 32;
  int tx = threadIdx.x, ty = threadIdx.y;  // 32 x 8
#pragma unroll
  for (int i = 0; i < 32; i += 8)
    t[ty + i][tx] = (n0 + tx < dd.Nsrc)
        ? dd.src[(size_t)(k0 + ty + i) * dd.Nsrc + n0 + tx] : 0.f;
  __syncthreads();
#pragma unroll
  for (int i = 0; i < 32; i += 8) {
    float vv = t[tx][ty + i];
    ushort h = f2b(vv);
    size_t di = (size_t)(n0 + ty + i) * dd.K + k0 + tx;
    dd.dh[di] = h;
    if (dd.dl) dd.dl[di] = f2b(vv - b2f(h));
  }
}

// ---------- plain bf16 MFMA GEMM (W1 relu^2, W2 +Res) ----------
__global__ void __launch_bounds__(256)
k_gemm_bf16(const float* __restrict__ A, const ushort* __restrict__ BT,
            const float* __restrict__ Res, float* __restrict__ Co,
            int Kd, int Nd, int epi) {
  __shared__ ushort As[64 * 40];
  __shared__ ushort Bs[64 * 40];
  int tid = threadIdx.x;
  int lane = tid & 63, wave = tid >> 6;
  int rb = blockIdx.y * 64, cb = blockIdx.x * 64;
  int wm = (wave >> 1) * 32, wn = (wave & 1) * 32;
  int q = lane >> 4, l15 = lane & 15;
  int srow = tid >> 2, scol = (tid & 3) * 8;

  f32x4 acc[2][2];
#pragma unroll
  for (int i = 0; i < 2; i++)
#pragma unroll
    for (int j = 0; j < 2; j++) acc[i][j] = (f32x4){0.f, 0.f, 0.f, 0.f};

  const float*  ap = A  + (size_t)(rb + srow) * Kd + scol;
  const ushort* bp = BT + (size_t)(cb + srow) * Kd + scol;
  ushort* aw = &As[srow * 40 + scol];
  ushort* bw = &Bs[srow * 40 + scol];

  for (int k0 = 0; k0 < Kd; k0 += 32) {
    float4 a0 = *(const float4*)(ap + k0);
    float4 a1 = *(const float4*)(ap + k0 + 4);
    ushort h[8] = {f2b(a0.x), f2b(a0.y), f2b(a0.z), f2b(a0.w),
                   f2b(a1.x), f2b(a1.y), f2b(a1.z), f2b(a1.w)};
    *(int4*)aw = *(int4*)h;
    *(int4*)bw = *(const int4*)(bp + k0);
    __syncthreads();
    bf16x8 af[2], bfr[2];
#pragma unroll
    for (int t = 0; t < 2; t++) {
      af[t]  = *(const bf16x8*)&As[(wm + t * 16 + l15) * 40 + q * 8];
      bfr[t] = *(const bf16x8*)&Bs[(wn + t * 16 + l15) * 40 + q * 8];
    }
#pragma unroll
    for (int i = 0; i < 2; i++)
#pragma unroll
      for (int j = 0; j < 2; j++)
        acc[i][j] = __builtin_amdgcn_mfma_f32_16x16x32_bf16(af[i], bfr[j],
                                                            acc[i][j], 0, 0, 0);
    __syncthreads();
  }

#pragma unroll
  for (int i = 0; i < 2; i++) {
#pragma unroll
    for (int j = 0; j < 2; j++) {
      int col = cb + wn + j * 16 + l15;
#pragma unroll
      for (int r = 0; r < 4; r++) {
        int row = rb + wm + i * 16 + q * 4 + r;
        float vv = acc[i][j][r];
        if (epi == 1) { float t = fmaxf(vv, 0.f); vv = t * t; }
        if (Res) vv += Res[(size_t)row * Nd + col];
        Co[(size_t)row * Nd + col] = vv;
      }
    }
  }
}

// ---------- Wo GEMM with fused gated combine in A-staging ----------
__global__ void __launch_bounds__(256)
k_gemm_wo(const float* __restrict__ cg, const float* __restrict__ fg,
          const float* __restrict__ sg, const float* __restrict__ gates,
          const ushort* __restrict__ BT, const float* __restrict__ Res,
          float* __restrict__ Co) {
  __shared__ ushort As[64 * 40];
  __shared__ ushort Bs[64 * 40];
  int tid = threadIdx.x;
  int lane = tid & 63, wave = tid >> 6;
  int rb = blockIdx.y * 64, cb = blockIdx.x * 64;
  int wm = (wave >> 1) * 32, wn = (wave & 1) * 32;
  int q = lane >> 4, l15 = lane & 15;
  int srow = tid >> 2, scol = (tid & 3) * 8;

  f32x4 acc[2][2];
#pragma unroll
  for (int i = 0; i < 2; i++)
#pragma unroll
    for (int j = 0; j < 2; j++) acc[i][j] = (f32x4){0.f, 0.f, 0.f, 0.f};

  int row = rb + srow;
  const ushort* bp = BT + (size_t)(cb + srow) * 512 + scol;
  ushort* aw = &As[srow * 40 + scol];
  ushort* bw = &Bs[srow * 40 + scol];

  for (int k0 = 0; k0 < 512; k0 += 32) {
    int colb = k0 + scol;
    int hh = colb >> 6;
    const float* gp = gates + (size_t)row * 24 + hh * 3;
    float g0 = gp[0], g1 = gp[1], g2 = gp[2];
    size_t off = (size_t)row * 512 + colb;
    float4 c0 = *(const float4*)(cg + off), c1 = *(const float4*)(cg + off + 4);
    float4 f0 = *(const float4*)(fg + off), f1 = *(const float4*)(fg + off + 4);
    float4 s0 = *(const float4*)(sg + off), s1 = *(const float4*)(sg + off + 4);
    float va[8] = {g0 * c0.x + g1 * f0.x + g2 * s0.x,
                   g0 * c0.y + g1 * f0.y + g2 * s0.y,
                   g0 * c0.z + g1 * f0.z + g2 * s0.z,
                   g0 * c0.w + g1 * f0.w + g2 * s0.w,
                   g0 * c1.x + g1 * f1.x + g2 * s1.x,
                   g0 * c1.y + g1 * f1.y + g2 * s1.y,
                   g0 * c1.z + g1 * f1.z + g2 * s1.z,
                   g0 * c1.w + g1 * f1.w + g2 * s1.w};
    ushort h[8];
#pragma unroll
    for (int e = 0; e < 8; e++) h[e] = f2b(va[e]);
    *(int4*)aw = *(int4*)h;
    *(int4*)bw = *(const int4*)(bp + k0);
    __syncthreads();
    bf16x8 af[2], bfr[2];
#pragma unroll
    for (int t = 0; t < 2; t++) {
      af[t]  = *(const bf16x8*)&As[(wm + t * 16 + l15) * 40 + q * 8];
      bfr[t] = *(const bf16x8*)&Bs[(wn + t * 16 + l15) * 40 + q * 8];
    }
#pragma unroll
    for (int i = 0; i < 2; i++)
#pragma unroll
      for (int j = 0; j < 2; j++)
        acc[i][j] = __builtin_amdgcn_mfma_f32_16x16x32_bf16(af[i], bfr[j],
                                                            acc[i][j], 0, 0, 0);
    __syncthreads();
  }

#pragma unroll
  for (int i = 0; i < 2; i++) {
#pragma unroll
    for (int j = 0; j < 2; j++) {
      int col = cb + wn + j * 16 + l15;
#pragma unroll
      for (int r = 0; r < 4; r++) {
        int rr = rb + wm + i * 16 + q * 4 + r;
        Co[(size_t)rr * 512 + col] = acc[i][j][r] + Res[(size_t)rr * 512 + col];
      }
    }
  }
}

// ---------- split-bf16 MFMA GEMM (hi+lo): QKV + gates; v written head-major ----------
__global__ void __launch_bounds__(256)
k_gemm_qkv(const float* __restrict__ A, const ushort* __restrict__ BTh,
           const ushort* __restrict__ BTl, float* __restrict__ Co,
           float* __restrict__ vhm, float* __restrict__ gates, int Kd) {
  __shared__ ushort Ash[64 * 40];
  __shared__ ushort Asl[64 * 40];
  __shared__ ushort Bsh[64 * 40];
  __shared__ ushort Bsl[64 * 40];
  int tid = threadIdx.x;
  int lane = tid & 63, wave = tid >> 6;
  int rb = blockIdx.y * 64, cb = blockIdx.x * 64;
  int wm = (wave >> 1) * 32, wn = (wave & 1) * 32;
  int q = lane >> 4, l15 = lane & 15;
  int srow = tid >> 2, scol = (tid & 3) * 8;

  f32x4 acc[2][2];
#pragma unroll
  for (int i = 0; i < 2; i++)
#pragma unroll
    for (int j = 0; j < 2; j++) acc[i][j] = (f32x4){0.f, 0.f, 0.f, 0.f};

  const float*  ap  = A   + (size_t)(rb + srow) * Kd + scol;
  const ushort* bph = BTh + (size_t)(cb + srow) * Kd + scol;
  const ushort* bpl = BTl + (size_t)(cb + srow) * Kd + scol;
  ushort* awh = &Ash[srow * 40 + scol];
  ushort* awl = &Asl[srow * 40 + scol];
  ushort* bwh = &Bsh[srow * 40 + scol];
  ushort* bwl = &Bsl[srow * 40 + scol];

  for (int k0 = 0; k0 < Kd; k0 += 32) {
    float4 a0 = *(const float4*)(ap + k0);
    float4 a1 = *(const float4*)(ap + k0 + 4);
    float va[8] = {a0.x, a0.y, a0.z, a0.w, a1.x, a1.y, a1.z, a1.w};
    ushort hh[8], hl[8];
#pragma unroll
    for (int e = 0; e < 8; e++) {
      hh[e] = f2b(va[e]);
      hl[e] = f2b(va[e] - b2f(hh[e]));
    }
    *(int4*)awh = *(int4*)hh;
    *(int4*)awl = *(int4*)hl;
    *(int4*)bwh = *(const int4*)(bph + k0);
    *(int4*)bwl = *(const int4*)(bpl + k0);
    __syncthreads();
    bf16x8 afh[2], afl[2], bfh[2], bfl[2];
#pragma unroll
    for (int t = 0; t < 2; t++) {
      int ar = (wm + t * 16 + l15) * 40 + q * 8;
      int br = (wn + t * 16 + l15) * 40 + q * 8;
      afh[t] = *(const bf16x8*)&Ash[ar];
      afl[t] = *(const bf16x8*)&Asl[ar];
      bfh[t] = *(const bf16x8*)&Bsh[br];
      bfl[t] = *(const bf16x8*)&Bsl[br];
    }
#pragma unroll
    for (int i = 0; i < 2; i++)
#pragma unroll
      for (int j = 0; j < 2; j++) {
        acc[i][j] = __builtin_amdgcn_mfma_f32_16x16x32_bf16(afh[i], bfh[j],
                                                            acc[i][j], 0, 0, 0);
        acc[i][j] = __builtin_amdgcn_mfma_f32_16x16x32_bf16(afh[i], bfl[j],
                                                            acc[i][j], 0, 0, 0);
        acc[i][j] = __builtin_amdgcn_mfma_f32_16x16x32_bf16(afl[i], bfh[j],
                                                            acc[i][j], 0, 0, 0);
      }
    __syncthreads();
  }

  const size_t NW = (size_t)NTOK * DIMM;
#pragma unroll
  for (int i = 0; i < 2; i++) {
#pragma unroll
    for (int j = 0; j < 2; j++) {
      int col = cb + wn + j * 16 + l15;
#pragma unroll
      for (int r = 0; r < 4; r++) {
        int row = rb + wm + i * 16 + q * 4 + r;
        float vv = acc[i][j][r];
        if (cb >= 1536) {
          int c24 = col - 1536;
          if (c24 < 24)
            gates[(size_t)row * 24 + c24] = 1.f / (1.f + expf(-vv));
        } else if (col >= 1024) {
          int c = col - 1024;   // v plane -> head-major
          vhm[(size_t)(c >> 6) * 65536 + (size_t)row * 64 + (c & 63)] = vv;
        } else {
          Co[(size_t)(col >> 9) * NW + (size_t)row * 512 + (col & 511)] = vv;
        }
      }
    }
  }
}

// ---------- RoPE: q in-place (token-major); k -> khm (head-major) ----------
__global__ void __launch_bounds__(256)
k_rope(float* __restrict__ q, const float* __restrict__ k,
       float* __restrict__ khm) {
  int idx = blockIdx.x * 256 + threadIdx.x;
  int ten = idx >> 18;
  int r = idx & 262143;
  int j = r & 31;
  int h = (r >> 5) & 7;
  int n = r >> 8;
  float inv = powf(10000.f, -(float)j / 32.f);
  float ang = (float)n * inv;
  float sn, cs;
  sincosf(ang, &sn, &cs);
  size_t base = (size_t)n * DIMM + h * HD + j;
  if (ten == 0) {
    float x1 = q[base], x2 = q[base + 32];
    q[base] = x1 * cs - x2 * sn;
    q[base + 32] = x2 * cs + x1 * sn;
  } else {
    float x1 = k[base], x2 = k[base + 32];
    size_t ob = (size_t)h * 65536 + (size_t)n * 64 + j;
    khm[ob] = x1 * cs - x2 * sn;
    khm[ob + 32] = x2 * cs + x1 * sn;
  }
}

// ---------- compressed k/v via MFMA hi/lo (head-major inputs) ----------
__global__ void __launch_bounds__(256)
k_ckcv_m(const float* __restrict__ khm, const float* __restrict__ vhm,
         const float* __restrict__ k_pos, const float* __restrict__ v_pos,
         const ushort* __restrict__ WckTh, const ushort* __restrict__ WckTl,
         const ushort* __restrict__ WcvTh, const ushort* __restrict__ WcvTl,
         const float* __restrict__ bck, const float* __restrict__ bcv,
         float* __restrict__ ckb, float* __restrict__ cvb) {
  int h = blockIdx.x, kv = blockIdx.y;
  const float* src = kv ? vhm : khm;
  const float* pos = kv ? v_pos : k_pos;
  const ushort* WTh = kv ? WcvTh : WckTh;
  const ushort* WTl = kv ? WcvTl : WckTl;
  const float* bias = kv ? bcv : bck;
  float* outp = kv ? cvb : ckb;

  __shared__ ushort Ash[64 * 72], Asl[64 * 72];
  __shared__ ushort Bsh[64 * 72], Bsl[64 * 72];
  int tid = threadIdx.x;
  int lane = tid & 63, wave = tid >> 6;
  int wm = (wave >> 1) * 32, wn = (wave & 1) * 32;
  int q = lane >> 4, l15 = lane & 15;
  int srow = tid >> 2;
  int e0 = (tid & 3) * 16;

  f32x4 acc[2][2];
#pragma unroll
  for (int i = 0; i < 2; i++)
#pragma unroll
    for (int j = 0; j < 2; j++) acc[i][j] = (f32x4){0.f, 0.f, 0.f, 0.f};

  for (int t = 0; t < 16; t++) {
    const float* ar = src + (size_t)h * 65536 + (size_t)(srow * 16 + t) * 64 + e0;
    const float* pr = pos + (size_t)(h * 16 + t) * HD + e0;
    ushort hh[16], hl[16];
#pragma unroll
    for (int u = 0; u < 4; u++) {
      float4 av = *(const float4*)(ar + u * 4);
      float4 pv = *(const float4*)(pr + u * 4);
      float vals[4] = {av.x + pv.x, av.y + pv.y, av.z + pv.z, av.w + pv.w};
#pragma unroll
      for (int e = 0; e < 4; e++) {
        ushort hb = f2b(vals[e]);
        hh[u * 4 + e] = hb;
        hl[u * 4 + e] = f2b(vals[e] - b2f(hb));
      }
    }
    *(int4*)&Ash[srow * 72 + e0]     = *(int4*)&hh[0];
    *(int4*)&Ash[srow * 72 + e0 + 8] = *(int4*)&hh[8];
    *(int4*)&Asl[srow * 72 + e0]     = *(int4*)&hl[0];
    *(int4*)&Asl[srow * 72 + e0 + 8] = *(int4*)&hl[8];
    const ushort* bh = WTh + (size_t)srow * 1024 + t * 64 + e0;
    const ushort* bl = WTl + (size_t)srow * 1024 + t * 64 + e0;
    *(int4*)&Bsh[srow * 72 + e0]     = *(const int4*)bh;
    *(int4*)&Bsh[srow * 72 + e0 + 8] = *(const int4*)(bh + 8);
    *(int4*)&Bsl[srow * 72 + e0]     = *(const int4*)bl;
    *(int4*)&Bsl[srow * 72 + e0 + 8] = *(const int4*)(bl + 8);
    __syncthreads();
#pragma unroll
    for (int sub = 0; sub < 2; sub++) {
      bf16x8 afh[2], afl[2], bfh[2], bfl[2];
#pragma unroll
      for (int ti = 0; ti < 2; ti++) {
        int ar2 = (wm + ti * 16 + l15) * 72 + sub * 32 + q * 8;
        int br2 = (wn + ti * 16 + l15) * 72 + sub * 32 + q * 8;
        afh[ti] = *(const bf16x8*)&Ash[ar2];
        afl[ti] = *(const bf16x8*)&Asl[ar2];
        bfh[ti] = *(const bf16x8*)&Bsh[br2];
        bfl[ti] = *(const bf16x8*)&Bsl[br2];
      }
#pragma unroll
      for (int i = 0; i < 2; i++)
#pragma unroll
        for (int j = 0; j < 2; j++) {
          acc[i][j] = __builtin_amdgcn_mfma_f32_16x16x32_bf16(afh[i], bfh[j],
                                                              acc[i][j], 0, 0, 0);
          acc[i][j] = __builtin_amdgcn_mfma_f32_16x16x32_bf16(afh[i], bfl[j],
                                                              acc[i][j], 0, 0, 0);
          acc[i][j] = __builtin_amdgcn_mfma_f32_16x16x32_bf16(afl[i], bfh[j],
                                                              acc[i][j], 0, 0, 0);
        }
    }
    __syncthreads();
  }

#pragma unroll
  for (int i = 0; i < 2; i++) {
#pragma unroll
    for (int j = 0; j < 2; j++) {
      int d = wn + j * 16 + l15;
      float bv = bias[d];
#pragma unroll
      for (int r = 0; r < 4; r++) {
        int c = wm + i * 16 + q * 4 + r;
        outp[((size_t)h * 64 + c) * 64 + d] = acc[i][j][r] + bv;
      }
    }
  }
}

// ---------- fused compressed-attention(+top8) / sliding-window ----------
__global__ void __launch_bounds__(256)
k_attn_cs(const float* __restrict__ qg, const float* __restrict__ khm,
          const float* __restrict__ vhm, const float* __restrict__ ckb,
          const float* __restrict__ cvb, const float* __restrict__ k_mem,
          const float* __restrict__ v_mem, float* __restrict__ cout,
          int* __restrict__ sel, float* __restrict__ sout) {
  __shared__ float U[9728];          // union: M0[64*65] M1[64*65] QS[16*64] KM[64] VM[64] SP[4*64]
  float* M0 = U;
  float* M1 = U + 4160;
  float* QS = U + 8320;
  float* KM = U + 9344;
  float* VM = U + 9408;
  float* SP = U + 9472;
  int h = blockIdx.y;
  int tid = threadIdx.x, lane = tid & 63, w = tid >> 6;

  if (blockIdx.x < 64) {
    // ---- compressed branch ----
    int i0 = blockIdx.x * 16;
#pragma unroll
    for (int r = 0; r < 4; r++) {
      int f = r * 256 + tid;
      int c = f >> 4, d0 = (f & 15) * 4;
      float4 t = *(const float4*)(ckb + ((size_t)h * 64 + c) * 64 + d0);
      M0[d0 * 65 + c] = t.x; M0[(d0 + 1) * 65 + c] = t.y;
      M0[(d0 + 2) * 65 + c] = t.z; M0[(d0 + 3) * 65 + c] = t.w;
      float4 u = *(const float4*)(cvb + ((size_t)h * 64 + c) * 64 + d0);
      M1[c * 65 + d0] = u.x; M1[c * 65 + d0 + 1] = u.y;
      M1[c * 65 + d0 + 2] = u.z; M1[c * 65 + d0 + 3] = u.w;
    }
    {
      int r = tid >> 4, d0 = (tid & 15) * 4;
      float4 t = *(const float4*)(qg + (size_t)(i0 + r) * DIMM + h * HD + d0);
      QS[r * 64 + d0] = t.x; QS[r * 64 + d0 + 1] = t.y;
      QS[r * 64 + d0 + 2] = t.z; QS[r * 64 + d0 + 3] = t.w;
    }
    if (tid < 64) KM[tid] = k_mem[h * HD + tid];
    else if (tid < 128) VM[tid - 64] = v_mem[h * HD + tid - 64];
    __syncthreads();

    for (int s = 0; s < 4; s++) {
      int ql = w * 4 + s, qi = i0 + ql;
      float dot = 0.f, dm = 0.f;
#pragma unroll 8
      for (int e = 0; e < 64; e++) {
        float qe = QS[ql * 64 + e];
        dot = fmaf(qe, M0[e * 65 + lane], dot);
        dm  = fmaf(qe, KM[e], dm);
      }
      bool vis = (lane * BCB + BCB - 1) < qi;
      float sj = vis ? dot * SCALE : NEGV;
      float smem = dm * SCALE;
      float m = wred_max(fmaxf(sj, smem));
      float p = expf(sj - m);
      float pmem = expf(smem - m);
      float l = wred_sum(p) + pmem;
      float inv = 1.f / l;

      float impv = vis ? p : NEGV;
#pragma unroll
      for (int kk = 0; kk < KSEL; kk++) {
        float bv = impv; int bi = lane;
#pragma unroll
        for (int off = 32; off > 0; off >>= 1) {
          float ov = __shfl_xor(bv, off);
          int   oi = __shfl_xor(bi, off);
          if (ov > bv || (ov == bv && oi < bi)) { bv = ov; bi = oi; }
        }
        if (lane == 0) sel[((size_t)h * NTOK + qi) * KSEL + kk] = (bv >= 0.f) ? bi : -1;
        if (lane == bi) impv = NEGV;
      }

      SP[w * 64 + lane] = p;
      __syncthreads();
      float od = pmem * VM[lane];
#pragma unroll 8
      for (int j = 0; j < 64; j++) od = fmaf(SP[w * 64 + j], M1[j * 65 + lane], od);
      cout[(size_t)qi * DIMM + h * HD + lane] = od * inv;
      __syncthreads();
    }
  } else {
    // ---- sliding-window branch ----
    int i0 = (blockIdx.x - 64) * 16;
    {
      int r = tid >> 4, d0 = (tid & 15) * 4;
      float4 t = *(const float4*)(qg + (size_t)(i0 + r) * DIMM + h * HD + d0);
      QS[r * 64 + d0] = t.x; QS[r * 64 + d0 + 1] = t.y;
      QS[r * 64 + d0 + 2] = t.z; QS[r * 64 + d0 + 3] = t.w;
    }
    int lo = i0 - (WWIN - 1); if (lo < 0) lo = 0;
    int jb_lo = lo >> 6, jb_hi = (i0 + 15) >> 6;

    float mrow[4], lrow[4], orow[4];
#pragma unroll
    for (int s = 0; s < 4; s++) { mrow[s] = NEGV; lrow[s] = 0.f; orow[s] = 0.f; }

    for (int jb = jb_lo; jb <= jb_hi; jb++) {
      __syncthreads();
#pragma unroll
      for (int r = 0; r < 4; r++) {
        int f = r * 256 + tid;
        int c = f >> 4, d0 = (f & 15) * 4;
        float4 t = *(const float4*)(khm + (size_t)h * 65536 + jb * 4096 + f * 4);
        M0[d0 * 65 + c] = t.x; M0[(d0 + 1) * 65 + c] = t.y;
        M0[(d0 + 2) * 65 + c] = t.z; M0[(d0 + 3) * 65 + c] = t.w;
        float4 u = *(const float4*)(vhm + (size_t)h * 65536 + jb * 4096 + f * 4);
        M1[c * 65 + d0] = u.x; M1[c * 65 + d0 + 1] = u.y;
        M1[c * 65 + d0 + 2] = u.z; M1[c * 65 + d0 + 3] = u.w;
      }
      __syncthreads();

      for (int s = 0; s < 4; s++) {
        int ql = w * 4 + s, qi = i0 + ql;
        float dot = 0.f;
#pragma unroll 8
        for (int e = 0; e < 64; e++) dot = fmaf(QS[ql * 64 + e], M0[e * 65 + lane], dot);
        int gj = jb * 64 + lane;
        bool vis = (gj <= qi) && (qi - gj < WWIN);
        float sj = vis ? dot * SCALE : NEGV;
        float tm = wred_max(sj);
        float newm = fmaxf(mrow[s], tm);
        float p = vis ? expf(sj - newm) : 0.f;
        float ts = wred_sum(p);
        float alpha = expf(mrow[s] - newm);
        SP[w * 64 + lane] = p;
        __syncthreads();
        float acc = 0.f;
#pragma unroll 8
        for (int j = 0; j < 64; j++) acc = fmaf(SP[w * 64 + j], M1[j * 65 + lane], acc);
        orow[s] = orow[s] * alpha + acc;
        lrow[s] = lrow[s] * alpha + ts;
        mrow[s] = newm;
        __syncthreads();
      }
    }
#pragma unroll
    for (int s = 0; s < 4; s++) {
      int qi = i0 + w * 4 + s;
      sout[(size_t)qi * DIMM + h * HD + lane] = orow[s] / lrow[s];
    }
  }
}

// ---------- fine attention: direct QK gather + bf16 V staged in LDS ----------
__global__ void __launch_bounds__(256)
k_fine(const float* __restrict__ qg, const float* __restrict__ khm,
       const float* __restrict__ vhm, const int* __restrict__ sel,
       float* __restrict__ fout) {
  int i = blockIdx.x, h = blockIdx.y;
  int tid = threadIdx.x, lane = tid & 63, w = tid >> 6;
  __shared__ float qsh[64];
  __shared__ ushort vsb[144 * 64];
  __shared__ float sp[144];
  __shared__ int selS[8];
  __shared__ float mred[4], sredS[4];
  __shared__ float pacc[4][64];

  int own = i >> 4;
  if (tid < 64) qsh[tid] = qg[(size_t)i * DIMM + h * HD + tid];
  if (tid >= 64 && tid < 72)
    selS[tid - 64] = sel[((size_t)h * NTOK + i) * KSEL + tid - 64];
  __syncthreads();

  const float* kbase = khm + (size_t)h * 65536;
  const float* vbase = vhm + (size_t)h * 65536;

  // stage v rows as bf16 (addresses known pre-softmax; latency hides under QK)
#pragma unroll
  for (int it = 0; it < 9; it++) {
    int idx = it * 256 + tid;
    int row = idx >> 4, c4 = (idx & 15) * 4;
    int kk = row >> 4;
    int bidx = (kk < KSEL) ? selS[kk] : own;
    if (bidx < 0) bidx = 0;
    float4 t = *(const float4*)(vbase + (size_t)(bidx * BSB + (row & 15)) * 64 + c4);
    ushort4 u = {f2b(t.x), f2b(t.y), f2b(t.z), f2b(t.w)};
    *(ushort4*)&vsb[row * 64 + c4] = u;
  }

  float s_loc = NEGV;
  bool active = (tid < 144);
  if (active) {
    int kk = tid >> 4;
    int bidx; bool vis;
    if (kk < KSEL) {
      bidx = selS[kk];
      vis = (bidx >= 0);
      if (!vis) bidx = 0;
    } else {
      bidx = own;
      vis = (tid - 128) <= (i & 15);
    }
    const float* kr = kbase + (size_t)(bidx * BSB + (tid & 15)) * 64;
    float dot = 0.f;
#pragma unroll
    for (int e4 = 0; e4 < 16; e4++) {
      float4 kv = *(const float4*)(kr + e4 * 4);
      float4 qv = *(const float4*)&qsh[e4 * 4];
      dot = fmaf(qv.x, kv.x, dot); dot = fmaf(qv.y, kv.y, dot);
      dot = fmaf(qv.z, kv.z, dot); dot = fmaf(qv.w, kv.w, dot);
    }
    s_loc = vis ? dot * SCALE : NEGV;
  }
  float mw = wred_max(s_loc);
  if (lane == 0) mred[w] = mw;
  __syncthreads();
  float m = fmaxf(fmaxf(mred[0], mred[1]), fmaxf(mred[2], mred[3]));
  float p = active ? expf(s_loc - m) : 0.f;
  float sw = wred_sum(p);
  if (lane == 0) sredS[w] = sw;
  if (active) sp[tid] = p;
  __syncthreads();
  float l = sredS[0] + sredS[1] + sredS[2] + sredS[3];

  float acc = 0.f;
  int j0 = w * 36;
#pragma unroll 6
  for (int jj = 0; jj < 36; jj++) {
    int j = j0 + jj;
    acc = fmaf(sp[j], b2f(vsb[j * 64 + lane]), acc);
  }
  pacc[w][lane] = acc;
  __syncthreads();
  if (w == 0)
    fout[(size_t)i * DIMM + h * HD + lane] =
        (pacc[0][lane] + pacc[1][lane] + pacc[2][lane] + pacc[3][lane]) / l;
}

extern "C" void kernel_launch(void* const* d_in, const int* in_sizes, int n_in,
                              void* d_out, int out_size, void* d_ws, size_t ws_size,
                              hipStream_t stream) {
  const float* x     = (const float*)d_in[0];
  const float* ve    = (const float*)d_in[1]; (void)ve;
  const float* x0    = (const float*)d_in[2];
  const float* lam   = (const float*)d_in[3];
  const float* Wq    = (const float*)d_in[4];
  const float* Wk    = (const float*)d_in[5];
  const float* Wv    = (const float*)d_in[6];
  const float* Wo    = (const float*)d_in[7];
  const float* Wg    = (const float*)d_in[8];
  const float* k_pos = (const float*)d_in[9];
  const float* v_pos = (const float*)d_in[10];
  const float* Wck   = (const float*)d_in[11];
  const float* bck   = (const float*)d_in[12];
  const float* Wcv   = (const float*)d_in[13];
  const float* bcv   = (const float*)d_in[14];
  const float* k_mem = (const float*)d_in[15];
  const float* v_mem = (const float*)d_in[16];
  const float* W1    = (const float*)d_in[17];
  const float* W2    = (const float*)d_in[18];
  float* out = (float*)d_out;
  float* ws  = (float*)d_ws;

  const size_t NW = (size_t)NTOK * DIMM;   // 524288
  float* xr    = ws;
  float* xn    = ws + 1 * NW;
  float* q     = ws + 2 * NW;
  float* k     = ws + 3 * NW;     // token-major k (dead after rope)
  float* vhm   = ws + 4 * NW;     // head-major v (written by QKV epilogue)
  float* coutb = ws + 5 * NW;
  float* foutb = ws + 6 * NW;
  float* soutb = ws + 7 * NW;
  float* x2    = ws + 8 * NW;     // khm until gemm_wo overwrites as x2
  float* khm   = x2;
  float* gates = ws + 9 * NW;
  float* ckb   = gates + 32768;
  float* cvb   = ckb + 32768;
  int*   selb  = (int*)(cvb + 32768);
  ushort* qkvTh = (ushort*)(cvb + 32768 + 65536);
  ushort* qkvTl = qkvTh + 1600 * 512;
  ushort* WoT   = qkvTl + 1600 * 512;
  ushort* W1T   = WoT   + 512 * 512;
  ushort* W2T   = W1T   + 2048 * 512;
  ushort* WckTh = W2T   + 512 * 2048;
  ushort* WckTl = WckTh + 64 * 1024;
  ushort* WcvTh = WckTl + 64 * 1024;
  ushort* WcvTl = WcvTh + 64 * 1024;
  float* y  = xr;   // reuse after Wo residual consumed xr
  float* h1 = q;    // f32 1024x2048 spans q,k,vhm,coutb (all dead post-Wo)

  WtrPack pk;
  pk.d[0] = {Wq, qkvTh,              qkvTl,              512, 512,  512};
  pk.d[1] = {Wk, qkvTh + 512 * 512,  qkvTl + 512 * 512,  512, 512,  512};
  pk.d[2] = {Wv, qkvTh + 1024 * 512, qkvTl + 1024 * 512, 512, 512,  512};
  pk.d[3] = {Wo, WoT, nullptr,  512, 512,  512};
  pk.d[4] = {W1, W1T, nullptr,  512, 2048, 2048};
  pk.d[5] = {W2, W2T, nullptr, 2048, 512,  512};
  pk.d[6] = {Wck, WckTh, WckTl, 1024, 64, 64};
  pk.d[7] = {Wcv, WcvTh, WcvTl, 1024, 64, 64};
  pk.d[8] = {Wg, qkvTh + 1536 * 512, qkvTl + 1536 * 512, 512, 24, 64};
  int cum = 0;
  for (int e = 0; e < 9; e++) {
    cum += (pk.d[e].Npad / 32) * (pk.d[e].K / 32);
    pk.cum[e] = cum;
  }
  k_wtr_all<<<cum, dim3(32, 8), 0, stream>>>(pk);

  k_resid_rms<<<NTOK, 256, 0, stream>>>(x, x0, lam, xr, xn);

  k_gemm_qkv<<<dim3(25, NTOK / 64), 256, 0, stream>>>(
      xn, qkvTh, qkvTl, q, vhm, gates, 512);
  k_rope<<<(2 * NTOK * NH * 32) / 256, 256, 0, stream>>>(q, k, khm);

  k_ckcv_m<<<dim3(NH, 2), 256, 0, stream>>>(khm, vhm, k_pos, v_pos,
                                            WckTh, WckTl, WcvTh, WcvTl,
                                            bck, bcv, ckb, cvb);
  k_attn_cs<<<dim3(128, NH), 256, 0, stream>>>(q, khm, vhm, ckb, cvb,
                                               k_mem, v_mem, coutb, selb, soutb);
  k_fine<<<dim3(NTOK, NH), 256, 0, stream>>>(q, khm, vhm, selb, foutb);

  k_gemm_wo<<<dim3(512 / 64, NTOK / 64), 256, 0, stream>>>(
      coutb, foutb, soutb, gates, WoT, xr, x2);

  k_rms<<<NTOK, 256, 0, stream>>>(x2, y);
  k_gemm_bf16<<<dim3(2048 / 64, NTOK / 64), 256, 0, stream>>>(
      y, W1T, nullptr, h1, 512, 2048, 1);
  k_gemm_bf16<<<dim3(512 / 64, NTOK / 64), 256, 0, stream>>>(
      h1, W2T, x2, out, 2048, 512, 0);
}

// Round 8
// 341.177 us; speedup vs baseline: 2.3297x; 1.0651x over previous
//
#include <hip/hip_runtime.h>
#include <math.h>

#define NTOK 1024
#define DIMM 512
#define NH 8
#define HD 64
#define BCB 16
#define BSB 16
#define KSEL 8
#define WWIN 256
#define CBLK 64
#define SCALE 0.125f
#define EPSV 1e-6f
#define NEGV -1e30f

typedef short bf16x8 __attribute__((ext_vector_type(8)));
typedef float f32x4 __attribute__((ext_vector_type(4)));

__device__ inline ushort f2b(float f) {
  union { float f; unsigned int u; } c; c.f = f;
  unsigned int u = c.u;
  return (ushort)((u + 0x7FFFu + ((u >> 16) & 1u)) >> 16);
}
__device__ inline float b2f(ushort h) {
  union { unsigned int u; float f; } c; c.u = ((unsigned int)h) << 16;
  return c.f;
}

__device__ inline float wred_max(float v) {
#pragma unroll
  for (int off = 1; off < 64; off <<= 1) v = fmaxf(v, __shfl_xor(v, off));
  return v;
}
__device__ inline float wred_sum(float v) {
#pragma unroll
  for (int off = 1; off < 64; off <<= 1) v += __shfl_xor(v, off);
  return v;
}

// ---------- residual mix + rmsnorm ----------
__global__ void __launch_bounds__(256)
k_resid_rms(const float* __restrict__ x, const float* __restrict__ x0,
            const float* __restrict__ lam, float* __restrict__ xr,
            float* __restrict__ xn) {
  int row = blockIdx.x, tid = threadIdx.x;
  float l0 = lam[0], l1 = lam[1];
  size_t b = (size_t)row * DIMM;
  float a0 = l0 * x[b + tid]       + l1 * x0[b + tid];
  float a1 = l0 * x[b + tid + 256] + l1 * x0[b + tid + 256];
  xr[b + tid] = a0; xr[b + tid + 256] = a1;
  float ss = a0 * a0 + a1 * a1;
  __shared__ float sm[8];
  for (int o = 32; o > 0; o >>= 1) ss += __shfl_down(ss, o);
  int lane = tid & 63, wid = tid >> 6;
  if (lane == 0) sm[wid] = ss;
  __syncthreads();
  if (tid == 0) {
    float s = sm[0] + sm[1] + sm[2] + sm[3];
    sm[0] = rsqrtf(s / (float)DIMM + EPSV);
  }
  __syncthreads();
  float r = sm[0];
  xn[b + tid] = a0 * r; xn[b + tid + 256] = a1 * r;
}

// ---------- plain rmsnorm ----------
__global__ void __launch_bounds__(256)
k_rms(const float* __restrict__ xin, float* __restrict__ y) {
  int row = blockIdx.x, tid = threadIdx.x;
  size_t b = (size_t)row * DIMM;
  float a0 = xin[b + tid], a1 = xin[b + tid + 256];
  float ss = a0 * a0 + a1 * a1;
  __shared__ float sm[8];
  for (int o = 32; o > 0; o >>= 1) ss += __shfl_down(ss, o);
  int lane = tid & 63, wid = tid >> 6;
  if (lane == 0) sm[wid] = ss;
  __syncthreads();
  if (tid == 0) {
    float s = sm[0] + sm[1] + sm[2] + sm[3];
    sm[0] = rsqrtf(s / (float)DIMM + EPSV);
  }
  __syncthreads();
  float r = sm[0];
  y[b + tid] = a0 * r; y[b + tid + 256] = a1 * r;
}

// ---------- consolidated weight transposes (f32 K×N -> bf16 hi/lo N×K) ----------
struct WtrDesc { const float* src; ushort* dh; ushort* dl; int K; int Nsrc; int Npad; };
struct WtrPack { WtrDesc d[9]; int cum[9]; };

__global__ void __launch_bounds__(256)
k_wtr_all(WtrPack pk) {
  int gb = blockIdx.x;
  int e = 0;
  while (gb >= pk.cum[e]) e++;
  int start = e ? pk.cum[e - 1] : 0;
  WtrDesc dd = pk.d[e];
  int local = gb - start;
  int XT = dd.Npad >> 5;
  int bx = local % XT, by = local / XT;
  __shared__ float t[32][33];
  int n0 = bx * 32, k0 = by * 32;
  int tx = threadIdx.x, ty = threadIdx.y;  // 32 x 8
#pragma unroll
  for (int i = 0; i < 32; i += 8)
    t[ty + i][tx] = (n0 + tx < dd.Nsrc)
        ? dd.src[(size_t)(k0 + ty + i) * dd.Nsrc + n0 + tx] : 0.f;
  __syncthreads();
#pragma unroll
  for (int i = 0; i < 32; i += 8) {
    float vv = t[tx][ty + i];
    ushort h = f2b(vv);
    size_t di = (size_t)(n0 + ty + i) * dd.K + k0 + tx;
    dd.dh[di] = h;
    if (dd.dl) dd.dl[di] = f2b(vv - b2f(h));
  }
}

// ---------- plain bf16 MFMA GEMM (W1 relu^2, W2 +Res) ----------
__global__ void __launch_bounds__(256)
k_gemm_bf16(const float* __restrict__ A, const ushort* __restrict__ BT,
            const float* __restrict__ Res, float* __restrict__ Co,
            int Kd, int Nd, int epi) {
  __shared__ ushort As[64 * 40];
  __shared__ ushort Bs[64 * 40];
  int tid = threadIdx.x;
  int lane = tid & 63, wave = tid >> 6;
  int rb = blockIdx.y * 64, cb = blockIdx.x * 64;
  int wm = (wave >> 1) * 32, wn = (wave & 1) * 32;
  int q = lane >> 4, l15 = lane & 15;
  int srow = tid >> 2, scol = (tid & 3) * 8;

  f32x4 acc[2][2];
#pragma unroll
  for (int i = 0; i < 2; i++)
#pragma unroll
    for (int j = 0; j < 2; j++) acc[i][j] = (f32x4){0.f, 0.f, 0.f, 0.f};

  const float*  ap = A  + (size_t)(rb + srow) * Kd + scol;
  const ushort* bp = BT + (size_t)(cb + srow) * Kd + scol;
  ushort* aw = &As[srow * 40 + scol];
  ushort* bw = &Bs[srow * 40 + scol];

  for (int k0 = 0; k0 < Kd; k0 += 32) {
    float4 a0 = *(const float4*)(ap + k0);
    float4 a1 = *(const float4*)(ap + k0 + 4);
    ushort h[8] = {f2b(a0.x), f2b(a0.y), f2b(a0.z), f2b(a0.w),
                   f2b(a1.x), f2b(a1.y), f2b(a1.z), f2b(a1.w)};
    *(int4*)aw = *(int4*)h;
    *(int4*)bw = *(const int4*)(bp + k0);
    __syncthreads();
    bf16x8 af[2], bfr[2];
#pragma unroll
    for (int t = 0; t < 2; t++) {
      af[t]  = *(const bf16x8*)&As[(wm + t * 16 + l15) * 40 + q * 8];
      bfr[t] = *(const bf16x8*)&Bs[(wn + t * 16 + l15) * 40 + q * 8];
    }
#pragma unroll
    for (int i = 0; i < 2; i++)
#pragma unroll
      for (int j = 0; j < 2; j++)
        acc[i][j] = __builtin_amdgcn_mfma_f32_16x16x32_bf16(af[i], bfr[j],
                                                            acc[i][j], 0, 0, 0);
    __syncthreads();
  }

#pragma unroll
  for (int i = 0; i < 2; i++) {
#pragma unroll
    for (int j = 0; j < 2; j++) {
      int col = cb + wn + j * 16 + l15;
#pragma unroll
      for (int r = 0; r < 4; r++) {
        int row = rb + wm + i * 16 + q * 4 + r;
        float vv = acc[i][j][r];
        if (epi == 1) { float t = fmaxf(vv, 0.f); vv = t * t; }
        if (Res) vv += Res[(size_t)row * Nd + col];
        Co[(size_t)row * Nd + col] = vv;
      }
    }
  }
}

// ---------- Wo GEMM with fused gated combine in A-staging ----------
__global__ void __launch_bounds__(256)
k_gemm_wo(const float* __restrict__ cg, const float* __restrict__ fg,
          const float* __restrict__ sg, const float* __restrict__ gates,
          const ushort* __restrict__ BT, const float* __restrict__ Res,
          float* __restrict__ Co) {
  __shared__ ushort As[64 * 40];
  __shared__ ushort Bs[64 * 40];
  int tid = threadIdx.x;
  int lane = tid & 63, wave = tid >> 6;
  int rb = blockIdx.y * 64, cb = blockIdx.x * 64;
  int wm = (wave >> 1) * 32, wn = (wave & 1) * 32;
  int q = lane >> 4, l15 = lane & 15;
  int srow = tid >> 2, scol = (tid & 3) * 8;

  f32x4 acc[2][2];
#pragma unroll
  for (int i = 0; i < 2; i++)
#pragma unroll
    for (int j = 0; j < 2; j++) acc[i][j] = (f32x4){0.f, 0.f, 0.f, 0.f};

  int row = rb + srow;
  const ushort* bp = BT + (size_t)(cb + srow) * 512 + scol;
  ushort* aw = &As[srow * 40 + scol];
  ushort* bw = &Bs[srow * 40 + scol];

  for (int k0 = 0; k0 < 512; k0 += 32) {
    int colb = k0 + scol;
    int hh = colb >> 6;
    const float* gp = gates + (size_t)row * 24 + hh * 3;
    float g0 = gp[0], g1 = gp[1], g2 = gp[2];
    size_t off = (size_t)row * 512 + colb;
    float4 c0 = *(const float4*)(cg + off), c1 = *(const float4*)(cg + off + 4);
    float4 f0 = *(const float4*)(fg + off), f1 = *(const float4*)(fg + off + 4);
    float4 s0 = *(const float4*)(sg + off), s1 = *(const float4*)(sg + off + 4);
    float va[8] = {g0 * c0.x + g1 * f0.x + g2 * s0.x,
                   g0 * c0.y + g1 * f0.y + g2 * s0.y,
                   g0 * c0.z + g1 * f0.z + g2 * s0.z,
                   g0 * c0.w + g1 * f0.w + g2 * s0.w,
                   g0 * c1.x + g1 * f1.x + g2 * s1.x,
                   g0 * c1.y + g1 * f1.y + g2 * s1.y,
                   g0 * c1.z + g1 * f1.z + g2 * s1.z,
                   g0 * c1.w + g1 * f1.w + g2 * s1.w};
    ushort h[8];
#pragma unroll
    for (int e = 0; e < 8; e++) h[e] = f2b(va[e]);
    *(int4*)aw = *(int4*)h;
    *(int4*)bw = *(const int4*)(bp + k0);
    __syncthreads();
    bf16x8 af[2], bfr[2];
#pragma unroll
    for (int t = 0; t < 2; t++) {
      af[t]  = *(const bf16x8*)&As[(wm + t * 16 + l15) * 40 + q * 8];
      bfr[t] = *(const bf16x8*)&Bs[(wn + t * 16 + l15) * 40 + q * 8];
    }
#pragma unroll
    for (int i = 0; i < 2; i++)
#pragma unroll
      for (int j = 0; j < 2; j++)
        acc[i][j] = __builtin_amdgcn_mfma_f32_16x16x32_bf16(af[i], bfr[j],
                                                            acc[i][j], 0, 0, 0);
    __syncthreads();
  }

#pragma unroll
  for (int i = 0; i < 2; i++) {
#pragma unroll
    for (int j = 0; j < 2; j++) {
      int col = cb + wn + j * 16 + l15;
#pragma unroll
      for (int r = 0; r < 4; r++) {
        int rr = rb + wm + i * 16 + q * 4 + r;
        Co[(size_t)rr * 512 + col] = acc[i][j][r] + Res[(size_t)rr * 512 + col];
      }
    }
  }
}

// ---------- split-bf16 MFMA GEMM (hi+lo): QKV + gates; v written head-major ----------
__global__ void __launch_bounds__(256)
k_gemm_qkv(const float* __restrict__ A, const ushort* __restrict__ BTh,
           const ushort* __restrict__ BTl, float* __restrict__ Co,
           float* __restrict__ vhm, float* __restrict__ gates, int Kd) {
  __shared__ ushort Ash[64 * 40];
  __shared__ ushort Asl[64 * 40];
  __shared__ ushort Bsh[64 * 40];
  __shared__ ushort Bsl[64 * 40];
  int tid = threadIdx.x;
  int lane = tid & 63, wave = tid >> 6;
  int rb = blockIdx.y * 64, cb = blockIdx.x * 64;
  int wm = (wave >> 1) * 32, wn = (wave & 1) * 32;
  int q = lane >> 4, l15 = lane & 15;
  int srow = tid >> 2, scol = (tid & 3) * 8;

  f32x4 acc[2][2];
#pragma unroll
  for (int i = 0; i < 2; i++)
#pragma unroll
    for (int j = 0; j < 2; j++) acc[i][j] = (f32x4){0.f, 0.f, 0.f, 0.f};

  const float*  ap  = A   + (size_t)(rb + srow) * Kd + scol;
  const ushort* bph = BTh + (size_t)(cb + srow) * Kd + scol;
  const ushort* bpl = BTl + (size_t)(cb + srow) * Kd + scol;
  ushort* awh = &Ash[srow * 40 + scol];
  ushort* awl = &Asl[srow * 40 + scol];
  ushort* bwh = &Bsh[srow * 40 + scol];
  ushort* bwl = &Bsl[srow * 40 + scol];

  for (int k0 = 0; k0 < Kd; k0 += 32) {
    float4 a0 = *(const float4*)(ap + k0);
    float4 a1 = *(const float4*)(ap + k0 + 4);
    float va[8] = {a0.x, a0.y, a0.z, a0.w, a1.x, a1.y, a1.z, a1.w};
    ushort hh[8], hl[8];
#pragma unroll
    for (int e = 0; e < 8; e++) {
      hh[e] = f2b(va[e]);
      hl[e] = f2b(va[e] - b2f(hh[e]));
    }
    *(int4*)awh = *(int4*)hh;
    *(int4*)awl = *(int4*)hl;
    *(int4*)bwh = *(const int4*)(bph + k0);
    *(int4*)bwl = *(const int4*)(bpl + k0);
    __syncthreads();
    bf16x8 afh[2], afl[2], bfh[2], bfl[2];
#pragma unroll
    for (int t = 0; t < 2; t++) {
      int ar = (wm + t * 16 + l15) * 40 + q * 8;
      int br = (wn + t * 16 + l15) * 40 + q * 8;
      afh[t] = *(const bf16x8*)&Ash[ar];
      afl[t] = *(const bf16x8*)&Asl[ar];
      bfh[t] = *(const bf16x8*)&Bsh[br];
      bfl[t] = *(const bf16x8*)&Bsl[br];
    }
#pragma unroll
    for (int i = 0; i < 2; i++)
#pragma unroll
      for (int j = 0; j < 2; j++) {
        acc[i][j] = __builtin_amdgcn_mfma_f32_16x16x32_bf16(afh[i], bfh[j],
                                                            acc[i][j], 0, 0, 0);
        acc[i][j] = __builtin_amdgcn_mfma_f32_16x16x32_bf16(afh[i], bfl[j],
                                                            acc[i][j], 0, 0, 0);
        acc[i][j] = __builtin_amdgcn_mfma_f32_16x16x32_bf16(afl[i], bfh[j],
                                                            acc[i][j], 0, 0, 0);
      }
    __syncthreads();
  }

  const size_t NW = (size_t)NTOK * DIMM;
#pragma unroll
  for (int i = 0; i < 2; i++) {
#pragma unroll
    for (int j = 0; j < 2; j++) {
      int col = cb + wn + j * 16 + l15;
#pragma unroll
      for (int r = 0; r < 4; r++) {
        int row = rb + wm + i * 16 + q * 4 + r;
        float vv = acc[i][j][r];
        if (cb >= 1536) {
          int c24 = col - 1536;
          if (c24 < 24)
            gates[(size_t)row * 24 + c24] = 1.f / (1.f + expf(-vv));
        } else if (col >= 1024) {
          int c = col - 1024;   // v plane -> head-major
          vhm[(size_t)(c >> 6) * 65536 + (size_t)row * 64 + (c & 63)] = vv;
        } else {
          Co[(size_t)(col >> 9) * NW + (size_t)row * 512 + (col & 511)] = vv;
        }
      }
    }
  }
}

// ---------- RoPE: q in-place (token-major); k -> khm (head-major) ----------
__global__ void __launch_bounds__(256)
k_rope(float* __restrict__ q, const float* __restrict__ k,
       float* __restrict__ khm) {
  int idx = blockIdx.x * 256 + threadIdx.x;
  int ten = idx >> 18;
  int r = idx & 262143;
  int j = r & 31;
  int h = (r >> 5) & 7;
  int n = r >> 8;
  float inv = powf(10000.f, -(float)j / 32.f);
  float ang = (float)n * inv;
  float sn, cs;
  sincosf(ang, &sn, &cs);
  size_t base = (size_t)n * DIMM + h * HD + j;
  if (ten == 0) {
    float x1 = q[base], x2 = q[base + 32];
    q[base] = x1 * cs - x2 * sn;
    q[base + 32] = x2 * cs + x1 * sn;
  } else {
    float x1 = k[base], x2 = k[base + 32];
    size_t ob = (size_t)h * 65536 + (size_t)n * 64 + j;
    khm[ob] = x1 * cs - x2 * sn;
    khm[ob + 32] = x2 * cs + x1 * sn;
  }
}

// ---------- compressed k/v via MFMA hi/lo (head-major inputs) ----------
__global__ void __launch_bounds__(256)
k_ckcv_m(const float* __restrict__ khm, const float* __restrict__ vhm,
         const float* __restrict__ k_pos, const float* __restrict__ v_pos,
         const ushort* __restrict__ WckTh, const ushort* __restrict__ WckTl,
         const ushort* __restrict__ WcvTh, const ushort* __restrict__ WcvTl,
         const float* __restrict__ bck, const float* __restrict__ bcv,
         float* __restrict__ ckb, float* __restrict__ cvb) {
  int h = blockIdx.x, kv = blockIdx.y;
  const float* src = kv ? vhm : khm;
  const float* pos = kv ? v_pos : k_pos;
  const ushort* WTh = kv ? WcvTh : WckTh;
  const ushort* WTl = kv ? WcvTl : WckTl;
  const float* bias = kv ? bcv : bck;
  float* outp = kv ? cvb : ckb;

  __shared__ ushort Ash[64 * 72], Asl[64 * 72];
  __shared__ ushort Bsh[64 * 72], Bsl[64 * 72];
  int tid = threadIdx.x;
  int lane = tid & 63, wave = tid >> 6;
  int wm = (wave >> 1) * 32, wn = (wave & 1) * 32;
  int q = lane >> 4, l15 = lane & 15;
  int srow = tid >> 2;
  int e0 = (tid & 3) * 16;

  f32x4 acc[2][2];
#pragma unroll
  for (int i = 0; i < 2; i++)
#pragma unroll
    for (int j = 0; j < 2; j++) acc[i][j] = (f32x4){0.f, 0.f, 0.f, 0.f};

  for (int t = 0; t < 16; t++) {
    const float* ar = src + (size_t)h * 65536 + (size_t)(srow * 16 + t) * 64 + e0;
    const float* pr = pos + (size_t)(h * 16 + t) * HD + e0;
    ushort hh[16], hl[16];
#pragma unroll
    for (int u = 0; u < 4; u++) {
      float4 av = *(const float4*)(ar + u * 4);
      float4 pv = *(const float4*)(pr + u * 4);
      float vals[4] = {av.x + pv.x, av.y + pv.y, av.z + pv.z, av.w + pv.w};
#pragma unroll
      for (int e = 0; e < 4; e++) {
        ushort hb = f2b(vals[e]);
        hh[u * 4 + e] = hb;
        hl[u * 4 + e] = f2b(vals[e] - b2f(hb));
      }
    }
    *(int4*)&Ash[srow * 72 + e0]     = *(int4*)&hh[0];
    *(int4*)&Ash[srow * 72 + e0 + 8] = *(int4*)&hh[8];
    *(int4*)&Asl[srow * 72 + e0]     = *(int4*)&hl[0];
    *(int4*)&Asl[srow * 72 + e0 + 8] = *(int4*)&hl[8];
    const ushort* bh = WTh + (size_t)srow * 1024 + t * 64 + e0;
    const ushort* bl = WTl + (size_t)srow * 1024 + t * 64 + e0;
    *(int4*)&Bsh[srow * 72 + e0]     = *(const int4*)bh;
    *(int4*)&Bsh[srow * 72 + e0 + 8] = *(const int4*)(bh + 8);
    *(int4*)&Bsl[srow * 72 + e0]     = *(const int4*)bl;
    *(int4*)&Bsl[srow * 72 + e0 + 8] = *(const int4*)(bl + 8);
    __syncthreads();
#pragma unroll
    for (int sub = 0; sub < 2; sub++) {
      bf16x8 afh[2], afl[2], bfh[2], bfl[2];
#pragma unroll
      for (int ti = 0; ti < 2; ti++) {
        int ar2 = (wm + ti * 16 + l15) * 72 + sub * 32 + q * 8;
        int br2 = (wn + ti * 16 + l15) * 72 + sub * 32 + q * 8;
        afh[ti] = *(const bf16x8*)&Ash[ar2];
        afl[ti] = *(const bf16x8*)&Asl[ar2];
        bfh[ti] = *(const bf16x8*)&Bsh[br2];
        bfl[ti] = *(const bf16x8*)&Bsl[br2];
      }
#pragma unroll
      for (int i = 0; i < 2; i++)
#pragma unroll
        for (int j = 0; j < 2; j++) {
          acc[i][j] = __builtin_amdgcn_mfma_f32_16x16x32_bf16(afh[i], bfh[j],
                                                              acc[i][j], 0, 0, 0);
          acc[i][j] = __builtin_amdgcn_mfma_f32_16x16x32_bf16(afh[i], bfl[j],
                                                              acc[i][j], 0, 0, 0);
          acc[i][j] = __builtin_amdgcn_mfma_f32_16x16x32_bf16(afl[i], bfh[j],
                                                              acc[i][j], 0, 0, 0);
        }
    }
    __syncthreads();
  }

#pragma unroll
  for (int i = 0; i < 2; i++) {
#pragma unroll
    for (int j = 0; j < 2; j++) {
      int d = wn + j * 16 + l15;
      float bv = bias[d];
#pragma unroll
      for (int r = 0; r < 4; r++) {
        int c = wm + i * 16 + q * 4 + r;
        outp[((size_t)h * 64 + c) * 64 + d] = acc[i][j][r] + bv;
      }
    }
  }
}

// ---------- compressed attention + top-8 (standalone, barrier-light) ----------
__global__ void __launch_bounds__(256)
k_cmp(const float* __restrict__ qg, const float* __restrict__ ckb,
      const float* __restrict__ cvb, const float* __restrict__ k_mem,
      const float* __restrict__ v_mem, float* __restrict__ cout,
      int* __restrict__ sel) {
  int h = blockIdx.y, i0 = blockIdx.x * 16;
  int tid = threadIdx.x, lane = tid & 63, w = tid >> 6;
  __shared__ float ckt[64][65];
  __shared__ float cvs[64][65];
  __shared__ float qs[16][64];
  __shared__ float kms[64], vms[64];
  __shared__ float sp[4][64];

#pragma unroll
  for (int r = 0; r < 4; r++) {
    int f = r * 256 + tid;
    int c = f >> 4, d0 = (f & 15) * 4;
    float4 t = *(const float4*)(ckb + ((size_t)h * 64 + c) * 64 + d0);
    ckt[d0][c] = t.x; ckt[d0 + 1][c] = t.y; ckt[d0 + 2][c] = t.z; ckt[d0 + 3][c] = t.w;
    float4 u = *(const float4*)(cvb + ((size_t)h * 64 + c) * 64 + d0);
    cvs[c][d0] = u.x; cvs[c][d0 + 1] = u.y; cvs[c][d0 + 2] = u.z; cvs[c][d0 + 3] = u.w;
  }
  {
    int r = tid >> 4, d0 = (tid & 15) * 4;
    float4 t = *(const float4*)(qg + (size_t)(i0 + r) * DIMM + h * HD + d0);
    qs[r][d0] = t.x; qs[r][d0 + 1] = t.y; qs[r][d0 + 2] = t.z; qs[r][d0 + 3] = t.w;
  }
  if (tid < 64) kms[tid] = k_mem[h * HD + tid];
  else if (tid < 128) vms[tid - 64] = v_mem[h * HD + tid - 64];
  __syncthreads();

  for (int s = 0; s < 4; s++) {
    int ql = w * 4 + s, qi = i0 + ql;
    float dot = 0.f, dm = 0.f;
#pragma unroll 8
    for (int e = 0; e < 64; e++) {
      float qe = qs[ql][e];
      dot = fmaf(qe, ckt[e][lane], dot);
      dm  = fmaf(qe, kms[e], dm);
    }
    bool vis = (lane * BCB + BCB - 1) < qi;
    float sj = vis ? dot * SCALE : NEGV;
    float smem = dm * SCALE;
    float m = wred_max(fmaxf(sj, smem));
    float p = expf(sj - m);
    float pmem = expf(smem - m);
    float l = wred_sum(p) + pmem;
    float inv = 1.f / l;

    float impv = vis ? p : NEGV;
#pragma unroll
    for (int kk = 0; kk < KSEL; kk++) {
      float bv = impv; int bi = lane;
#pragma unroll
      for (int off = 32; off > 0; off >>= 1) {
        float ov = __shfl_xor(bv, off);
        int   oi = __shfl_xor(bi, off);
        if (ov > bv || (ov == bv && oi < bi)) { bv = ov; bi = oi; }
      }
      if (lane == 0) sel[((size_t)h * NTOK + qi) * KSEL + kk] = (bv >= 0.f) ? bi : -1;
      if (lane == bi) impv = NEGV;
    }

    // sp slice is per-wave: no barrier needed between write and read
    sp[w][lane] = p;
    float od = pmem * vms[lane];
#pragma unroll 8
    for (int j = 0; j < 64; j++) od = fmaf(sp[w][j], cvs[j][lane], od);
    cout[(size_t)qi * DIMM + h * HD + lane] = od * inv;
  }
}

// ---------- sliding window: MFMA flash. block=(h, 64 q rows), wave owns 16 rows ----------
__global__ void __launch_bounds__(256)
k_swin(const float* __restrict__ qg, const float* __restrict__ khm,
       const float* __restrict__ vhm, float* __restrict__ sout) {
  int h = blockIdx.y, i0 = blockIdx.x * 64;
  int tid = threadIdx.x, lane = tid & 63, w = tid >> 6;
  int quad = lane >> 4, l15 = lane & 15;

  __shared__ ushort Kt[64 * 72];      // key-major [key][dim]
  __shared__ ushort VT[64 * 72];      // dim-major [dim][key]
  __shared__ ushort Qs[64 * 72];      // [row][dim]
  __shared__ ushort Ps[4][16 * 72];   // per-wave P scratch [row][key]

  // stage Q rows i0..i0+63 as bf16
#pragma unroll
  for (int it = 0; it < 4; it++) {
    int f = it * 256 + tid;
    int r = f >> 4, d0 = (f & 15) * 4;
    float4 t = *(const float4*)(qg + (size_t)(i0 + r) * DIMM + h * HD + d0);
    ushort4 u = {f2b(t.x), f2b(t.y), f2b(t.z), f2b(t.w)};
    *(ushort4*)&Qs[r * 72 + d0] = u;
  }

  int lo = i0 - (WWIN - 1); if (lo < 0) lo = 0;
  int jb_lo = lo >> 6, jb_hi = (i0 + 63) >> 6;

  float mrow[4], lrow[4];
  f32x4 Of[4];
#pragma unroll
  for (int r = 0; r < 4; r++) { mrow[r] = NEGV; lrow[r] = 0.f; }
#pragma unroll
  for (int d = 0; d < 4; d++) Of[d] = (f32x4){0.f, 0.f, 0.f, 0.f};

  for (int jb = jb_lo; jb <= jb_hi; jb++) {
    __syncthreads();
#pragma unroll
    for (int it = 0; it < 4; it++) {
      int f = it * 256 + tid;
      int r = f >> 4, d0 = (f & 15) * 4;
      const float* kp = khm + (size_t)h * 65536 + (size_t)(jb * 64 + r) * 64 + d0;
      float4 t = *(const float4*)kp;
      ushort4 u = {f2b(t.x), f2b(t.y), f2b(t.z), f2b(t.w)};
      *(ushort4*)&Kt[r * 72 + d0] = u;
      const float* vp = vhm + (size_t)h * 65536 + (size_t)(jb * 64 + r) * 64 + d0;
      float4 v4 = *(const float4*)vp;
      VT[(d0    ) * 72 + r] = f2b(v4.x);
      VT[(d0 + 1) * 72 + r] = f2b(v4.y);
      VT[(d0 + 2) * 72 + r] = f2b(v4.z);
      VT[(d0 + 3) * 72 + r] = f2b(v4.w);
    }
    __syncthreads();

    // QK^T: 16 rows x 64 keys
    bf16x8 qa[2];
#pragma unroll
    for (int c = 0; c < 2; c++)
      qa[c] = *(const bf16x8*)&Qs[(w * 16 + l15) * 72 + c * 32 + quad * 8];

    f32x4 sc[4];
#pragma unroll
    for (int ks = 0; ks < 4; ks++) {
      f32x4 a = (f32x4){0.f, 0.f, 0.f, 0.f};
#pragma unroll
      for (int c = 0; c < 2; c++) {
        bf16x8 kb = *(const bf16x8*)&Kt[(ks * 16 + l15) * 72 + c * 32 + quad * 8];
        a = __builtin_amdgcn_mfma_f32_16x16x32_bf16(qa[c], kb, a, 0, 0, 0);
      }
      sc[ks] = a;
    }

    // mask + online softmax (row = quad*4+r, col = ks*16+l15)
    float pm[4][4], rmax[4];
#pragma unroll
    for (int r = 0; r < 4; r++) rmax[r] = NEGV;
#pragma unroll
    for (int ks = 0; ks < 4; ks++) {
      int gj = jb * 64 + ks * 16 + l15;
#pragma unroll
      for (int r = 0; r < 4; r++) {
        int qi = i0 + w * 16 + quad * 4 + r;
        bool vis = (gj <= qi) && (qi - gj < WWIN);
        float s = vis ? sc[ks][r] * SCALE : NEGV;
        pm[ks][r] = s;
        rmax[r] = fmaxf(rmax[r], s);
      }
    }
#pragma unroll
    for (int off = 1; off < 16; off <<= 1)
#pragma unroll
      for (int r = 0; r < 4; r++)
        rmax[r] = fmaxf(rmax[r], __shfl_xor(rmax[r], off));

    float alpha[4], rsum[4];
#pragma unroll
    for (int r = 0; r < 4; r++) {
      float newm = fmaxf(mrow[r], rmax[r]);
      alpha[r] = expf(mrow[r] - newm);
      mrow[r] = newm;
      rsum[r] = 0.f;
    }
#pragma unroll
    for (int ks = 0; ks < 4; ks++)
#pragma unroll
      for (int r = 0; r < 4; r++) {
        float p = expf(pm[ks][r] - mrow[r]);
        pm[ks][r] = p;
        rsum[r] += p;
      }
#pragma unroll
    for (int off = 1; off < 16; off <<= 1)
#pragma unroll
      for (int r = 0; r < 4; r++)
        rsum[r] += __shfl_xor(rsum[r], off);
#pragma unroll
    for (int r = 0; r < 4; r++)
      lrow[r] = lrow[r] * alpha[r] + rsum[r];

    // P -> per-wave LDS (C layout -> A layout), O rescale
#pragma unroll
    for (int ks = 0; ks < 4; ks++)
#pragma unroll
      for (int r = 0; r < 4; r++)
        Ps[w][(quad * 4 + r) * 72 + ks * 16 + l15] = f2b(pm[ks][r]);
#pragma unroll
    for (int d = 0; d < 4; d++)
#pragma unroll
      for (int r = 0; r < 4; r++)
        Of[d][r] *= alpha[r];

    // PV: 16 rows x 64 dims over 64 keys
#pragma unroll
    for (int c = 0; c < 2; c++) {
      bf16x8 pa = *(const bf16x8*)&Ps[w][l15 * 72 + c * 32 + quad * 8];
#pragma unroll
      for (int d = 0; d < 4; d++) {
        bf16x8 vb = *(const bf16x8*)&VT[(d * 16 + l15) * 72 + c * 32 + quad * 8];
        Of[d] = __builtin_amdgcn_mfma_f32_16x16x32_bf16(pa, vb, Of[d], 0, 0, 0);
      }
    }
  }

#pragma unroll
  for (int d = 0; d < 4; d++)
#pragma unroll
    for (int r = 0; r < 4; r++) {
      int qi = i0 + w * 16 + quad * 4 + r;
      sout[(size_t)qi * DIMM + h * HD + d * 16 + l15] = Of[d][r] / lrow[r];
    }
}

// ---------- fine attention: direct QK gather + bf16 V staged in LDS ----------
__global__ void __launch_bounds__(256)
k_fine(const float* __restrict__ qg, const float* __restrict__ khm,
       const float* __restrict__ vhm, const int* __restrict__ sel,
       float* __restrict__ fout) {
  int i = blockIdx.x, h = blockIdx.y;
  int tid = threadIdx.x, lane = tid & 63, w = tid >> 6;
  __shared__ float qsh[64];
  __shared__ ushort vsb[144 * 64];
  __shared__ float sp[144];
  __shared__ int selS[8];
  __shared__ float mred[4], sredS[4];
  __shared__ float pacc[4][64];

  int own = i >> 4;
  if (tid < 64) qsh[tid] = qg[(size_t)i * DIMM + h * HD + tid];
  if (tid >= 64 && tid < 72)
    selS[tid - 64] = sel[((size_t)h * NTOK + i) * KSEL + tid - 64];
  __syncthreads();

  const float* kbase = khm + (size_t)h * 65536;
  const float* vbase = vhm + (size_t)h * 65536;

#pragma unroll
  for (int it = 0; it < 9; it++) {
    int idx = it * 256 + tid;
    int row = idx >> 4, c4 = (idx & 15) * 4;
    int kk = row >> 4;
    int bidx = (kk < KSEL) ? selS[kk] : own;
    if (bidx < 0) bidx = 0;
    float4 t = *(const float4*)(vbase + (size_t)(bidx * BSB + (row & 15)) * 64 + c4);
    ushort4 u = {f2b(t.x), f2b(t.y), f2b(t.z), f2b(t.w)};
    *(ushort4*)&vsb[row * 64 + c4] = u;
  }

  float s_loc = NEGV;
  bool active = (tid < 144);
  if (active) {
    int kk = tid >> 4;
    int bidx; bool vis;
    if (kk < KSEL) {
      bidx = selS[kk];
      vis = (bidx >= 0);
      if (!vis) bidx = 0;
    } else {
      bidx = own;
      vis = (tid - 128) <= (i & 15);
    }
    const float* kr = kbase + (size_t)(bidx * BSB + (tid & 15)) * 64;
    float dot = 0.f;
#pragma unroll
    for (int e4 = 0; e4 < 16; e4++) {
      float4 kv = *(const float4*)(kr + e4 * 4);
      float4 qv = *(const float4*)&qsh[e4 * 4];
      dot = fmaf(qv.x, kv.x, dot); dot = fmaf(qv.y, kv.y, dot);
      dot = fmaf(qv.z, kv.z, dot); dot = fmaf(qv.w, kv.w, dot);
    }
    s_loc = vis ? dot * SCALE : NEGV;
  }
  float mw = wred_max(s_loc);
  if (lane == 0) mred[w] = mw;
  __syncthreads();
  float m = fmaxf(fmaxf(mred[0], mred[1]), fmaxf(mred[2], mred[3]));
  float p = active ? expf(s_loc - m) : 0.f;
  float sw = wred_sum(p);
  if (lane == 0) sredS[w] = sw;
  if (active) sp[tid] = p;
  __syncthreads();
  float l = sredS[0] + sredS[1] + sredS[2] + sredS[3];

  float acc = 0.f;
  int j0 = w * 36;
#pragma unroll 6
  for (int jj = 0; jj < 36; jj++) {
    int j = j0 + jj;
    acc = fmaf(sp[j], b2f(vsb[j * 64 + lane]), acc);
  }
  pacc[w][lane] = acc;
  __syncthreads();
  if (w == 0)
    fout[(size_t)i * DIMM + h * HD + lane] =
        (pacc[0][lane] + pacc[1][lane] + pacc[2][lane] + pacc[3][lane]) / l;
}

extern "C" void kernel_launch(void* const* d_in, const int* in_sizes, int n_in,
                              void* d_out, int out_size, void* d_ws, size_t ws_size,
                              hipStream_t stream) {
  const float* x     = (const float*)d_in[0];
  const float* ve    = (const float*)d_in[1]; (void)ve;
  const float* x0    = (const float*)d_in[2];
  const float* lam   = (const float*)d_in[3];
  const float* Wq    = (const float*)d_in[4];
  const float* Wk    = (const float*)d_in[5];
  const float* Wv    = (const float*)d_in[6];
  const float* Wo    = (const float*)d_in[7];
  const float* Wg    = (const float*)d_in[8];
  const float* k_pos = (const float*)d_in[9];
  const float* v_pos = (const float*)d_in[10];
  const float* Wck   = (const float*)d_in[11];
  const float* bck   = (const float*)d_in[12];
  const float* Wcv   = (const float*)d_in[13];
  const float* bcv   = (const float*)d_in[14];
  const float* k_mem = (const float*)d_in[15];
  const float* v_mem = (const float*)d_in[16];
  const float* W1    = (const float*)d_in[17];
  const float* W2    = (const float*)d_in[18];
  float* out = (float*)d_out;
  float* ws  = (float*)d_ws;

  const size_t NW = (size_t)NTOK * DIMM;   // 524288
  float* xr    = ws;
  float* xn    = ws + 1 * NW;
  float* q     = ws + 2 * NW;
  float* k     = ws + 3 * NW;     // token-major k (dead after rope)
  float* vhm   = ws + 4 * NW;     // head-major v (written by QKV epilogue)
  float* coutb = ws + 5 * NW;
  float* foutb = ws + 6 * NW;
  float* soutb = ws + 7 * NW;
  float* x2    = ws + 8 * NW;     // khm until gemm_wo overwrites as x2
  float* khm   = x2;
  float* gates = ws + 9 * NW;
  float* ckb   = gates + 32768;
  float* cvb   = ckb + 32768;
  int*   selb  = (int*)(cvb + 32768);
  ushort* qkvTh = (ushort*)(cvb + 32768 + 65536);
  ushort* qkvTl = qkvTh + 1600 * 512;
  ushort* WoT   = qkvTl + 1600 * 512;
  ushort* W1T   = WoT   + 512 * 512;
  ushort* W2T   = W1T   + 2048 * 512;
  ushort* WckTh = W2T   + 512 * 2048;
  ushort* WckTl = WckTh + 64 * 1024;
  ushort* WcvTh = WckTl + 64 * 1024;
  ushort* WcvTl = WcvTh + 64 * 1024;
  float* y  = xr;   // reuse after Wo residual consumed xr
  float* h1 = q;    // f32 1024x2048 spans q,k,vhm,coutb (all dead post-Wo)

  WtrPack pk;
  pk.d[0] = {Wq, qkvTh,              qkvTl,              512, 512,  512};
  pk.d[1] = {Wk, qkvTh + 512 * 512,  qkvTl + 512 * 512,  512, 512,  512};
  pk.d[2] = {Wv, qkvTh + 1024 * 512, qkvTl + 1024 * 512, 512, 512,  512};
  pk.d[3] = {Wo, WoT, nullptr,  512, 512,  512};
  pk.d[4] = {W1, W1T, nullptr,  512, 2048, 2048};
  pk.d[5] = {W2, W2T, nullptr, 2048, 512,  512};
  pk.d[6] = {Wck, WckTh, WckTl, 1024, 64, 64};
  pk.d[7] = {Wcv, WcvTh, WcvTl, 1024, 64, 64};
  pk.d[8] = {Wg, qkvTh + 1536 * 512, qkvTl + 1536 * 512, 512, 24, 64};
  int cum = 0;
  for (int e = 0; e < 9; e++) {
    cum += (pk.d[e].Npad / 32) * (pk.d[e].K / 32);
    pk.cum[e] = cum;
  }
  k_wtr_all<<<cum, dim3(32, 8), 0, stream>>>(pk);

  k_resid_rms<<<NTOK, 256, 0, stream>>>(x, x0, lam, xr, xn);

  k_gemm_qkv<<<dim3(25, NTOK / 64), 256, 0, stream>>>(
      xn, qkvTh, qkvTl, q, vhm, gates, 512);
  k_rope<<<(2 * NTOK * NH * 32) / 256, 256, 0, stream>>>(q, k, khm);

  k_ckcv_m<<<dim3(NH, 2), 256, 0, stream>>>(khm, vhm, k_pos, v_pos,
                                            WckTh, WckTl, WcvTh, WcvTl,
                                            bck, bcv, ckb, cvb);
  k_cmp<<<dim3(NTOK / 16, NH), 256, 0, stream>>>(q, ckb, cvb, k_mem, v_mem,
                                                 coutb, selb);
  k_swin<<<dim3(NTOK / 64, NH), 256, 0, stream>>>(q, khm, vhm, soutb);
  k_fine<<<dim3(NTOK, NH), 256, 0, stream>>>(q, khm, vhm, selb, foutb);

  k_gemm_wo<<<dim3(512 / 64, NTOK / 64), 256, 0, stream>>>(
      coutb, foutb, soutb, gates, WoT, xr, x2);

  k_rms<<<NTOK, 256, 0, stream>>>(x2, y);
  k_gemm_bf16<<<dim3(2048 / 64, NTOK / 64), 256, 0, stream>>>(
      y, W1T, nullptr, h1, 512, 2048, 1);
  k_gemm_bf16<<<dim3(512 / 64, NTOK / 64), 256, 0, stream>>>(
      h1, W2T, x2, out, 2048, 512, 0);
}